// Round 2
// baseline (2358.607 us; speedup 1.0000x reference)
//
#include <hip/hip_runtime.h>

#define NN 4096
#define EE 65536
#define HC 256   // hidden channels

// ---------------- degree / GCN scatter ----------------
__global__ void deg_init_k(float* __restrict__ deg) {
    int i = blockIdx.x * 256 + threadIdx.x;
    deg[i] = 1.0f;  // self loop
}
__global__ void deg_scatter_k(const int* __restrict__ dst, float* __restrict__ deg) {
    int e = blockIdx.x * 256 + threadIdx.x;
    atomicAdd(&deg[dst[e]], 1.0f);
}
__global__ void dinv_k(const float* __restrict__ deg, float* __restrict__ dinv) {
    int i = blockIdx.x * 256 + threadIdx.x;
    dinv[i] = rsqrtf(deg[i]);
}
// agg[i][c] = xw[i][c] * dinv[i]^2   (self-loop term, also zero-inits the buffer)
__global__ void agg_init_k(const float* __restrict__ xw, const float* __restrict__ dinv,
                           float* __restrict__ agg) {
    int idx = blockIdx.x * 256 + threadIdx.x;
    int i = idx >> 8;
    float di = dinv[i];
    agg[idx] = xw[idx] * di * di;
}
// one thread = one edge x 4 channels
__global__ void edge_scatter_k(const int* __restrict__ src, const int* __restrict__ dst,
                               const float* __restrict__ xw, const float* __restrict__ dinv,
                               float* __restrict__ agg) {
    int idx = blockIdx.x * 256 + threadIdx.x;
    int e = idx >> 6;
    int c = (idx & 63) << 2;
    int s = src[e], d = dst[e];
    float coef = dinv[s] * dinv[d];
    const float4 v = *(const float4*)&xw[s * HC + c];
    atomicAdd(&agg[d * HC + c + 0], v.x * coef);
    atomicAdd(&agg[d * HC + c + 1], v.y * coef);
    atomicAdd(&agg[d * HC + c + 2], v.z * coef);
    atomicAdd(&agg[d * HC + c + 3], v.w * coef);
}

// ---------------- generic GEMM: out[N,M] = act(X[N,K] @ W[M,K]^T + b1 + b2 + res1 + s*res2)
__global__ __launch_bounds__(256)
void gemm_k(const float* __restrict__ X, const float* __restrict__ W,
            const float* __restrict__ bias1, const float* __restrict__ bias2,
            const float* __restrict__ res1, const float* __restrict__ res2, float res2scale,
            float* __restrict__ out, int K, int M, int dorelu)
{
    __shared__ float Xs[16][68];
    __shared__ float Ws[16][68];
    const int t = threadIdx.x;
    const int tx = t & 15, ty = t >> 4;
    const int row0 = blockIdx.y << 6, col0 = blockIdx.x << 6;
    const int lr = t >> 2, lc4 = (t & 3) << 2;
    float acc[4][4] = {};
    for (int k0 = 0; k0 < K; k0 += 16) {
        float4 xu = *(const float4*)&X[(row0 + lr) * K + k0 + lc4];
        float4 wu = *(const float4*)&W[(col0 + lr) * K + k0 + lc4];
        __syncthreads();
        Xs[lc4 + 0][lr] = xu.x;
        Xs[lc4 + 1][lr] = xu.y;
        Xs[lc4 + 2][lr] = xu.z;
        Xs[lc4 + 3][lr] = xu.w;
        Ws[lc4 + 0][lr] = wu.x;
        Ws[lc4 + 1][lr] = wu.y;
        Ws[lc4 + 2][lr] = wu.z;
        Ws[lc4 + 3][lr] = wu.w;
        __syncthreads();
        #pragma unroll
        for (int kk = 0; kk < 16; kk++) {
            float4 a4 = *(const float4*)&Xs[kk][ty << 2];
            float4 b4 = *(const float4*)&Ws[kk][tx << 2];
            float a[4] = {a4.x, a4.y, a4.z, a4.w};
            float b[4] = {b4.x, b4.y, b4.z, b4.w};
            #pragma unroll
            for (int i = 0; i < 4; i++)
                #pragma unroll
                for (int j = 0; j < 4; j++)
                    acc[i][j] += a[i] * b[j];
        }
    }
    #pragma unroll
    for (int i = 0; i < 4; i++) {
        int row = row0 + (ty << 2) + i;
        int cb = col0 + (tx << 2);
        float v[4] = {acc[i][0], acc[i][1], acc[i][2], acc[i][3]};
        if (bias1) {
            #pragma unroll
            for (int j = 0; j < 4; j++) v[j] += bias1[cb + j];
        }
        if (bias2) {
            #pragma unroll
            for (int j = 0; j < 4; j++) v[j] += bias2[cb + j];
        }
        if (res1) {
            float4 r = *(const float4*)&res1[row * M + cb];
            v[0] += r.x; v[1] += r.y; v[2] += r.z; v[3] += r.w;
        }
        if (res2) {
            float4 r = *(const float4*)&res2[row * M + cb];
            v[0] += res2scale * r.x; v[1] += res2scale * r.y;
            v[2] += res2scale * r.z; v[3] += res2scale * r.w;
        }
        if (dorelu) {
            #pragma unroll
            for (int j = 0; j < 4; j++) v[j] = fmaxf(v[j], 0.f);
        }
        *(float4*)&out[row * M + cb] = make_float4(v[0], v[1], v[2], v[3]);
    }
}

// ---------------- attention: block = 16 queries x 1 head, flash-style ----------------
__global__ __launch_bounds__(256)
void attn_k(const float* __restrict__ qkv, float* __restrict__ att)
{
    __shared__ float Ks[64][68];
    __shared__ float Vt[64][65];   // Vt[d][j]
    __shared__ float Qs[16][64];
    __shared__ float Ps[4][64][4]; // [wave][key][qi]
    const int hh = blockIdx.y;
    const int q0 = blockIdx.x << 4;
    const int t = threadIdx.x;
    const int w = t >> 6, lane = t & 63;

    for (int i = t; i < 16 * 64; i += 256) {
        int qi = i >> 6, d = i & 63;
        Qs[qi][d] = qkv[(q0 + qi) * 768 + hh * 64 + d] * 0.125f;
    }

    float m[4], l[4], o[4];
    #pragma unroll
    for (int qi = 0; qi < 4; qi++) { m[qi] = -1e30f; l[qi] = 0.f; o[qi] = 0.f; }

    for (int kb = 0; kb < 64; kb++) {
        __syncthreads();
        for (int i = t; i < 64 * 64; i += 256) {
            int j = i >> 6, d = i & 63;
            int base = (kb * 64 + j) * 768 + hh * 64 + d;
            Ks[j][d] = qkv[base + 256];
            Vt[d][j] = qkv[base + 512];
        }
        __syncthreads();

        // scores: lane = key j
        float s[4] = {0.f, 0.f, 0.f, 0.f};
        #pragma unroll 4
        for (int d4 = 0; d4 < 64; d4 += 4) {
            float4 kv = *(const float4*)&Ks[lane][d4];
            float k0 = kv.x, k1 = kv.y, k2 = kv.z, k3 = kv.w;
            #pragma unroll
            for (int qi = 0; qi < 4; qi++) {
                float4 qv = *(const float4*)&Qs[(w << 2) + qi][d4];
                s[qi] += qv.x * k0 + qv.y * k1 + qv.z * k2 + qv.w * k3;
            }
        }
        float alpha[4];
        #pragma unroll
        for (int qi = 0; qi < 4; qi++) {
            float mx = s[qi];
            #pragma unroll
            for (int off = 32; off > 0; off >>= 1)
                mx = fmaxf(mx, __shfl_xor(mx, off));
            float mnew = fmaxf(m[qi], mx);
            float p = __expf(s[qi] - mnew);
            Ps[w][lane][qi] = p;
            float ps = p;
            #pragma unroll
            for (int off = 32; off > 0; off >>= 1)
                ps += __shfl_xor(ps, off);
            alpha[qi] = __expf(m[qi] - mnew);
            l[qi] = l[qi] * alpha[qi] + ps;
            m[qi] = mnew;
        }
        #pragma unroll
        for (int qi = 0; qi < 4; qi++) o[qi] *= alpha[qi];
        // o-accum: lane = dim d (Ps written/read by the same wave; no barrier needed)
        #pragma unroll 8
        for (int j = 0; j < 64; j++) {
            float vv = Vt[lane][j];
            float4 pv = *(const float4*)&Ps[w][j][0];
            o[0] += pv.x * vv;
            o[1] += pv.y * vv;
            o[2] += pv.z * vv;
            o[3] += pv.w * vv;
        }
    }
    #pragma unroll
    for (int qi = 0; qi < 4; qi++) {
        int q = q0 + (w << 2) + qi;
        att[q * 256 + hh * 64 + lane] = o[qi] / l[qi];
    }
}

// ---------------- symmetrized final MLP: out = 0.5*(delta + delta^T), fused ----------------
__global__ __launch_bounds__(256)
void sym_mlp_k(const float* __restrict__ T, const float* __restrict__ W2,
               const float* __restrict__ b2, float* __restrict__ out)
{
    const int bi = blockIdx.y, bj = blockIdx.x;
    if (bi > bj) return;
    __shared__ float Ti[16][68], Tj[16][68], Wi[16][68], Wj[16][68];
    const int t = threadIdx.x;
    const int tx = t & 15, ty = t >> 4;
    const int lr = t >> 2, lc4 = (t & 3) << 2;
    const int ri = bi << 6, rj = bj << 6;
    float d1[4][4] = {}, d2[4][4] = {};
    for (int k0 = 0; k0 < 256; k0 += 16) {
        float4 ta = *(const float4*)&T[(ri + lr) * 256 + k0 + lc4];
        float4 tb = *(const float4*)&T[(rj + lr) * 256 + k0 + lc4];
        float4 wa = *(const float4*)&W2[(ri + lr) * 256 + k0 + lc4];
        float4 wb = *(const float4*)&W2[(rj + lr) * 256 + k0 + lc4];
        __syncthreads();
        Ti[lc4 + 0][lr] = ta.x; Ti[lc4 + 1][lr] = ta.y; Ti[lc4 + 2][lr] = ta.z; Ti[lc4 + 3][lr] = ta.w;
        Tj[lc4 + 0][lr] = tb.x; Tj[lc4 + 1][lr] = tb.y; Tj[lc4 + 2][lr] = tb.z; Tj[lc4 + 3][lr] = tb.w;
        Wi[lc4 + 0][lr] = wa.x; Wi[lc4 + 1][lr] = wa.y; Wi[lc4 + 2][lr] = wa.z; Wi[lc4 + 3][lr] = wa.w;
        Wj[lc4 + 0][lr] = wb.x; Wj[lc4 + 1][lr] = wb.y; Wj[lc4 + 2][lr] = wb.z; Wj[lc4 + 3][lr] = wb.w;
        __syncthreads();
        #pragma unroll
        for (int kk = 0; kk < 16; kk++) {
            float4 a1 = *(const float4*)&Ti[kk][ty << 2];
            float4 b1 = *(const float4*)&Wj[kk][tx << 2];
            float4 a2 = *(const float4*)&Wi[kk][ty << 2];
            float4 bb = *(const float4*)&Tj[kk][tx << 2];
            float A1[4] = {a1.x, a1.y, a1.z, a1.w};
            float B1[4] = {b1.x, b1.y, b1.z, b1.w};
            float A2[4] = {a2.x, a2.y, a2.z, a2.w};
            float B2[4] = {bb.x, bb.y, bb.z, bb.w};
            #pragma unroll
            for (int i = 0; i < 4; i++)
                #pragma unroll
                for (int j = 0; j < 4; j++) {
                    d1[i][j] += A1[i] * B1[j];
                    d2[i][j] += A2[i] * B2[j];
                }
        }
    }
    #pragma unroll
    for (int i = 0; i < 4; i++) {
        int row = ri + (ty << 2) + i;
        float brow = b2[row];
        #pragma unroll
        for (int j = 0; j < 4; j++) {
            int col = rj + (tx << 2) + j;
            float v = 0.5f * (d1[i][j] + d2[i][j] + b2[col] + brow);
            out[row * NN + col] = v;
            out[col * NN + row] = v;
        }
    }
}

// ---------------- launch ----------------
extern "C" void kernel_launch(void* const* d_in, const int* in_sizes, int n_in,
                              void* d_out, int out_size, void* d_ws, size_t ws_size,
                              hipStream_t stream) {
    (void)in_sizes; (void)n_in; (void)out_size; (void)ws_size;
    const float* x = (const float*)d_in[0];
    const int* ei = (const int*)d_in[1];
    const int* src = ei;
    const int* dst = ei + EE;

    float* ws = (float*)d_ws;
    const int NH = NN * HC;          // 1,048,576 floats
    float* h0  = ws;                 // current h
    float* hb  = ws + 1 * NH;        // gcn agg (h1 minus bias/residual)
    float* hc  = ws + 2 * NH;        // "out"
    float* att = ws + 3 * NH;        // xw / attention out / mlp hidden (reused)
    float* qkv = ws + 4 * NH;        // N x 768 ; FFN hidden reuses this region later
    float* ffh = ws + 4 * NH;        // N x 512 (qkv dead by then)
    float* deg = ws + 7 * NH;
    float* dinv = deg + NN;

    // graph degree (static across both GPS layers)
    deg_init_k<<<NN / 256, 256, 0, stream>>>(deg);
    deg_scatter_k<<<EE / 256, 256, 0, stream>>>(dst, deg);
    dinv_k<<<NN / 256, 256, 0, stream>>>(deg, dinv);

    // pre: h0 = relu(x @ pre_w^T + pre_b)
    gemm_k<<<dim3(4, 64), 256, 0, stream>>>(
        x, (const float*)d_in[2], (const float*)d_in[3], nullptr,
        nullptr, nullptr, 0.f, h0, 128, 256, 1);

    for (int L = 0; L < 2; L++) {
        int B = 4 + L * 10;
        const float* gw = (const float*)d_in[B + 0];
        const float* gb = (const float*)d_in[B + 1];
        const float* iw = (const float*)d_in[B + 2];
        const float* ib = (const float*)d_in[B + 3];
        const float* ow = (const float*)d_in[B + 4];
        const float* ob = (const float*)d_in[B + 5];
        const float* w1 = (const float*)d_in[B + 6];
        const float* b1 = (const float*)d_in[B + 7];
        const float* w2 = (const float*)d_in[B + 8];
        const float* b2 = (const float*)d_in[B + 9];

        // xw = h0 @ gcn_w^T   (into att buffer)
        gemm_k<<<dim3(4, 64), 256, 0, stream>>>(
            h0, gw, nullptr, nullptr, nullptr, nullptr, 0.f, att, 256, 256, 0);
        // gcn aggregation into hb
        agg_init_k<<<NH / 256, 256, 0, stream>>>(att, dinv, hb);
        edge_scatter_k<<<EE * 64 / 256, 256, 0, stream>>>(src, dst, att, dinv, hb);
        // qkv = h0 @ in_w^T + in_b
        gemm_k<<<dim3(12, 64), 256, 0, stream>>>(
            h0, iw, ib, nullptr, nullptr, nullptr, 0.f, qkv, 256, 768, 0);
        // attention -> att
        attn_k<<<dim3(256, 4), 256, 0, stream>>>(qkv, att);
        // out = att @ out_w^T + ob + gb + hb + 2*h0   -> hc
        gemm_k<<<dim3(4, 64), 256, 0, stream>>>(
            att, ow, ob, gb, hb, h0, 2.0f, hc, 256, 256, 0);
        // ffh = relu(hc @ w1^T + b1)
        gemm_k<<<dim3(8, 64), 256, 0, stream>>>(
            hc, w1, b1, nullptr, nullptr, nullptr, 0.f, ffh, 256, 512, 1);
        // h0 = relu(ffh @ w2^T + b2 + hc)
        gemm_k<<<dim3(4, 64), 256, 0, stream>>>(
            ffh, w2, b2, nullptr, hc, nullptr, 0.f, h0, 512, 256, 1);
    }

    // t = relu(h0 @ mlp_w1^T + mlp_b1)  (into att buffer)
    gemm_k<<<dim3(4, 64), 256, 0, stream>>>(
        h0, (const float*)d_in[24], (const float*)d_in[25], nullptr,
        nullptr, nullptr, 0.f, att, 256, 256, 1);
    // out = 0.5*(delta + delta^T)
    sym_mlp_k<<<dim3(64, 64), 256, 0, stream>>>(
        att, (const float*)d_in[26], (const float*)d_in[27], (float*)d_out);
}

// Round 3
// 1315.133 us; speedup vs baseline: 1.7934x; 1.7934x over previous
//
#include <hip/hip_runtime.h>

#define NN 4096
#define EE 65536
#define HC 256   // hidden channels

typedef unsigned short ushort_t;
typedef __attribute__((ext_vector_type(8))) short bf16x8;
typedef __attribute__((ext_vector_type(4))) float f32x4;

__device__ __forceinline__ ushort_t f2bf(float f) {
    unsigned int u = __float_as_uint(f);
    unsigned int r = (u + 0x7fffu + ((u >> 16) & 1u)) >> 16;
    return (ushort_t)r;
}

// ---------------- degree / GCN scatter ----------------
__global__ void deg_init_k(float* __restrict__ deg) {
    int i = blockIdx.x * 256 + threadIdx.x;
    deg[i] = 1.0f;  // self loop
}
__global__ void deg_scatter_k(const int* __restrict__ dst, float* __restrict__ deg) {
    int e = blockIdx.x * 256 + threadIdx.x;
    atomicAdd(&deg[dst[e]], 1.0f);
}
__global__ void dinv_k(const float* __restrict__ deg, float* __restrict__ dinv) {
    int i = blockIdx.x * 256 + threadIdx.x;
    dinv[i] = rsqrtf(deg[i]);
}
__global__ void agg_init_k(const float* __restrict__ xw, const float* __restrict__ dinv,
                           float* __restrict__ agg) {
    int idx = blockIdx.x * 256 + threadIdx.x;
    int i = idx >> 8;
    float di = dinv[i];
    agg[idx] = xw[idx] * di * di;
}
__global__ void edge_scatter_k(const int* __restrict__ src, const int* __restrict__ dst,
                               const float* __restrict__ xw, const float* __restrict__ dinv,
                               float* __restrict__ agg) {
    int idx = blockIdx.x * 256 + threadIdx.x;
    int e = idx >> 6;
    int c = (idx & 63) << 2;
    int s = src[e], d = dst[e];
    float coef = dinv[s] * dinv[d];
    const float4 v = *(const float4*)&xw[s * HC + c];
    atomicAdd(&agg[d * HC + c + 0], v.x * coef);
    atomicAdd(&agg[d * HC + c + 1], v.y * coef);
    atomicAdd(&agg[d * HC + c + 2], v.z * coef);
    atomicAdd(&agg[d * HC + c + 3], v.w * coef);
}

// ---------------- generic GEMM (vector fp32, unchanged this round) ----------------
__global__ __launch_bounds__(256)
void gemm_k(const float* __restrict__ X, const float* __restrict__ W,
            const float* __restrict__ bias1, const float* __restrict__ bias2,
            const float* __restrict__ res1, const float* __restrict__ res2, float res2scale,
            float* __restrict__ out, int K, int M, int dorelu)
{
    __shared__ float Xs[16][68];
    __shared__ float Ws[16][68];
    const int t = threadIdx.x;
    const int tx = t & 15, ty = t >> 4;
    const int row0 = blockIdx.y << 6, col0 = blockIdx.x << 6;
    const int lr = t >> 2, lc4 = (t & 3) << 2;
    float acc[4][4] = {};
    for (int k0 = 0; k0 < K; k0 += 16) {
        float4 xu = *(const float4*)&X[(row0 + lr) * K + k0 + lc4];
        float4 wu = *(const float4*)&W[(col0 + lr) * K + k0 + lc4];
        __syncthreads();
        Xs[lc4 + 0][lr] = xu.x;
        Xs[lc4 + 1][lr] = xu.y;
        Xs[lc4 + 2][lr] = xu.z;
        Xs[lc4 + 3][lr] = xu.w;
        Ws[lc4 + 0][lr] = wu.x;
        Ws[lc4 + 1][lr] = wu.y;
        Ws[lc4 + 2][lr] = wu.z;
        Ws[lc4 + 3][lr] = wu.w;
        __syncthreads();
        #pragma unroll
        for (int kk = 0; kk < 16; kk++) {
            float4 a4 = *(const float4*)&Xs[kk][ty << 2];
            float4 b4 = *(const float4*)&Ws[kk][tx << 2];
            float a[4] = {a4.x, a4.y, a4.z, a4.w};
            float b[4] = {b4.x, b4.y, b4.z, b4.w};
            #pragma unroll
            for (int i = 0; i < 4; i++)
                #pragma unroll
                for (int j = 0; j < 4; j++)
                    acc[i][j] += a[i] * b[j];
        }
    }
    #pragma unroll
    for (int i = 0; i < 4; i++) {
        int row = row0 + (ty << 2) + i;
        int cb = col0 + (tx << 2);
        float v[4] = {acc[i][0], acc[i][1], acc[i][2], acc[i][3]};
        if (bias1) {
            #pragma unroll
            for (int j = 0; j < 4; j++) v[j] += bias1[cb + j];
        }
        if (bias2) {
            #pragma unroll
            for (int j = 0; j < 4; j++) v[j] += bias2[cb + j];
        }
        if (res1) {
            float4 r = *(const float4*)&res1[row * M + cb];
            v[0] += r.x; v[1] += r.y; v[2] += r.z; v[3] += r.w;
        }
        if (res2) {
            float4 r = *(const float4*)&res2[row * M + cb];
            v[0] += res2scale * r.x; v[1] += res2scale * r.y;
            v[2] += res2scale * r.z; v[3] += res2scale * r.w;
        }
        if (dorelu) {
            #pragma unroll
            for (int j = 0; j < 4; j++) v[j] = fmaxf(v[j], 0.f);
        }
        *(float4*)&out[row * M + cb] = make_float4(v[0], v[1], v[2], v[3]);
    }
}

// ---------------- K/V bf16 prep: Kb[h][n][d], Vtb[h][d][n] ----------------
__global__ __launch_bounds__(256)
void kv_prep_k(const float* __restrict__ qkv, ushort_t* __restrict__ Kb,
               ushort_t* __restrict__ Vtb)
{
    __shared__ ushort_t Vs[64][72];
    const int h = blockIdx.y;
    const int n0 = blockIdx.x << 6;
    const int t = threadIdx.x;
    for (int u = t; u < 1024; u += 256) {
        int r = u >> 4, c = u & 15;   // row r, floats c*4..+4
        const float* kp = &qkv[(size_t)(n0 + r) * 768 + 256 + h * 64 + c * 4];
        float4 kv = *(const float4*)kp;
        float4 vv = *(const float4*)(kp + 256);
        ushort4 kb;
        kb.x = f2bf(kv.x); kb.y = f2bf(kv.y); kb.z = f2bf(kv.z); kb.w = f2bf(kv.w);
        *(ushort4*)&Kb[((size_t)(h * 4096 + n0 + r)) * 64 + c * 4] = kb;
        ushort4 vb;
        vb.x = f2bf(vv.x); vb.y = f2bf(vv.y); vb.z = f2bf(vv.z); vb.w = f2bf(vv.w);
        *(ushort4*)&Vs[r][c * 4] = vb;
    }
    __syncthreads();
    // transposed write: thread -> (dim d, key-chunk kc of 16)
    int d = t >> 2, kc = t & 3;
    __attribute__((aligned(16))) ushort_t vals[16];
    #pragma unroll
    for (int k = 0; k < 16; k++) vals[k] = Vs[kc * 16 + k][d];
    ushort_t* op = &Vtb[((size_t)(h * 64 + d)) * 4096 + n0 + kc * 16];
    *(uint4*)op = *(const uint4*)&vals[0];
    *(uint4*)(op + 8) = *(const uint4*)&vals[8];
}

// ---------------- MFMA flash attention: block = (64 queries, 1 head), 4 waves ----------------
__global__ __launch_bounds__(256)
void attn_mfma_k(const float* __restrict__ qkv, const ushort_t* __restrict__ Kb,
                 const ushort_t* __restrict__ Vtb, float* __restrict__ att)
{
    __shared__ ushort_t Kt[64][72];   // [key][dim], pad->36 dwords/row
    __shared__ ushort_t Vt[64][72];   // [dim][key]
    __shared__ float Pl[4][16][68];   // per-wave P scratch [qrow][key]
    const int h = blockIdx.y;
    const int q0 = blockIdx.x << 6;
    const int t = threadIdx.x;
    const int w = t >> 6, lane = t & 63;
    const int m = lane & 15, quad = lane >> 4;

    // Q fragments (A-layout: row=m, k=quad*8+j), prescaled by 0.125 (exact in bf16)
    bf16x8 qf[2];
    #pragma unroll
    for (int kc = 0; kc < 2; kc++) {
        const float* qp = &qkv[(size_t)(q0 + w * 16 + m) * 768 + h * 64 + kc * 32 + quad * 8];
        float4 a = *(const float4*)qp;
        float4 b = *(const float4*)(qp + 4);
        qf[kc][0] = (short)f2bf(a.x * 0.125f);
        qf[kc][1] = (short)f2bf(a.y * 0.125f);
        qf[kc][2] = (short)f2bf(a.z * 0.125f);
        qf[kc][3] = (short)f2bf(a.w * 0.125f);
        qf[kc][4] = (short)f2bf(b.x * 0.125f);
        qf[kc][5] = (short)f2bf(b.y * 0.125f);
        qf[kc][6] = (short)f2bf(b.z * 0.125f);
        qf[kc][7] = (short)f2bf(b.w * 0.125f);
    }

    f32x4 o[4];
    float mrow[4], lrow[4];
    #pragma unroll
    for (int i = 0; i < 4; i++) {
        o[i] = (f32x4){0.f, 0.f, 0.f, 0.f};
        mrow[i] = -1e30f; lrow[i] = 0.f;
    }

    for (int kb = 0; kb < 64; kb++) {
        __syncthreads();   // previous tile fully consumed
        for (int u = t; u < 512; u += 256) {
            int r = u >> 3, c = u & 7;   // 16B chunks
            *(uint4*)&Kt[r][c * 8] = *(const uint4*)&Kb[((size_t)(h * 4096 + kb * 64 + r)) * 64 + c * 8];
            *(uint4*)&Vt[r][c * 8] = *(const uint4*)&Vtb[((size_t)(h * 64 + r)) * 4096 + kb * 64 + c * 8];
        }
        __syncthreads();

        // S = Q K^T : rows=q (quad*4+reg), cols=key (b*16+m)
        f32x4 s[4];
        #pragma unroll
        for (int b = 0; b < 4; b++) s[b] = (f32x4){0.f, 0.f, 0.f, 0.f};
        #pragma unroll
        for (int b = 0; b < 4; b++)
            #pragma unroll
            for (int kc = 0; kc < 2; kc++) {
                bf16x8 kf = *(const bf16x8*)&Kt[b * 16 + m][kc * 32 + quad * 8];
                s[b] = __builtin_amdgcn_mfma_f32_16x16x32_bf16(qf[kc], kf, s[b], 0, 0, 0);
            }

        // online softmax (per C-row r, reduce across 16 lanes of the quad)
        float alpha[4];
        #pragma unroll
        for (int r = 0; r < 4; r++) {
            float mx = fmaxf(fmaxf(s[0][r], s[1][r]), fmaxf(s[2][r], s[3][r]));
            #pragma unroll
            for (int off = 1; off < 16; off <<= 1)
                mx = fmaxf(mx, __shfl_xor(mx, off));
            float mn = fmaxf(mrow[r], mx);
            alpha[r] = __expf(mrow[r] - mn);
            mrow[r] = mn;
            float rs = 0.f;
            #pragma unroll
            for (int b = 0; b < 4; b++) {
                float p = __expf(s[b][r] - mn);
                Pl[w][quad * 4 + r][b * 16 + m] = p;
                rs += p;
            }
            #pragma unroll
            for (int off = 1; off < 16; off <<= 1)
                rs += __shfl_xor(rs, off);
            lrow[r] = lrow[r] * alpha[r] + rs;
            o[0][r] *= alpha[r]; o[1][r] *= alpha[r];
            o[2][r] *= alpha[r]; o[3][r] *= alpha[r];
        }

        // PV: P (A-layout via LDS round-trip) x V (B-layout from transposed tile)
        #pragma unroll
        for (int kc = 0; kc < 2; kc++) {
            float4 p0 = *(const float4*)&Pl[w][m][kc * 32 + quad * 8];
            float4 p1 = *(const float4*)&Pl[w][m][kc * 32 + quad * 8 + 4];
            bf16x8 pa;
            pa[0] = (short)f2bf(p0.x); pa[1] = (short)f2bf(p0.y);
            pa[2] = (short)f2bf(p0.z); pa[3] = (short)f2bf(p0.w);
            pa[4] = (short)f2bf(p1.x); pa[5] = (short)f2bf(p1.y);
            pa[6] = (short)f2bf(p1.z); pa[7] = (short)f2bf(p1.w);
            #pragma unroll
            for (int nb = 0; nb < 4; nb++) {
                bf16x8 vf = *(const bf16x8*)&Vt[nb * 16 + m][kc * 32 + quad * 8];
                o[nb] = __builtin_amdgcn_mfma_f32_16x16x32_bf16(pa, vf, o[nb], 0, 0, 0);
            }
        }
    }

    #pragma unroll
    for (int nb = 0; nb < 4; nb++)
        #pragma unroll
        for (int r = 0; r < 4; r++) {
            int q = q0 + w * 16 + quad * 4 + r;
            att[(size_t)q * 256 + h * 64 + nb * 16 + m] = o[nb][r] / lrow[r];
        }
}

// ---------------- symmetrized final MLP (unchanged) ----------------
__global__ __launch_bounds__(256)
void sym_mlp_k(const float* __restrict__ T, const float* __restrict__ W2,
               const float* __restrict__ b2, float* __restrict__ out)
{
    const int bi = blockIdx.y, bj = blockIdx.x;
    if (bi > bj) return;
    __shared__ float Ti[16][68], Tj[16][68], Wi[16][68], Wj[16][68];
    const int t = threadIdx.x;
    const int tx = t & 15, ty = t >> 4;
    const int lr = t >> 2, lc4 = (t & 3) << 2;
    const int ri = bi << 6, rj = bj << 6;
    float d1[4][4] = {}, d2[4][4] = {};
    for (int k0 = 0; k0 < 256; k0 += 16) {
        float4 ta = *(const float4*)&T[(ri + lr) * 256 + k0 + lc4];
        float4 tb = *(const float4*)&T[(rj + lr) * 256 + k0 + lc4];
        float4 wa = *(const float4*)&W2[(ri + lr) * 256 + k0 + lc4];
        float4 wb = *(const float4*)&W2[(rj + lr) * 256 + k0 + lc4];
        __syncthreads();
        Ti[lc4 + 0][lr] = ta.x; Ti[lc4 + 1][lr] = ta.y; Ti[lc4 + 2][lr] = ta.z; Ti[lc4 + 3][lr] = ta.w;
        Tj[lc4 + 0][lr] = tb.x; Tj[lc4 + 1][lr] = tb.y; Tj[lc4 + 2][lr] = tb.z; Tj[lc4 + 3][lr] = tb.w;
        Wi[lc4 + 0][lr] = wa.x; Wi[lc4 + 1][lr] = wa.y; Wi[lc4 + 2][lr] = wa.z; Wi[lc4 + 3][lr] = wa.w;
        Wj[lc4 + 0][lr] = wb.x; Wj[lc4 + 1][lr] = wb.y; Wj[lc4 + 2][lr] = wb.z; Wj[lc4 + 3][lr] = wb.w;
        __syncthreads();
        #pragma unroll
        for (int kk = 0; kk < 16; kk++) {
            float4 a1 = *(const float4*)&Ti[kk][ty << 2];
            float4 b1 = *(const float4*)&Wj[kk][tx << 2];
            float4 a2 = *(const float4*)&Wi[kk][ty << 2];
            float4 bb = *(const float4*)&Tj[kk][tx << 2];
            float A1[4] = {a1.x, a1.y, a1.z, a1.w};
            float B1[4] = {b1.x, b1.y, b1.z, b1.w};
            float A2[4] = {a2.x, a2.y, a2.z, a2.w};
            float B2[4] = {bb.x, bb.y, bb.z, bb.w};
            #pragma unroll
            for (int i = 0; i < 4; i++)
                #pragma unroll
                for (int j = 0; j < 4; j++) {
                    d1[i][j] += A1[i] * B1[j];
                    d2[i][j] += A2[i] * B2[j];
                }
        }
    }
    #pragma unroll
    for (int i = 0; i < 4; i++) {
        int row = ri + (ty << 2) + i;
        float brow = b2[row];
        #pragma unroll
        for (int j = 0; j < 4; j++) {
            int col = rj + (tx << 2) + j;
            float v = 0.5f * (d1[i][j] + d2[i][j] + b2[col] + brow);
            out[row * NN + col] = v;
            out[col * NN + row] = v;
        }
    }
}

// ---------------- launch ----------------
extern "C" void kernel_launch(void* const* d_in, const int* in_sizes, int n_in,
                              void* d_out, int out_size, void* d_ws, size_t ws_size,
                              hipStream_t stream) {
    (void)in_sizes; (void)n_in; (void)out_size; (void)ws_size;
    const float* x = (const float*)d_in[0];
    const int* ei = (const int*)d_in[1];
    const int* src = ei;
    const int* dst = ei + EE;

    float* ws = (float*)d_ws;
    const int NH = NN * HC;          // 1,048,576 floats
    float* h0  = ws;                 // current h
    float* hb  = ws + 1 * NH;        // gcn agg
    float* hc  = ws + 2 * NH;        // "out"  (region doubles as bf16 K/Vt during attention)
    float* att = ws + 3 * NH;        // xw / attention out / mlp hidden (reused)
    float* qkv = ws + 4 * NH;        // N x 768 ; FFN hidden reuses this region later
    float* ffh = ws + 4 * NH;        // N x 512 (qkv dead by then)
    float* deg = ws + 7 * NH;
    float* dinv = deg + NN;
    ushort_t* Kb  = (ushort_t*)hc;        // [4][4096][64] bf16  (2 MB)
    ushort_t* Vtb = Kb + NH;              // [4][64][4096] bf16  (2 MB)  -> exactly fills hc

    deg_init_k<<<NN / 256, 256, 0, stream>>>(deg);
    deg_scatter_k<<<EE / 256, 256, 0, stream>>>(dst, deg);
    dinv_k<<<NN / 256, 256, 0, stream>>>(deg, dinv);

    // pre: h0 = relu(x @ pre_w^T + pre_b)
    gemm_k<<<dim3(4, 64), 256, 0, stream>>>(
        x, (const float*)d_in[2], (const float*)d_in[3], nullptr,
        nullptr, nullptr, 0.f, h0, 128, 256, 1);

    for (int L = 0; L < 2; L++) {
        int B = 4 + L * 10;
        const float* gw = (const float*)d_in[B + 0];
        const float* gb = (const float*)d_in[B + 1];
        const float* iw = (const float*)d_in[B + 2];
        const float* ib = (const float*)d_in[B + 3];
        const float* ow = (const float*)d_in[B + 4];
        const float* ob = (const float*)d_in[B + 5];
        const float* w1 = (const float*)d_in[B + 6];
        const float* b1 = (const float*)d_in[B + 7];
        const float* w2 = (const float*)d_in[B + 8];
        const float* b2 = (const float*)d_in[B + 9];

        // xw = h0 @ gcn_w^T   (into att buffer)
        gemm_k<<<dim3(4, 64), 256, 0, stream>>>(
            h0, gw, nullptr, nullptr, nullptr, nullptr, 0.f, att, 256, 256, 0);
        agg_init_k<<<NH / 256, 256, 0, stream>>>(att, dinv, hb);
        edge_scatter_k<<<EE * 64 / 256, 256, 0, stream>>>(src, dst, att, dinv, hb);
        // qkv = h0 @ in_w^T + in_b
        gemm_k<<<dim3(12, 64), 256, 0, stream>>>(
            h0, iw, ib, nullptr, nullptr, nullptr, 0.f, qkv, 256, 768, 0);
        // bf16 K / V^T prep, then MFMA flash attention -> att
        kv_prep_k<<<dim3(64, 4), 256, 0, stream>>>(qkv, Kb, Vtb);
        attn_mfma_k<<<dim3(64, 4), 256, 0, stream>>>(qkv, Kb, Vtb, att);
        // out = att @ out_w^T + ob + gb + hb + 2*h0   -> hc  (overwrites Kb/Vtb: dead)
        gemm_k<<<dim3(4, 64), 256, 0, stream>>>(
            att, ow, ob, gb, hb, h0, 2.0f, hc, 256, 256, 0);
        // ffh = relu(hc @ w1^T + b1)
        gemm_k<<<dim3(8, 64), 256, 0, stream>>>(
            hc, w1, b1, nullptr, nullptr, nullptr, 0.f, ffh, 256, 512, 1);
        // h0 = relu(ffh @ w2^T + b2 + hc)
        gemm_k<<<dim3(4, 64), 256, 0, stream>>>(
            ffh, w2, b2, nullptr, hc, nullptr, 0.f, h0, 512, 256, 1);
    }

    // t = relu(h0 @ mlp_w1^T + mlp_b1)  (into att buffer)
    gemm_k<<<dim3(4, 64), 256, 0, stream>>>(
        h0, (const float*)d_in[24], (const float*)d_in[25], nullptr,
        nullptr, nullptr, 0.f, att, 256, 256, 1);
    // out = 0.5*(delta + delta^T)
    sym_mlp_k<<<dim3(64, 64), 256, 0, stream>>>(
        att, (const float*)d_in[26], (const float*)d_in[27], (float*)d_out);
}

// Round 5
// 1126.967 us; speedup vs baseline: 2.0929x; 1.1670x over previous
//
#include <hip/hip_runtime.h>

#define NN 4096
#define EE 65536
#define HC 256   // hidden channels

typedef unsigned short ushort_t;
typedef __attribute__((ext_vector_type(8))) short bf16x8;
typedef __attribute__((ext_vector_type(4))) float f32x4;

__device__ __forceinline__ ushort_t f2bf(float f) {
    unsigned int u = __float_as_uint(f);
    unsigned int r = (u + 0x7fffu + ((u >> 16) & 1u)) >> 16;
    return (ushort_t)r;
}

// ---------------- degree / GCN scatter ----------------
__global__ void deg_init_k(float* __restrict__ deg) {
    int i = blockIdx.x * 256 + threadIdx.x;
    deg[i] = 1.0f;  // self loop
}
__global__ void deg_scatter_k(const int* __restrict__ dst, float* __restrict__ deg) {
    int e = blockIdx.x * 256 + threadIdx.x;
    atomicAdd(&deg[dst[e]], 1.0f);
}
__global__ void dinv_k(const float* __restrict__ deg, float* __restrict__ dinv) {
    int i = blockIdx.x * 256 + threadIdx.x;
    dinv[i] = rsqrtf(deg[i]);
}
__global__ void agg_init_k(const float* __restrict__ xw, const float* __restrict__ dinv,
                           float* __restrict__ agg) {
    int idx = blockIdx.x * 256 + threadIdx.x;
    int i = idx >> 8;
    float di = dinv[i];
    agg[idx] = xw[idx] * di * di;
}
__global__ void edge_scatter_k(const int* __restrict__ src, const int* __restrict__ dst,
                               const float* __restrict__ xw, const float* __restrict__ dinv,
                               float* __restrict__ agg) {
    int idx = blockIdx.x * 256 + threadIdx.x;
    int e = idx >> 6;
    int c = (idx & 63) << 2;
    int s = src[e], d = dst[e];
    float coef = dinv[s] * dinv[d];
    const float4 v = *(const float4*)&xw[s * HC + c];
    atomicAdd(&agg[d * HC + c + 0], v.x * coef);
    atomicAdd(&agg[d * HC + c + 1], v.y * coef);
    atomicAdd(&agg[d * HC + c + 2], v.z * coef);
    atomicAdd(&agg[d * HC + c + 3], v.w * coef);
}

// ---------------- fp32 -> bf16 convert (float4 -> ushort4) ----------------
__global__ void cvt_bf16_k(const float* __restrict__ in, ushort_t* __restrict__ out) {
    int i = (blockIdx.x * 256 + threadIdx.x) * 4;
    float4 v = *(const float4*)&in[i];
    ushort4 o;
    o.x = f2bf(v.x); o.y = f2bf(v.y); o.z = f2bf(v.z); o.w = f2bf(v.w);
    *(ushort4*)&out[i] = o;
}

// ---------------- generic GEMM (vector fp32; optional bf16 output) ----------------
__global__ __launch_bounds__(256)
void gemm_k(const float* __restrict__ X, const float* __restrict__ W,
            const float* __restrict__ bias1, const float* __restrict__ bias2,
            const float* __restrict__ res1, const float* __restrict__ res2, float res2scale,
            float* __restrict__ out, int K, int M, int dorelu, int obf)
{
    __shared__ float Xs[16][68];
    __shared__ float Ws[16][68];
    const int t = threadIdx.x;
    const int tx = t & 15, ty = t >> 4;
    const int row0 = blockIdx.y << 6, col0 = blockIdx.x << 6;
    const int lr = t >> 2, lc4 = (t & 3) << 2;
    float acc[4][4] = {};
    for (int k0 = 0; k0 < K; k0 += 16) {
        float4 xu = *(const float4*)&X[(row0 + lr) * K + k0 + lc4];
        float4 wu = *(const float4*)&W[(col0 + lr) * K + k0 + lc4];
        __syncthreads();
        Xs[lc4 + 0][lr] = xu.x;
        Xs[lc4 + 1][lr] = xu.y;
        Xs[lc4 + 2][lr] = xu.z;
        Xs[lc4 + 3][lr] = xu.w;
        Ws[lc4 + 0][lr] = wu.x;
        Ws[lc4 + 1][lr] = wu.y;
        Ws[lc4 + 2][lr] = wu.z;
        Ws[lc4 + 3][lr] = wu.w;
        __syncthreads();
        #pragma unroll
        for (int kk = 0; kk < 16; kk++) {
            float4 a4 = *(const float4*)&Xs[kk][ty << 2];
            float4 b4 = *(const float4*)&Ws[kk][tx << 2];
            float a[4] = {a4.x, a4.y, a4.z, a4.w};
            float b[4] = {b4.x, b4.y, b4.z, b4.w};
            #pragma unroll
            for (int i = 0; i < 4; i++)
                #pragma unroll
                for (int j = 0; j < 4; j++)
                    acc[i][j] += a[i] * b[j];
        }
    }
    #pragma unroll
    for (int i = 0; i < 4; i++) {
        int row = row0 + (ty << 2) + i;
        int cb = col0 + (tx << 2);
        float v[4] = {acc[i][0], acc[i][1], acc[i][2], acc[i][3]};
        if (bias1) {
            #pragma unroll
            for (int j = 0; j < 4; j++) v[j] += bias1[cb + j];
        }
        if (bias2) {
            #pragma unroll
            for (int j = 0; j < 4; j++) v[j] += bias2[cb + j];
        }
        if (res1) {
            float4 r = *(const float4*)&res1[row * M + cb];
            v[0] += r.x; v[1] += r.y; v[2] += r.z; v[3] += r.w;
        }
        if (res2) {
            float4 r = *(const float4*)&res2[row * M + cb];
            v[0] += res2scale * r.x; v[1] += res2scale * r.y;
            v[2] += res2scale * r.z; v[3] += res2scale * r.w;
        }
        if (dorelu) {
            #pragma unroll
            for (int j = 0; j < 4; j++) v[j] = fmaxf(v[j], 0.f);
        }
        if (obf) {
            ushort4 o;
            o.x = f2bf(v[0]); o.y = f2bf(v[1]); o.z = f2bf(v[2]); o.w = f2bf(v[3]);
            *(ushort4*)&((ushort_t*)out)[row * M + cb] = o;
        } else {
            *(float4*)&out[row * M + cb] = make_float4(v[0], v[1], v[2], v[3]);
        }
    }
}

// ---------------- K/V bf16 prep: Kb[h][n][d], Vtb[h][d][n] ----------------
__global__ __launch_bounds__(256)
void kv_prep_k(const float* __restrict__ qkv, ushort_t* __restrict__ Kb,
               ushort_t* __restrict__ Vtb)
{
    __shared__ ushort_t Vs[64][72];
    const int h = blockIdx.y;
    const int n0 = blockIdx.x << 6;
    const int t = threadIdx.x;
    for (int u = t; u < 1024; u += 256) {
        int r = u >> 4, c = u & 15;
        const float* kp = &qkv[(size_t)(n0 + r) * 768 + 256 + h * 64 + c * 4];
        float4 kv = *(const float4*)kp;
        float4 vv = *(const float4*)(kp + 256);
        ushort4 kb;
        kb.x = f2bf(kv.x); kb.y = f2bf(kv.y); kb.z = f2bf(kv.z); kb.w = f2bf(kv.w);
        *(ushort4*)&Kb[((size_t)(h * 4096 + n0 + r)) * 64 + c * 4] = kb;
        ushort4 vb;
        vb.x = f2bf(vv.x); vb.y = f2bf(vv.y); vb.z = f2bf(vv.z); vb.w = f2bf(vv.w);
        *(ushort4*)&Vs[r][c * 4] = vb;
    }
    __syncthreads();
    int d = t >> 2, kc = t & 3;
    __attribute__((aligned(16))) ushort_t vals[16];
    #pragma unroll
    for (int k = 0; k < 16; k++) vals[k] = Vs[kc * 16 + k][d];
    ushort_t* op = &Vtb[((size_t)(h * 64 + d)) * 4096 + n0 + kc * 16];
    *(uint4*)op = *(const uint4*)&vals[0];
    *(uint4*)(op + 8) = *(const uint4*)&vals[8];
}

// ---------------- MFMA flash attention (unchanged) ----------------
__global__ __launch_bounds__(256)
void attn_mfma_k(const float* __restrict__ qkv, const ushort_t* __restrict__ Kb,
                 const ushort_t* __restrict__ Vtb, float* __restrict__ att)
{
    __shared__ ushort_t Kt[64][72];
    __shared__ ushort_t Vt[64][72];
    __shared__ float Pl[4][16][68];
    const int h = blockIdx.y;
    const int q0 = blockIdx.x << 6;
    const int t = threadIdx.x;
    const int w = t >> 6, lane = t & 63;
    const int m = lane & 15, quad = lane >> 4;

    bf16x8 qf[2];
    #pragma unroll
    for (int kc = 0; kc < 2; kc++) {
        const float* qp = &qkv[(size_t)(q0 + w * 16 + m) * 768 + h * 64 + kc * 32 + quad * 8];
        float4 a = *(const float4*)qp;
        float4 b = *(const float4*)(qp + 4);
        qf[kc][0] = (short)f2bf(a.x * 0.125f);
        qf[kc][1] = (short)f2bf(a.y * 0.125f);
        qf[kc][2] = (short)f2bf(a.z * 0.125f);
        qf[kc][3] = (short)f2bf(a.w * 0.125f);
        qf[kc][4] = (short)f2bf(b.x * 0.125f);
        qf[kc][5] = (short)f2bf(b.y * 0.125f);
        qf[kc][6] = (short)f2bf(b.z * 0.125f);
        qf[kc][7] = (short)f2bf(b.w * 0.125f);
    }

    f32x4 o[4];
    float mrow[4], lrow[4];
    #pragma unroll
    for (int i = 0; i < 4; i++) {
        o[i] = (f32x4){0.f, 0.f, 0.f, 0.f};
        mrow[i] = -1e30f; lrow[i] = 0.f;
    }

    for (int kb = 0; kb < 64; kb++) {
        __syncthreads();
        for (int u = t; u < 512; u += 256) {
            int r = u >> 3, c = u & 7;
            *(uint4*)&Kt[r][c * 8] = *(const uint4*)&Kb[((size_t)(h * 4096 + kb * 64 + r)) * 64 + c * 8];
            *(uint4*)&Vt[r][c * 8] = *(const uint4*)&Vtb[((size_t)(h * 64 + r)) * 4096 + kb * 64 + c * 8];
        }
        __syncthreads();

        f32x4 s[4];
        #pragma unroll
        for (int b = 0; b < 4; b++) s[b] = (f32x4){0.f, 0.f, 0.f, 0.f};
        #pragma unroll
        for (int b = 0; b < 4; b++)
            #pragma unroll
            for (int kc = 0; kc < 2; kc++) {
                bf16x8 kf = *(const bf16x8*)&Kt[b * 16 + m][kc * 32 + quad * 8];
                s[b] = __builtin_amdgcn_mfma_f32_16x16x32_bf16(qf[kc], kf, s[b], 0, 0, 0);
            }

        float alpha[4];
        #pragma unroll
        for (int r = 0; r < 4; r++) {
            float mx = fmaxf(fmaxf(s[0][r], s[1][r]), fmaxf(s[2][r], s[3][r]));
            #pragma unroll
            for (int off = 1; off < 16; off <<= 1)
                mx = fmaxf(mx, __shfl_xor(mx, off));
            float mn = fmaxf(mrow[r], mx);
            alpha[r] = __expf(mrow[r] - mn);
            mrow[r] = mn;
            float rs = 0.f;
            #pragma unroll
            for (int b = 0; b < 4; b++) {
                float p = __expf(s[b][r] - mn);
                Pl[w][quad * 4 + r][b * 16 + m] = p;
                rs += p;
            }
            #pragma unroll
            for (int off = 1; off < 16; off <<= 1)
                rs += __shfl_xor(rs, off);
            lrow[r] = lrow[r] * alpha[r] + rs;
            o[0][r] *= alpha[r]; o[1][r] *= alpha[r];
            o[2][r] *= alpha[r]; o[3][r] *= alpha[r];
        }

        #pragma unroll
        for (int kc = 0; kc < 2; kc++) {
            float4 p0 = *(const float4*)&Pl[w][m][kc * 32 + quad * 8];
            float4 p1 = *(const float4*)&Pl[w][m][kc * 32 + quad * 8 + 4];
            bf16x8 pa;
            pa[0] = (short)f2bf(p0.x); pa[1] = (short)f2bf(p0.y);
            pa[2] = (short)f2bf(p0.z); pa[3] = (short)f2bf(p0.w);
            pa[4] = (short)f2bf(p1.x); pa[5] = (short)f2bf(p1.y);
            pa[6] = (short)f2bf(p1.z); pa[7] = (short)f2bf(p1.w);
            #pragma unroll
            for (int nb = 0; nb < 4; nb++) {
                bf16x8 vf = *(const bf16x8*)&Vt[nb * 16 + m][kc * 32 + quad * 8];
                o[nb] = __builtin_amdgcn_mfma_f32_16x16x32_bf16(pa, vf, o[nb], 0, 0, 0);
            }
        }
    }

    #pragma unroll
    for (int nb = 0; nb < 4; nb++)
        #pragma unroll
        for (int r = 0; r < 4; r++) {
            int q = q0 + w * 16 + quad * 4 + r;
            att[(size_t)q * 256 + h * 64 + nb * 16 + m] = o[nb][r] / lrow[r];
        }
}

// ---------------- symmetrized final MLP, MFMA bf16 ----------------
// out[r][c] = 0.5*(T_r.W_c + W_r.T_c + b2[r] + b2[c])  == K=512 GEMM with A=[T|W], B=[W|T]
__global__ __launch_bounds__(256)
void sym_mlp_mfma_k(const ushort_t* __restrict__ Tb, const ushort_t* __restrict__ Wb,
                    const float* __restrict__ b2, float* __restrict__ out)
{
    __shared__ ushort_t As[128][72];   // 36-dword row stride -> conflict-free b128 frag reads
    __shared__ ushort_t Bs[128][72];
    const int t = threadIdx.x;
    const int w = t >> 6, lane = t & 63;
    const int m = lane & 15, quad = lane >> 4;
    const int wr = (w >> 1) * 64, wc = (w & 1) * 64;
    const int ri = blockIdx.y * 128, rj = blockIdx.x * 128;

    f32x4 acc[4][4] = {};
    for (int kk = 0; kk < 8; kk++) {
        const int k0 = kk * 64;
        const ushort_t* Asrc = (k0 < 256) ? Tb : Wb;
        const ushort_t* Bsrc = (k0 < 256) ? Wb : Tb;
        const int kcol = k0 & 255;
        __syncthreads();
        #pragma unroll
        for (int i = 0; i < 4; i++) {
            int s = t + i * 256;
            int row = s >> 3, ch = (s & 7) * 8;   // full 128 x 64 tile
            *(uint4*)&As[row][ch] = *(const uint4*)&Asrc[(size_t)(ri + row) * 256 + kcol + ch];
            *(uint4*)&Bs[row][ch] = *(const uint4*)&Bsrc[(size_t)(rj + row) * 256 + kcol + ch];
        }
        __syncthreads();
        #pragma unroll
        for (int kc = 0; kc < 2; kc++) {
            bf16x8 af[4], bfr[4];
            #pragma unroll
            for (int rb = 0; rb < 4; rb++)
                af[rb] = *(const bf16x8*)&As[wr + rb * 16 + m][kc * 32 + quad * 8];
            #pragma unroll
            for (int cb = 0; cb < 4; cb++)
                bfr[cb] = *(const bf16x8*)&Bs[wc + cb * 16 + m][kc * 32 + quad * 8];
            #pragma unroll
            for (int rb = 0; rb < 4; rb++)
                #pragma unroll
                for (int cb = 0; cb < 4; cb++)
                    acc[rb][cb] = __builtin_amdgcn_mfma_f32_16x16x32_bf16(af[rb], bfr[cb], acc[rb][cb], 0, 0, 0);
        }
    }
    #pragma unroll
    for (int rb = 0; rb < 4; rb++) {
        #pragma unroll
        for (int r = 0; r < 4; r++) {
            const int gr = ri + wr + rb * 16 + quad * 4 + r;
            const float br = b2[gr];
            #pragma unroll
            for (int cb = 0; cb < 4; cb++) {
                const int gc = rj + wc + cb * 16 + m;
                out[(size_t)gr * NN + gc] = 0.5f * (acc[rb][cb][r] + br + b2[gc]);
            }
        }
    }
}

// ---------------- launch ----------------
extern "C" void kernel_launch(void* const* d_in, const int* in_sizes, int n_in,
                              void* d_out, int out_size, void* d_ws, size_t ws_size,
                              hipStream_t stream) {
    (void)in_sizes; (void)n_in; (void)out_size; (void)ws_size;
    const float* x = (const float*)d_in[0];
    const int* ei = (const int*)d_in[1];
    const int* src = ei;
    const int* dst = ei + EE;

    float* ws = (float*)d_ws;
    const int NH = NN * HC;          // 1,048,576 floats
    float* h0  = ws;                 // current h
    float* hb  = ws + 1 * NH;        // gcn agg; after last use doubles as Tb/W2b (bf16)
    float* hc  = ws + 2 * NH;        // "out"  (doubles as bf16 K/Vt during attention)
    float* att = ws + 3 * NH;        // xw / attention out (reused)
    float* qkv = ws + 4 * NH;        // N x 768 ; FFN hidden reuses this region later
    float* ffh = ws + 4 * NH;        // N x 512 (qkv dead by then)
    float* deg = ws + 7 * NH;
    float* dinv = deg + NN;
    ushort_t* Kb  = (ushort_t*)hc;   // [4][4096][64] bf16
    ushort_t* Vtb = Kb + NH;         // [4][64][4096] bf16
    ushort_t* Tb  = (ushort_t*)hb;   // [4096][256] bf16  (after hb dead)
    ushort_t* W2b = Tb + NH;         // [4096][256] bf16

    deg_init_k<<<NN / 256, 256, 0, stream>>>(deg);
    deg_scatter_k<<<EE / 256, 256, 0, stream>>>(dst, deg);
    dinv_k<<<NN / 256, 256, 0, stream>>>(deg, dinv);

    // pre: h0 = relu(x @ pre_w^T + pre_b)
    gemm_k<<<dim3(4, 64), 256, 0, stream>>>(
        x, (const float*)d_in[2], (const float*)d_in[3], nullptr,
        nullptr, nullptr, 0.f, h0, 128, 256, 1, 0);

    for (int L = 0; L < 2; L++) {
        int B = 4 + L * 10;
        const float* gw = (const float*)d_in[B + 0];
        const float* gb = (const float*)d_in[B + 1];
        const float* iw = (const float*)d_in[B + 2];
        const float* ib = (const float*)d_in[B + 3];
        const float* ow = (const float*)d_in[B + 4];
        const float* ob = (const float*)d_in[B + 5];
        const float* w1 = (const float*)d_in[B + 6];
        const float* b1 = (const float*)d_in[B + 7];
        const float* w2 = (const float*)d_in[B + 8];
        const float* b2 = (const float*)d_in[B + 9];

        gemm_k<<<dim3(4, 64), 256, 0, stream>>>(
            h0, gw, nullptr, nullptr, nullptr, nullptr, 0.f, att, 256, 256, 0, 0);
        agg_init_k<<<NH / 256, 256, 0, stream>>>(att, dinv, hb);
        edge_scatter_k<<<EE * 64 / 256, 256, 0, stream>>>(src, dst, att, dinv, hb);
        gemm_k<<<dim3(12, 64), 256, 0, stream>>>(
            h0, iw, ib, nullptr, nullptr, nullptr, 0.f, qkv, 256, 768, 0, 0);
        kv_prep_k<<<dim3(64, 4), 256, 0, stream>>>(qkv, Kb, Vtb);
        attn_mfma_k<<<dim3(64, 4), 256, 0, stream>>>(qkv, Kb, Vtb, att);
        gemm_k<<<dim3(4, 64), 256, 0, stream>>>(
            att, ow, ob, gb, hb, h0, 2.0f, hc, 256, 256, 0, 0);
        gemm_k<<<dim3(8, 64), 256, 0, stream>>>(
            hc, w1, b1, nullptr, nullptr, nullptr, 0.f, ffh, 256, 512, 1, 0);
        gemm_k<<<dim3(4, 64), 256, 0, stream>>>(
            ffh, w2, b2, nullptr, hc, nullptr, 0.f, h0, 512, 256, 1, 0);
    }

    // Tb(bf16) = relu(h0 @ mlp_w1^T + mlp_b1)   (hb region is dead now)
    gemm_k<<<dim3(4, 64), 256, 0, stream>>>(
        h0, (const float*)d_in[24], (const float*)d_in[25], nullptr,
        nullptr, nullptr, 0.f, (float*)Tb, 256, 256, 1, 1);
    // W2b = bf16(mlp_w2)
    cvt_bf16_k<<<NH / 1024, 256, 0, stream>>>((const float*)d_in[26], W2b);
    // out = 0.5*(delta + delta^T) via K=512 concat GEMM
    sym_mlp_mfma_k<<<dim3(32, 32), 256, 0, stream>>>(
        Tb, W2b, (const float*)d_in[27], (float*)d_out);
}

// Round 6
// 735.067 us; speedup vs baseline: 3.2087x; 1.5331x over previous
//
#include <hip/hip_runtime.h>

#define NN 4096
#define EE 65536
#define HC 256   // hidden channels

typedef unsigned short ushort_t;
typedef __attribute__((ext_vector_type(8))) short bf16x8;
typedef __attribute__((ext_vector_type(4))) float f32x4;

__device__ __forceinline__ ushort_t f2bf(float f) {
    unsigned int u = __float_as_uint(f);
    unsigned int r = (u + 0x7fffu + ((u >> 16) & 1u)) >> 16;
    return (ushort_t)r;
}

// ---------------- degree / CSR build ----------------
__global__ void deg_init_k(float* __restrict__ deg) {
    int i = blockIdx.x * 256 + threadIdx.x;
    deg[i] = 1.0f;  // self loop
}
__global__ void deg_scatter_k(const int* __restrict__ dst, float* __restrict__ deg) {
    int e = blockIdx.x * 256 + threadIdx.x;
    atomicAdd(&deg[dst[e]], 1.0f);
}
__global__ void dinv_k(const float* __restrict__ deg, float* __restrict__ dinv) {
    int i = blockIdx.x * 256 + threadIdx.x;
    dinv[i] = rsqrtf(deg[i]);
}
// exclusive scan of in-degree counts (deg[i]-1), 4096 entries, single block
__global__ __launch_bounds__(1024)
void scan_offsets_k(const float* __restrict__ deg, int* __restrict__ offs,
                    int* __restrict__ cursor) {
    __shared__ int part[1024];
    const int t = threadIdx.x;
    int c0 = (int)deg[t * 4 + 0] - 1;
    int c1 = (int)deg[t * 4 + 1] - 1;
    int c2 = (int)deg[t * 4 + 2] - 1;
    int c3 = (int)deg[t * 4 + 3] - 1;
    part[t] = c0 + c1 + c2 + c3;
    __syncthreads();
    for (int off = 1; off < 1024; off <<= 1) {
        int v = (t >= off) ? part[t - off] : 0;
        __syncthreads();
        part[t] += v;
        __syncthreads();
    }
    int base = (t == 0) ? 0 : part[t - 1];
    offs[t * 4 + 0] = base;
    offs[t * 4 + 1] = base + c0;
    offs[t * 4 + 2] = base + c0 + c1;
    offs[t * 4 + 3] = base + c0 + c1 + c2;
    cursor[t * 4 + 0] = base;
    cursor[t * 4 + 1] = base + c0;
    cursor[t * 4 + 2] = base + c0 + c1;
    cursor[t * 4 + 3] = base + c0 + c1 + c2;
    if (t == 1023) offs[4096] = part[1023];
}
__global__ void csr_fill_k(const int* __restrict__ src, const int* __restrict__ dst,
                           int* __restrict__ cursor, int* __restrict__ csr_src) {
    int e = blockIdx.x * 256 + threadIdx.x;
    int pos = atomicAdd(&cursor[dst[e]], 1);
    csr_src[pos] = src[e];
}

// ---------------- GCN gather: 4 nodes/block, 64 lanes x float4 per node ----------------
__global__ __launch_bounds__(256)
void gcn_gather_k(const float* __restrict__ xw, const float* __restrict__ dinv,
                  const int* __restrict__ offs, const int* __restrict__ csr_src,
                  float* __restrict__ agg) {
    const int node = blockIdx.x * 4 + (threadIdx.x >> 6);
    const int c = (threadIdx.x & 63) * 4;
    const float dd = dinv[node];
    float4 a = *(const float4*)&xw[(size_t)node * HC + c];
    const float self = dd * dd;
    float4 acc = make_float4(a.x * self, a.y * self, a.z * self, a.w * self);
    const int beg = offs[node], end = offs[node + 1];
    for (int e = beg; e < end; e++) {
        int s = csr_src[e];
        float coef = dinv[s] * dd;
        const float4 v = *(const float4*)&xw[(size_t)s * HC + c];
        acc.x += v.x * coef;
        acc.y += v.y * coef;
        acc.z += v.z * coef;
        acc.w += v.w * coef;
    }
    *(float4*)&agg[(size_t)node * HC + c] = acc;
}

// ---------------- fp32 -> bf16 convert (float4 -> ushort4) ----------------
__global__ void cvt_bf16_k(const float* __restrict__ in, ushort_t* __restrict__ out) {
    int i = (blockIdx.x * 256 + threadIdx.x) * 4;
    float4 v = *(const float4*)&in[i];
    ushort4 o;
    o.x = f2bf(v.x); o.y = f2bf(v.y); o.z = f2bf(v.z); o.w = f2bf(v.w);
    *(ushort4*)&out[i] = o;
}

// ---------------- generic GEMM (vector fp32; optional bf16 output) ----------------
__global__ __launch_bounds__(256)
void gemm_k(const float* __restrict__ X, const float* __restrict__ W,
            const float* __restrict__ bias1, const float* __restrict__ bias2,
            const float* __restrict__ res1, const float* __restrict__ res2, float res2scale,
            float* __restrict__ out, int K, int M, int dorelu, int obf)
{
    __shared__ float Xs[16][68];
    __shared__ float Ws[16][68];
    const int t = threadIdx.x;
    const int tx = t & 15, ty = t >> 4;
    const int row0 = blockIdx.y << 6, col0 = blockIdx.x << 6;
    const int lr = t >> 2, lc4 = (t & 3) << 2;
    float acc[4][4] = {};
    for (int k0 = 0; k0 < K; k0 += 16) {
        float4 xu = *(const float4*)&X[(row0 + lr) * K + k0 + lc4];
        float4 wu = *(const float4*)&W[(col0 + lr) * K + k0 + lc4];
        __syncthreads();
        Xs[lc4 + 0][lr] = xu.x;
        Xs[lc4 + 1][lr] = xu.y;
        Xs[lc4 + 2][lr] = xu.z;
        Xs[lc4 + 3][lr] = xu.w;
        Ws[lc4 + 0][lr] = wu.x;
        Ws[lc4 + 1][lr] = wu.y;
        Ws[lc4 + 2][lr] = wu.z;
        Ws[lc4 + 3][lr] = wu.w;
        __syncthreads();
        #pragma unroll
        for (int kk = 0; kk < 16; kk++) {
            float4 a4 = *(const float4*)&Xs[kk][ty << 2];
            float4 b4 = *(const float4*)&Ws[kk][tx << 2];
            float a[4] = {a4.x, a4.y, a4.z, a4.w};
            float b[4] = {b4.x, b4.y, b4.z, b4.w};
            #pragma unroll
            for (int i = 0; i < 4; i++)
                #pragma unroll
                for (int j = 0; j < 4; j++)
                    acc[i][j] += a[i] * b[j];
        }
    }
    #pragma unroll
    for (int i = 0; i < 4; i++) {
        int row = row0 + (ty << 2) + i;
        int cb = col0 + (tx << 2);
        float v[4] = {acc[i][0], acc[i][1], acc[i][2], acc[i][3]};
        if (bias1) {
            #pragma unroll
            for (int j = 0; j < 4; j++) v[j] += bias1[cb + j];
        }
        if (bias2) {
            #pragma unroll
            for (int j = 0; j < 4; j++) v[j] += bias2[cb + j];
        }
        if (res1) {
            float4 r = *(const float4*)&res1[row * M + cb];
            v[0] += r.x; v[1] += r.y; v[2] += r.z; v[3] += r.w;
        }
        if (res2) {
            float4 r = *(const float4*)&res2[row * M + cb];
            v[0] += res2scale * r.x; v[1] += res2scale * r.y;
            v[2] += res2scale * r.z; v[3] += res2scale * r.w;
        }
        if (dorelu) {
            #pragma unroll
            for (int j = 0; j < 4; j++) v[j] = fmaxf(v[j], 0.f);
        }
        if (obf) {
            ushort4 o;
            o.x = f2bf(v[0]); o.y = f2bf(v[1]); o.z = f2bf(v[2]); o.w = f2bf(v[3]);
            *(ushort4*)&((ushort_t*)out)[row * M + cb] = o;
        } else {
            *(float4*)&out[row * M + cb] = make_float4(v[0], v[1], v[2], v[3]);
        }
    }
}

// ---------------- K/V bf16 prep: Kb[h][n][d], Vtb[h][d][n] ----------------
__global__ __launch_bounds__(256)
void kv_prep_k(const float* __restrict__ qkv, ushort_t* __restrict__ Kb,
               ushort_t* __restrict__ Vtb)
{
    __shared__ ushort_t Vs[64][72];
    const int h = blockIdx.y;
    const int n0 = blockIdx.x << 6;
    const int t = threadIdx.x;
    for (int u = t; u < 1024; u += 256) {
        int r = u >> 4, c = u & 15;
        const float* kp = &qkv[(size_t)(n0 + r) * 768 + 256 + h * 64 + c * 4];
        float4 kv = *(const float4*)kp;
        float4 vv = *(const float4*)(kp + 256);
        ushort4 kb;
        kb.x = f2bf(kv.x); kb.y = f2bf(kv.y); kb.z = f2bf(kv.z); kb.w = f2bf(kv.w);
        *(ushort4*)&Kb[((size_t)(h * 4096 + n0 + r)) * 64 + c * 4] = kb;
        ushort4 vb;
        vb.x = f2bf(vv.x); vb.y = f2bf(vv.y); vb.z = f2bf(vv.z); vb.w = f2bf(vv.w);
        *(ushort4*)&Vs[r][c * 4] = vb;
    }
    __syncthreads();
    int d = t >> 2, kc = t & 3;
    __attribute__((aligned(16))) ushort_t vals[16];
    #pragma unroll
    for (int k = 0; k < 16; k++) vals[k] = Vs[kc * 16 + k][d];
    ushort_t* op = &Vtb[((size_t)(h * 64 + d)) * 4096 + n0 + kc * 16];
    *(uint4*)op = *(const uint4*)&vals[0];
    *(uint4*)(op + 8) = *(const uint4*)&vals[8];
}

// ---------------- MFMA flash attention (unchanged) ----------------
__global__ __launch_bounds__(256)
void attn_mfma_k(const float* __restrict__ qkv, const ushort_t* __restrict__ Kb,
                 const ushort_t* __restrict__ Vtb, float* __restrict__ att)
{
    __shared__ ushort_t Kt[64][72];
    __shared__ ushort_t Vt[64][72];
    __shared__ float Pl[4][16][68];
    const int h = blockIdx.y;
    const int q0 = blockIdx.x << 6;
    const int t = threadIdx.x;
    const int w = t >> 6, lane = t & 63;
    const int m = lane & 15, quad = lane >> 4;

    bf16x8 qf[2];
    #pragma unroll
    for (int kc = 0; kc < 2; kc++) {
        const float* qp = &qkv[(size_t)(q0 + w * 16 + m) * 768 + h * 64 + kc * 32 + quad * 8];
        float4 a = *(const float4*)qp;
        float4 b = *(const float4*)(qp + 4);
        qf[kc][0] = (short)f2bf(a.x * 0.125f);
        qf[kc][1] = (short)f2bf(a.y * 0.125f);
        qf[kc][2] = (short)f2bf(a.z * 0.125f);
        qf[kc][3] = (short)f2bf(a.w * 0.125f);
        qf[kc][4] = (short)f2bf(b.x * 0.125f);
        qf[kc][5] = (short)f2bf(b.y * 0.125f);
        qf[kc][6] = (short)f2bf(b.z * 0.125f);
        qf[kc][7] = (short)f2bf(b.w * 0.125f);
    }

    f32x4 o[4];
    float mrow[4], lrow[4];
    #pragma unroll
    for (int i = 0; i < 4; i++) {
        o[i] = (f32x4){0.f, 0.f, 0.f, 0.f};
        mrow[i] = -1e30f; lrow[i] = 0.f;
    }

    for (int kb = 0; kb < 64; kb++) {
        __syncthreads();
        for (int u = t; u < 512; u += 256) {
            int r = u >> 3, c = u & 7;
            *(uint4*)&Kt[r][c * 8] = *(const uint4*)&Kb[((size_t)(h * 4096 + kb * 64 + r)) * 64 + c * 8];
            *(uint4*)&Vt[r][c * 8] = *(const uint4*)&Vtb[((size_t)(h * 64 + r)) * 4096 + kb * 64 + c * 8];
        }
        __syncthreads();

        f32x4 s[4];
        #pragma unroll
        for (int b = 0; b < 4; b++) s[b] = (f32x4){0.f, 0.f, 0.f, 0.f};
        #pragma unroll
        for (int b = 0; b < 4; b++)
            #pragma unroll
            for (int kc = 0; kc < 2; kc++) {
                bf16x8 kf = *(const bf16x8*)&Kt[b * 16 + m][kc * 32 + quad * 8];
                s[b] = __builtin_amdgcn_mfma_f32_16x16x32_bf16(qf[kc], kf, s[b], 0, 0, 0);
            }

        float alpha[4];
        #pragma unroll
        for (int r = 0; r < 4; r++) {
            float mx = fmaxf(fmaxf(s[0][r], s[1][r]), fmaxf(s[2][r], s[3][r]));
            #pragma unroll
            for (int off = 1; off < 16; off <<= 1)
                mx = fmaxf(mx, __shfl_xor(mx, off));
            float mn = fmaxf(mrow[r], mx);
            alpha[r] = __expf(mrow[r] - mn);
            mrow[r] = mn;
            float rs = 0.f;
            #pragma unroll
            for (int b = 0; b < 4; b++) {
                float p = __expf(s[b][r] - mn);
                Pl[w][quad * 4 + r][b * 16 + m] = p;
                rs += p;
            }
            #pragma unroll
            for (int off = 1; off < 16; off <<= 1)
                rs += __shfl_xor(rs, off);
            lrow[r] = lrow[r] * alpha[r] + rs;
            o[0][r] *= alpha[r]; o[1][r] *= alpha[r];
            o[2][r] *= alpha[r]; o[3][r] *= alpha[r];
        }

        #pragma unroll
        for (int kc = 0; kc < 2; kc++) {
            float4 p0 = *(const float4*)&Pl[w][m][kc * 32 + quad * 8];
            float4 p1 = *(const float4*)&Pl[w][m][kc * 32 + quad * 8 + 4];
            bf16x8 pa;
            pa[0] = (short)f2bf(p0.x); pa[1] = (short)f2bf(p0.y);
            pa[2] = (short)f2bf(p0.z); pa[3] = (short)f2bf(p0.w);
            pa[4] = (short)f2bf(p1.x); pa[5] = (short)f2bf(p1.y);
            pa[6] = (short)f2bf(p1.z); pa[7] = (short)f2bf(p1.w);
            #pragma unroll
            for (int nb = 0; nb < 4; nb++) {
                bf16x8 vf = *(const bf16x8*)&Vt[nb * 16 + m][kc * 32 + quad * 8];
                o[nb] = __builtin_amdgcn_mfma_f32_16x16x32_bf16(pa, vf, o[nb], 0, 0, 0);
            }
        }
    }

    #pragma unroll
    for (int nb = 0; nb < 4; nb++)
        #pragma unroll
        for (int r = 0; r < 4; r++) {
            int q = q0 + w * 16 + quad * 4 + r;
            att[(size_t)q * 256 + h * 64 + nb * 16 + m] = o[nb][r] / lrow[r];
        }
}

// ---------------- symmetrized final MLP, MFMA bf16 ----------------
__global__ __launch_bounds__(256)
void sym_mlp_mfma_k(const ushort_t* __restrict__ Tb, const ushort_t* __restrict__ Wb,
                    const float* __restrict__ b2, float* __restrict__ out)
{
    __shared__ ushort_t As[128][72];
    __shared__ ushort_t Bs[128][72];
    const int t = threadIdx.x;
    const int w = t >> 6, lane = t & 63;
    const int m = lane & 15, quad = lane >> 4;
    const int wr = (w >> 1) * 64, wc = (w & 1) * 64;
    const int ri = blockIdx.y * 128, rj = blockIdx.x * 128;

    f32x4 acc[4][4] = {};
    for (int kk = 0; kk < 8; kk++) {
        const int k0 = kk * 64;
        const ushort_t* Asrc = (k0 < 256) ? Tb : Wb;
        const ushort_t* Bsrc = (k0 < 256) ? Wb : Tb;
        const int kcol = k0 & 255;
        __syncthreads();
        #pragma unroll
        for (int i = 0; i < 4; i++) {
            int s = t + i * 256;
            int row = s >> 3, ch = (s & 7) * 8;
            *(uint4*)&As[row][ch] = *(const uint4*)&Asrc[(size_t)(ri + row) * 256 + kcol + ch];
            *(uint4*)&Bs[row][ch] = *(const uint4*)&Bsrc[(size_t)(rj + row) * 256 + kcol + ch];
        }
        __syncthreads();
        #pragma unroll
        for (int kc = 0; kc < 2; kc++) {
            bf16x8 af[4], bfr[4];
            #pragma unroll
            for (int rb = 0; rb < 4; rb++)
                af[rb] = *(const bf16x8*)&As[wr + rb * 16 + m][kc * 32 + quad * 8];
            #pragma unroll
            for (int cb = 0; cb < 4; cb++)
                bfr[cb] = *(const bf16x8*)&Bs[wc + cb * 16 + m][kc * 32 + quad * 8];
            #pragma unroll
            for (int rb = 0; rb < 4; rb++)
                #pragma unroll
                for (int cb = 0; cb < 4; cb++)
                    acc[rb][cb] = __builtin_amdgcn_mfma_f32_16x16x32_bf16(af[rb], bfr[cb], acc[rb][cb], 0, 0, 0);
        }
    }
    #pragma unroll
    for (int rb = 0; rb < 4; rb++) {
        #pragma unroll
        for (int r = 0; r < 4; r++) {
            const int gr = ri + wr + rb * 16 + quad * 4 + r;
            const float br = b2[gr];
            #pragma unroll
            for (int cb = 0; cb < 4; cb++) {
                const int gc = rj + wc + cb * 16 + m;
                out[(size_t)gr * NN + gc] = 0.5f * (acc[rb][cb][r] + br + b2[gc]);
            }
        }
    }
}

// ---------------- launch ----------------
extern "C" void kernel_launch(void* const* d_in, const int* in_sizes, int n_in,
                              void* d_out, int out_size, void* d_ws, size_t ws_size,
                              hipStream_t stream) {
    (void)in_sizes; (void)n_in; (void)out_size; (void)ws_size;
    const float* x = (const float*)d_in[0];
    const int* ei = (const int*)d_in[1];
    const int* src = ei;
    const int* dst = ei + EE;

    float* ws = (float*)d_ws;
    const int NH = NN * HC;          // 1,048,576 floats
    float* h0  = ws;                 // current h
    float* hb  = ws + 1 * NH;        // gcn agg; later doubles as Tb/W2b (bf16)
    float* hc  = ws + 2 * NH;        // "out"  (doubles as bf16 K/Vt during attention)
    float* att = ws + 3 * NH;        // xw / attention out (reused)
    float* qkv = ws + 4 * NH;        // N x 768 ; FFN hidden reuses this region
    float* ffh = ws + 4 * NH;        // N x 512 (qkv dead by then)
    float* deg = ws + 7 * NH;
    float* dinv = deg + NN;
    int* offs    = (int*)(dinv + NN);       // 4097 ints
    int* cursor  = offs + 4100;             // 4096 ints
    int* csr_src = cursor + 4096;           // 65536 ints
    ushort_t* Kb  = (ushort_t*)hc;   // [4][4096][64] bf16
    ushort_t* Vtb = Kb + NH;         // [4][64][4096] bf16
    ushort_t* Tb  = (ushort_t*)hb;   // [4096][256] bf16  (after hb dead)
    ushort_t* W2b = Tb + NH;         // [4096][256] bf16

    // degree + CSR (graph static across both GPS layers)
    deg_init_k<<<NN / 256, 256, 0, stream>>>(deg);
    deg_scatter_k<<<EE / 256, 256, 0, stream>>>(dst, deg);
    dinv_k<<<NN / 256, 256, 0, stream>>>(deg, dinv);
    scan_offsets_k<<<1, 1024, 0, stream>>>(deg, offs, cursor);
    csr_fill_k<<<EE / 256, 256, 0, stream>>>(src, dst, cursor, csr_src);

    // pre: h0 = relu(x @ pre_w^T + pre_b)
    gemm_k<<<dim3(4, 64), 256, 0, stream>>>(
        x, (const float*)d_in[2], (const float*)d_in[3], nullptr,
        nullptr, nullptr, 0.f, h0, 128, 256, 1, 0);

    for (int L = 0; L < 2; L++) {
        int B = 4 + L * 10;
        const float* gw = (const float*)d_in[B + 0];
        const float* gb = (const float*)d_in[B + 1];
        const float* iw = (const float*)d_in[B + 2];
        const float* ib = (const float*)d_in[B + 3];
        const float* ow = (const float*)d_in[B + 4];
        const float* ob = (const float*)d_in[B + 5];
        const float* w1 = (const float*)d_in[B + 6];
        const float* b1 = (const float*)d_in[B + 7];
        const float* w2 = (const float*)d_in[B + 8];
        const float* b2 = (const float*)d_in[B + 9];

        gemm_k<<<dim3(4, 64), 256, 0, stream>>>(
            h0, gw, nullptr, nullptr, nullptr, nullptr, 0.f, att, 256, 256, 0, 0);
        gcn_gather_k<<<NN / 4, 256, 0, stream>>>(att, dinv, offs, csr_src, hb);
        gemm_k<<<dim3(12, 64), 256, 0, stream>>>(
            h0, iw, ib, nullptr, nullptr, nullptr, 0.f, qkv, 256, 768, 0, 0);
        kv_prep_k<<<dim3(64, 4), 256, 0, stream>>>(qkv, Kb, Vtb);
        attn_mfma_k<<<dim3(64, 4), 256, 0, stream>>>(qkv, Kb, Vtb, att);
        gemm_k<<<dim3(4, 64), 256, 0, stream>>>(
            att, ow, ob, gb, hb, h0, 2.0f, hc, 256, 256, 0, 0);
        gemm_k<<<dim3(8, 64), 256, 0, stream>>>(
            hc, w1, b1, nullptr, nullptr, nullptr, 0.f, ffh, 256, 512, 1, 0);
        gemm_k<<<dim3(4, 64), 256, 0, stream>>>(
            ffh, w2, b2, nullptr, hc, nullptr, 0.f, h0, 512, 256, 1, 0);
    }

    // Tb(bf16) = relu(h0 @ mlp_w1^T + mlp_b1)
    gemm_k<<<dim3(4, 64), 256, 0, stream>>>(
        h0, (const float*)d_in[24], (const float*)d_in[25], nullptr,
        nullptr, nullptr, 0.f, (float*)Tb, 256, 256, 1, 1);
    // W2b = bf16(mlp_w2)
    cvt_bf16_k<<<NH / 1024, 256, 0, stream>>>((const float*)d_in[26], W2b);
    // out = 0.5*(delta + delta^T) via K=512 concat GEMM
    sym_mlp_mfma_k<<<dim3(32, 32), 256, 0, stream>>>(
        Tb, W2b, (const float*)d_in[27], (float*)d_out);
}

// Round 7
// 589.594 us; speedup vs baseline: 4.0004x; 1.2467x over previous
//
#include <hip/hip_runtime.h>

#define NN 4096
#define EE 65536
#define HC 256   // hidden channels

typedef unsigned short ushort_t;
typedef __attribute__((ext_vector_type(8))) short bf16x8;
typedef __attribute__((ext_vector_type(4))) float f32x4;

__device__ __forceinline__ ushort_t f2bf(float f) {
    unsigned int u = __float_as_uint(f);
    unsigned int r = (u + 0x7fffu + ((u >> 16) & 1u)) >> 16;
    return (ushort_t)r;
}
__device__ __forceinline__ float bf2f(ushort_t u) {
    return __uint_as_float(((unsigned int)u) << 16);
}

// ---------------- degree / CSR build ----------------
__global__ void deg_init_k(float* __restrict__ deg) {
    int i = blockIdx.x * 256 + threadIdx.x;
    deg[i] = 1.0f;  // self loop
}
__global__ void deg_scatter_k(const int* __restrict__ dst, float* __restrict__ deg) {
    int e = blockIdx.x * 256 + threadIdx.x;
    atomicAdd(&deg[dst[e]], 1.0f);
}
__global__ void dinv_k(const float* __restrict__ deg, float* __restrict__ dinv) {
    int i = blockIdx.x * 256 + threadIdx.x;
    dinv[i] = rsqrtf(deg[i]);
}
// exclusive scan of in-degree counts (deg[i]-1), 4096 entries, single block
__global__ __launch_bounds__(1024)
void scan_offsets_k(const float* __restrict__ deg, int* __restrict__ offs,
                    int* __restrict__ cursor) {
    __shared__ int part[1024];
    const int t = threadIdx.x;
    int c0 = (int)deg[t * 4 + 0] - 1;
    int c1 = (int)deg[t * 4 + 1] - 1;
    int c2 = (int)deg[t * 4 + 2] - 1;
    int c3 = (int)deg[t * 4 + 3] - 1;
    part[t] = c0 + c1 + c2 + c3;
    __syncthreads();
    for (int off = 1; off < 1024; off <<= 1) {
        int v = (t >= off) ? part[t - off] : 0;
        __syncthreads();
        part[t] += v;
        __syncthreads();
    }
    int base = (t == 0) ? 0 : part[t - 1];
    offs[t * 4 + 0] = base;
    offs[t * 4 + 1] = base + c0;
    offs[t * 4 + 2] = base + c0 + c1;
    offs[t * 4 + 3] = base + c0 + c1 + c2;
    cursor[t * 4 + 0] = base;
    cursor[t * 4 + 1] = base + c0;
    cursor[t * 4 + 2] = base + c0 + c1;
    cursor[t * 4 + 3] = base + c0 + c1 + c2;
    if (t == 1023) offs[4096] = part[1023];
}
__global__ void csr_fill_k(const int* __restrict__ src, const int* __restrict__ dst,
                           int* __restrict__ cursor, int* __restrict__ csr_src) {
    int e = blockIdx.x * 256 + threadIdx.x;
    int pos = atomicAdd(&cursor[dst[e]], 1);
    csr_src[pos] = src[e];
}

// ---------------- GCN gather: 4 nodes/block, 64 lanes x float4 per node ----------------
__global__ __launch_bounds__(256)
void gcn_gather_k(const float* __restrict__ xw, const float* __restrict__ dinv,
                  const int* __restrict__ offs, const int* __restrict__ csr_src,
                  float* __restrict__ agg) {
    const int node = blockIdx.x * 4 + (threadIdx.x >> 6);
    const int c = (threadIdx.x & 63) * 4;
    const float dd = dinv[node];
    float4 a = *(const float4*)&xw[(size_t)node * HC + c];
    const float self = dd * dd;
    float4 acc = make_float4(a.x * self, a.y * self, a.z * self, a.w * self);
    const int beg = offs[node], end = offs[node + 1];
    for (int e = beg; e < end; e++) {
        int s = csr_src[e];
        float coef = dinv[s] * dd;
        const float4 v = *(const float4*)&xw[(size_t)s * HC + c];
        acc.x += v.x * coef;
        acc.y += v.y * coef;
        acc.z += v.z * coef;
        acc.w += v.w * coef;
    }
    *(float4*)&agg[(size_t)node * HC + c] = acc;
}

// ---------------- fp32 -> bf16 convert (float4 -> ushort4) ----------------
__global__ void cvt_bf16_k(const float* __restrict__ in, ushort_t* __restrict__ out) {
    int i = (blockIdx.x * 256 + threadIdx.x) * 4;
    float4 v = *(const float4*)&in[i];
    ushort4 o;
    o.x = f2bf(v.x); o.y = f2bf(v.y); o.z = f2bf(v.z); o.w = f2bf(v.w);
    *(ushort4*)&out[i] = o;
}

// ---------------- generic GEMM (vector fp32; optional bf16 output) ----------------
__global__ __launch_bounds__(256)
void gemm_k(const float* __restrict__ X, const float* __restrict__ W,
            const float* __restrict__ bias1, const float* __restrict__ bias2,
            const float* __restrict__ res1, const float* __restrict__ res2, float res2scale,
            float* __restrict__ out, int K, int M, int dorelu, int obf)
{
    __shared__ float Xs[16][68];
    __shared__ float Ws[16][68];
    const int t = threadIdx.x;
    const int tx = t & 15, ty = t >> 4;
    const int row0 = blockIdx.y << 6, col0 = blockIdx.x << 6;
    const int lr = t >> 2, lc4 = (t & 3) << 2;
    float acc[4][4] = {};
    for (int k0 = 0; k0 < K; k0 += 16) {
        float4 xu = *(const float4*)&X[(row0 + lr) * K + k0 + lc4];
        float4 wu = *(const float4*)&W[(col0 + lr) * K + k0 + lc4];
        __syncthreads();
        Xs[lc4 + 0][lr] = xu.x;
        Xs[lc4 + 1][lr] = xu.y;
        Xs[lc4 + 2][lr] = xu.z;
        Xs[lc4 + 3][lr] = xu.w;
        Ws[lc4 + 0][lr] = wu.x;
        Ws[lc4 + 1][lr] = wu.y;
        Ws[lc4 + 2][lr] = wu.z;
        Ws[lc4 + 3][lr] = wu.w;
        __syncthreads();
        #pragma unroll
        for (int kk = 0; kk < 16; kk++) {
            float4 a4 = *(const float4*)&Xs[kk][ty << 2];
            float4 b4 = *(const float4*)&Ws[kk][tx << 2];
            float a[4] = {a4.x, a4.y, a4.z, a4.w};
            float b[4] = {b4.x, b4.y, b4.z, b4.w};
            #pragma unroll
            for (int i = 0; i < 4; i++)
                #pragma unroll
                for (int j = 0; j < 4; j++)
                    acc[i][j] += a[i] * b[j];
        }
    }
    #pragma unroll
    for (int i = 0; i < 4; i++) {
        int row = row0 + (ty << 2) + i;
        int cb = col0 + (tx << 2);
        float v[4] = {acc[i][0], acc[i][1], acc[i][2], acc[i][3]};
        if (bias1) {
            #pragma unroll
            for (int j = 0; j < 4; j++) v[j] += bias1[cb + j];
        }
        if (bias2) {
            #pragma unroll
            for (int j = 0; j < 4; j++) v[j] += bias2[cb + j];
        }
        if (res1) {
            float4 r = *(const float4*)&res1[row * M + cb];
            v[0] += r.x; v[1] += r.y; v[2] += r.z; v[3] += r.w;
        }
        if (res2) {
            float4 r = *(const float4*)&res2[row * M + cb];
            v[0] += res2scale * r.x; v[1] += res2scale * r.y;
            v[2] += res2scale * r.z; v[3] += res2scale * r.w;
        }
        if (dorelu) {
            #pragma unroll
            for (int j = 0; j < 4; j++) v[j] = fmaxf(v[j], 0.f);
        }
        if (obf) {
            ushort4 o;
            o.x = f2bf(v[0]); o.y = f2bf(v[1]); o.z = f2bf(v[2]); o.w = f2bf(v[3]);
            *(ushort4*)&((ushort_t*)out)[row * M + cb] = o;
        } else {
            *(float4*)&out[row * M + cb] = make_float4(v[0], v[1], v[2], v[3]);
        }
    }
}

// ---------------- K/V bf16 prep: Kb[h][n][d], Vtb[h][d][n] ----------------
__global__ __launch_bounds__(256)
void kv_prep_k(const float* __restrict__ qkv, ushort_t* __restrict__ Kb,
               ushort_t* __restrict__ Vtb)
{
    __shared__ ushort_t Vs[64][72];
    const int h = blockIdx.y;
    const int n0 = blockIdx.x << 6;
    const int t = threadIdx.x;
    for (int u = t; u < 1024; u += 256) {
        int r = u >> 4, c = u & 15;
        const float* kp = &qkv[(size_t)(n0 + r) * 768 + 256 + h * 64 + c * 4];
        float4 kv = *(const float4*)kp;
        float4 vv = *(const float4*)(kp + 256);
        ushort4 kb;
        kb.x = f2bf(kv.x); kb.y = f2bf(kv.y); kb.z = f2bf(kv.z); kb.w = f2bf(kv.w);
        *(ushort4*)&Kb[((size_t)(h * 4096 + n0 + r)) * 64 + c * 4] = kb;
        ushort4 vb;
        vb.x = f2bf(vv.x); vb.y = f2bf(vv.y); vb.z = f2bf(vv.z); vb.w = f2bf(vv.w);
        *(ushort4*)&Vs[r][c * 4] = vb;
    }
    __syncthreads();
    int d = t >> 2, kc = t & 3;
    __attribute__((aligned(16))) ushort_t vals[16];
    #pragma unroll
    for (int k = 0; k < 16; k++) vals[k] = Vs[kc * 16 + k][d];
    ushort_t* op = &Vtb[((size_t)(h * 64 + d)) * 4096 + n0 + kc * 16];
    *(uint4*)op = *(const uint4*)&vals[0];
    *(uint4*)(op + 8) = *(const uint4*)&vals[8];
}

// ---------------- split-K MFMA flash attention partials ----------------
// block = (64 queries, head h, split s); processes keys [s*1024, (s+1)*1024)
// partial o (unnormalized, bf16) -> dead K/V slots of qkv; m,l -> m_part/l_part
__global__ __launch_bounds__(256)
void attn_part_k(const float* qkv, const ushort_t* __restrict__ Kb,
                 const ushort_t* __restrict__ Vtb, ushort_t* opart,
                 float* __restrict__ m_part, float* __restrict__ l_part)
{
    __shared__ ushort_t Kt[64][72];
    __shared__ ushort_t Vt[64][72];
    __shared__ float Pl[4][16][68];
    const int h = blockIdx.y & 3;
    const int split = blockIdx.y >> 2;
    const int q0 = blockIdx.x << 6;
    const int t = threadIdx.x;
    const int w = t >> 6, lane = t & 63;
    const int m = lane & 15, quad = lane >> 4;

    bf16x8 qf[2];
    #pragma unroll
    for (int kc = 0; kc < 2; kc++) {
        const float* qp = &qkv[(size_t)(q0 + w * 16 + m) * 768 + h * 64 + kc * 32 + quad * 8];
        float4 a = *(const float4*)qp;
        float4 b = *(const float4*)(qp + 4);
        qf[kc][0] = (short)f2bf(a.x * 0.125f);
        qf[kc][1] = (short)f2bf(a.y * 0.125f);
        qf[kc][2] = (short)f2bf(a.z * 0.125f);
        qf[kc][3] = (short)f2bf(a.w * 0.125f);
        qf[kc][4] = (short)f2bf(b.x * 0.125f);
        qf[kc][5] = (short)f2bf(b.y * 0.125f);
        qf[kc][6] = (short)f2bf(b.z * 0.125f);
        qf[kc][7] = (short)f2bf(b.w * 0.125f);
    }

    f32x4 o[4];
    float mrow[4], lrow[4];
    #pragma unroll
    for (int i = 0; i < 4; i++) {
        o[i] = (f32x4){0.f, 0.f, 0.f, 0.f};
        mrow[i] = -1e30f; lrow[i] = 0.f;
    }

    for (int kb = split * 16; kb < split * 16 + 16; kb++) {
        __syncthreads();
        for (int u = t; u < 512; u += 256) {
            int r = u >> 3, c = u & 7;
            *(uint4*)&Kt[r][c * 8] = *(const uint4*)&Kb[((size_t)(h * 4096 + kb * 64 + r)) * 64 + c * 8];
            *(uint4*)&Vt[r][c * 8] = *(const uint4*)&Vtb[((size_t)(h * 64 + r)) * 4096 + kb * 64 + c * 8];
        }
        __syncthreads();

        f32x4 s[4];
        #pragma unroll
        for (int b = 0; b < 4; b++) s[b] = (f32x4){0.f, 0.f, 0.f, 0.f};
        #pragma unroll
        for (int b = 0; b < 4; b++)
            #pragma unroll
            for (int kc = 0; kc < 2; kc++) {
                bf16x8 kf = *(const bf16x8*)&Kt[b * 16 + m][kc * 32 + quad * 8];
                s[b] = __builtin_amdgcn_mfma_f32_16x16x32_bf16(qf[kc], kf, s[b], 0, 0, 0);
            }

        float alpha[4];
        #pragma unroll
        for (int r = 0; r < 4; r++) {
            float mx = fmaxf(fmaxf(s[0][r], s[1][r]), fmaxf(s[2][r], s[3][r]));
            #pragma unroll
            for (int off = 1; off < 16; off <<= 1)
                mx = fmaxf(mx, __shfl_xor(mx, off));
            float mn = fmaxf(mrow[r], mx);
            alpha[r] = __expf(mrow[r] - mn);
            mrow[r] = mn;
            float rs = 0.f;
            #pragma unroll
            for (int b = 0; b < 4; b++) {
                float p = __expf(s[b][r] - mn);
                Pl[w][quad * 4 + r][b * 16 + m] = p;
                rs += p;
            }
            #pragma unroll
            for (int off = 1; off < 16; off <<= 1)
                rs += __shfl_xor(rs, off);
            lrow[r] = lrow[r] * alpha[r] + rs;
            o[0][r] *= alpha[r]; o[1][r] *= alpha[r];
            o[2][r] *= alpha[r]; o[3][r] *= alpha[r];
        }

        #pragma unroll
        for (int kc = 0; kc < 2; kc++) {
            float4 p0 = *(const float4*)&Pl[w][m][kc * 32 + quad * 8];
            float4 p1 = *(const float4*)&Pl[w][m][kc * 32 + quad * 8 + 4];
            bf16x8 pa;
            pa[0] = (short)f2bf(p0.x); pa[1] = (short)f2bf(p0.y);
            pa[2] = (short)f2bf(p0.z); pa[3] = (short)f2bf(p0.w);
            pa[4] = (short)f2bf(p1.x); pa[5] = (short)f2bf(p1.y);
            pa[6] = (short)f2bf(p1.z); pa[7] = (short)f2bf(p1.w);
            #pragma unroll
            for (int nb = 0; nb < 4; nb++) {
                bf16x8 vf = *(const bf16x8*)&Vt[nb * 16 + m][kc * 32 + quad * 8];
                o[nb] = __builtin_amdgcn_mfma_f32_16x16x32_bf16(pa, vf, o[nb], 0, 0, 0);
            }
        }
    }

    // partial epilogue: unnormalized o (bf16) into dead qkv K/V slots; m,l fp32
    #pragma unroll
    for (int nb = 0; nb < 4; nb++)
        #pragma unroll
        for (int r = 0; r < 4; r++) {
            int q = q0 + w * 16 + quad * 4 + r;
            opart[(size_t)q * 1536 + 512 + split * 256 + h * 64 + nb * 16 + m] = f2bf(o[nb][r]);
        }
    if (m == 0) {
        #pragma unroll
        for (int r = 0; r < 4; r++) {
            int q = q0 + w * 16 + quad * 4 + r;
            m_part[(split * 4 + h) * 4096 + q] = mrow[r];
            l_part[(split * 4 + h) * 4096 + q] = lrow[r];
        }
    }
}

// merge 4 splits: out = sum_s exp(m_s - m*) o_s / sum_s exp(m_s - m*) l_s
__global__ __launch_bounds__(256)
void attn_merge_k(const ushort_t* __restrict__ opart, const float* __restrict__ m_part,
                  const float* __restrict__ l_part, float* __restrict__ att)
{
    int idx = blockIdx.x * 256 + threadIdx.x;   // over 4096*256
    int q = idx >> 8, c = idx & 255;
    int h = c >> 6, d = c & 63;
    float ms[4];
    float mmax = -1e30f;
    #pragma unroll
    for (int s = 0; s < 4; s++) {
        ms[s] = m_part[(s * 4 + h) * 4096 + q];
        mmax = fmaxf(mmax, ms[s]);
    }
    float onum = 0.f, lden = 0.f;
    #pragma unroll
    for (int s = 0; s < 4; s++) {
        float wgt = __expf(ms[s] - mmax);
        float ov = bf2f(opart[(size_t)q * 1536 + 512 + s * 256 + h * 64 + d]);
        onum += wgt * ov;
        lden += wgt * l_part[(s * 4 + h) * 4096 + q];
    }
    att[(size_t)q * 256 + c] = onum / lden;
}

// ---------------- symmetrized final MLP, MFMA bf16 ----------------
__global__ __launch_bounds__(256)
void sym_mlp_mfma_k(const ushort_t* __restrict__ Tb, const ushort_t* __restrict__ Wb,
                    const float* __restrict__ b2, float* __restrict__ out)
{
    __shared__ ushort_t As[128][72];
    __shared__ ushort_t Bs[128][72];
    const int t = threadIdx.x;
    const int w = t >> 6, lane = t & 63;
    const int m = lane & 15, quad = lane >> 4;
    const int wr = (w >> 1) * 64, wc = (w & 1) * 64;
    const int ri = blockIdx.y * 128, rj = blockIdx.x * 128;

    f32x4 acc[4][4] = {};
    for (int kk = 0; kk < 8; kk++) {
        const int k0 = kk * 64;
        const ushort_t* Asrc = (k0 < 256) ? Tb : Wb;
        const ushort_t* Bsrc = (k0 < 256) ? Wb : Tb;
        const int kcol = k0 & 255;
        __syncthreads();
        #pragma unroll
        for (int i = 0; i < 4; i++) {
            int s = t + i * 256;
            int row = s >> 3, ch = (s & 7) * 8;
            *(uint4*)&As[row][ch] = *(const uint4*)&Asrc[(size_t)(ri + row) * 256 + kcol + ch];
            *(uint4*)&Bs[row][ch] = *(const uint4*)&Bsrc[(size_t)(rj + row) * 256 + kcol + ch];
        }
        __syncthreads();
        #pragma unroll
        for (int kc = 0; kc < 2; kc++) {
            bf16x8 af[4], bfr[4];
            #pragma unroll
            for (int rb = 0; rb < 4; rb++)
                af[rb] = *(const bf16x8*)&As[wr + rb * 16 + m][kc * 32 + quad * 8];
            #pragma unroll
            for (int cb = 0; cb < 4; cb++)
                bfr[cb] = *(const bf16x8*)&Bs[wc + cb * 16 + m][kc * 32 + quad * 8];
            #pragma unroll
            for (int rb = 0; rb < 4; rb++)
                #pragma unroll
                for (int cb = 0; cb < 4; cb++)
                    acc[rb][cb] = __builtin_amdgcn_mfma_f32_16x16x32_bf16(af[rb], bfr[cb], acc[rb][cb], 0, 0, 0);
        }
    }
    #pragma unroll
    for (int rb = 0; rb < 4; rb++) {
        #pragma unroll
        for (int r = 0; r < 4; r++) {
            const int gr = ri + wr + rb * 16 + quad * 4 + r;
            const float br = b2[gr];
            #pragma unroll
            for (int cb = 0; cb < 4; cb++) {
                const int gc = rj + wc + cb * 16 + m;
                out[(size_t)gr * NN + gc] = 0.5f * (acc[rb][cb][r] + br + b2[gc]);
            }
        }
    }
}

// ---------------- launch ----------------
extern "C" void kernel_launch(void* const* d_in, const int* in_sizes, int n_in,
                              void* d_out, int out_size, void* d_ws, size_t ws_size,
                              hipStream_t stream) {
    (void)in_sizes; (void)n_in; (void)out_size; (void)ws_size;
    const float* x = (const float*)d_in[0];
    const int* ei = (const int*)d_in[1];
    const int* src = ei;
    const int* dst = ei + EE;

    float* ws = (float*)d_ws;
    const int NH = NN * HC;          // 1,048,576 floats
    float* h0  = ws;                 // current h
    float* hb  = ws + 1 * NH;        // gcn agg; later doubles as Tb/W2b (bf16)
    float* hc  = ws + 2 * NH;        // "out"  (doubles as bf16 K/Vt during attention)
    float* att = ws + 3 * NH;        // xw / attention out (reused)
    float* qkv = ws + 4 * NH;        // N x 768 ; K/V cols double as bf16 o-partials
    float* ffh = ws + 4 * NH;        // N x 512 (qkv dead by then)
    float* deg = ws + 7 * NH;
    float* dinv = deg + NN;
    int* offs    = (int*)(dinv + NN);       // 4097 ints
    int* cursor  = offs + 4100;             // 4096 ints
    int* csr_src = cursor + 4096;           // 65536 ints
    float* m_part = (float*)(csr_src + EE); // 65536 floats
    float* l_part = m_part + 65536;         // 65536 floats
    ushort_t* Kb  = (ushort_t*)hc;   // [4][4096][64] bf16
    ushort_t* Vtb = Kb + NH;         // [4][64][4096] bf16
    ushort_t* Tb  = (ushort_t*)hb;   // [4096][256] bf16  (after hb dead)
    ushort_t* W2b = Tb + NH;         // [4096][256] bf16

    // degree + CSR (graph static across both GPS layers)
    deg_init_k<<<NN / 256, 256, 0, stream>>>(deg);
    deg_scatter_k<<<EE / 256, 256, 0, stream>>>(dst, deg);
    dinv_k<<<NN / 256, 256, 0, stream>>>(deg, dinv);
    scan_offsets_k<<<1, 1024, 0, stream>>>(deg, offs, cursor);
    csr_fill_k<<<EE / 256, 256, 0, stream>>>(src, dst, cursor, csr_src);

    // pre: h0 = relu(x @ pre_w^T + pre_b)
    gemm_k<<<dim3(4, 64), 256, 0, stream>>>(
        x, (const float*)d_in[2], (const float*)d_in[3], nullptr,
        nullptr, nullptr, 0.f, h0, 128, 256, 1, 0);

    for (int L = 0; L < 2; L++) {
        int B = 4 + L * 10;
        const float* gw = (const float*)d_in[B + 0];
        const float* gb = (const float*)d_in[B + 1];
        const float* iw = (const float*)d_in[B + 2];
        const float* ib = (const float*)d_in[B + 3];
        const float* ow = (const float*)d_in[B + 4];
        const float* ob = (const float*)d_in[B + 5];
        const float* w1 = (const float*)d_in[B + 6];
        const float* b1 = (const float*)d_in[B + 7];
        const float* w2 = (const float*)d_in[B + 8];
        const float* b2 = (const float*)d_in[B + 9];

        gemm_k<<<dim3(4, 64), 256, 0, stream>>>(
            h0, gw, nullptr, nullptr, nullptr, nullptr, 0.f, att, 256, 256, 0, 0);
        gcn_gather_k<<<NN / 4, 256, 0, stream>>>(att, dinv, offs, csr_src, hb);
        gemm_k<<<dim3(12, 64), 256, 0, stream>>>(
            h0, iw, ib, nullptr, nullptr, nullptr, 0.f, qkv, 256, 768, 0, 0);
        kv_prep_k<<<dim3(64, 4), 256, 0, stream>>>(qkv, Kb, Vtb);
        // split-K flash attention: partials then merge -> att
        attn_part_k<<<dim3(64, 16), 256, 0, stream>>>(
            qkv, Kb, Vtb, (ushort_t*)qkv, m_part, l_part);
        attn_merge_k<<<NN, 256, 0, stream>>>(
            (const ushort_t*)qkv, m_part, l_part, att);
        gemm_k<<<dim3(4, 64), 256, 0, stream>>>(
            att, ow, ob, gb, hb, h0, 2.0f, hc, 256, 256, 0, 0);
        gemm_k<<<dim3(8, 64), 256, 0, stream>>>(
            hc, w1, b1, nullptr, nullptr, nullptr, 0.f, ffh, 256, 512, 1, 0);
        gemm_k<<<dim3(4, 64), 256, 0, stream>>>(
            ffh, w2, b2, nullptr, hc, nullptr, 0.f, h0, 512, 256, 1, 0);
    }

    // Tb(bf16) = relu(h0 @ mlp_w1^T + mlp_b1)
    gemm_k<<<dim3(4, 64), 256, 0, stream>>>(
        h0, (const float*)d_in[24], (const float*)d_in[25], nullptr,
        nullptr, nullptr, 0.f, (float*)Tb, 256, 256, 1, 1);
    // W2b = bf16(mlp_w2)
    cvt_bf16_k<<<NH / 1024, 256, 0, stream>>>((const float*)d_in[26], W2b);
    // out = 0.5*(delta + delta^T) via K=512 concat GEMM
    sym_mlp_mfma_k<<<dim3(32, 32), 256, 0, stream>>>(
        Tb, W2b, (const float*)d_in[27], (float*)d_out);
}

// Round 8
// 521.126 us; speedup vs baseline: 4.5260x; 1.1314x over previous
//
#include <hip/hip_runtime.h>

#define NN 4096
#define EE 65536
#define HC 256   // hidden channels

typedef unsigned short ushort_t;
typedef __attribute__((ext_vector_type(8))) short bf16x8;
typedef __attribute__((ext_vector_type(4))) float f32x4;

__device__ __forceinline__ ushort_t f2bf(float f) {
    unsigned int u = __float_as_uint(f);
    unsigned int r = (u + 0x7fffu + ((u >> 16) & 1u)) >> 16;
    return (ushort_t)r;
}
__device__ __forceinline__ float bf2f(ushort_t u) {
    return __uint_as_float(((unsigned int)u) << 16);
}

// ---------------- degree / CSR build ----------------
__global__ void deg_init_k(float* __restrict__ deg) {
    int i = blockIdx.x * 256 + threadIdx.x;
    deg[i] = 1.0f;  // self loop
}
__global__ void deg_scatter_k(const int* __restrict__ dst, float* __restrict__ deg) {
    int e = blockIdx.x * 256 + threadIdx.x;
    atomicAdd(&deg[dst[e]], 1.0f);
}
__global__ void dinv_k(const float* __restrict__ deg, float* __restrict__ dinv) {
    int i = blockIdx.x * 256 + threadIdx.x;
    dinv[i] = rsqrtf(deg[i]);
}
// exclusive scan of in-degree counts (deg[i]-1), 4096 entries, single block
__global__ __launch_bounds__(1024)
void scan_offsets_k(const float* __restrict__ deg, int* __restrict__ offs,
                    int* __restrict__ cursor) {
    __shared__ int part[1024];
    const int t = threadIdx.x;
    int c0 = (int)deg[t * 4 + 0] - 1;
    int c1 = (int)deg[t * 4 + 1] - 1;
    int c2 = (int)deg[t * 4 + 2] - 1;
    int c3 = (int)deg[t * 4 + 3] - 1;
    part[t] = c0 + c1 + c2 + c3;
    __syncthreads();
    for (int off = 1; off < 1024; off <<= 1) {
        int v = (t >= off) ? part[t - off] : 0;
        __syncthreads();
        part[t] += v;
        __syncthreads();
    }
    int base = (t == 0) ? 0 : part[t - 1];
    offs[t * 4 + 0] = base;
    offs[t * 4 + 1] = base + c0;
    offs[t * 4 + 2] = base + c0 + c1;
    offs[t * 4 + 3] = base + c0 + c1 + c2;
    cursor[t * 4 + 0] = base;
    cursor[t * 4 + 1] = base + c0;
    cursor[t * 4 + 2] = base + c0 + c1;
    cursor[t * 4 + 3] = base + c0 + c1 + c2;
    if (t == 1023) offs[4096] = part[1023];
}
__global__ void csr_fill_k(const int* __restrict__ src, const int* __restrict__ dst,
                           int* __restrict__ cursor, int* __restrict__ csr_src) {
    int e = blockIdx.x * 256 + threadIdx.x;
    int pos = atomicAdd(&cursor[dst[e]], 1);
    csr_src[pos] = src[e];
}

// ---------------- GCN gather: 4 nodes/block, 64 lanes x float4 per node ----------------
__global__ __launch_bounds__(256)
void gcn_gather_k(const float* __restrict__ xw, const float* __restrict__ dinv,
                  const int* __restrict__ offs, const int* __restrict__ csr_src,
                  float* __restrict__ agg) {
    const int node = blockIdx.x * 4 + (threadIdx.x >> 6);
    const int c = (threadIdx.x & 63) * 4;
    const float dd = dinv[node];
    float4 a = *(const float4*)&xw[(size_t)node * HC + c];
    const float self = dd * dd;
    float4 acc = make_float4(a.x * self, a.y * self, a.z * self, a.w * self);
    const int beg = offs[node], end = offs[node + 1];
    for (int e = beg; e < end; e++) {
        int s = csr_src[e];
        float coef = dinv[s] * dd;
        const float4 v = *(const float4*)&xw[(size_t)s * HC + c];
        acc.x += v.x * coef;
        acc.y += v.y * coef;
        acc.z += v.z * coef;
        acc.w += v.w * coef;
    }
    *(float4*)&agg[(size_t)node * HC + c] = acc;
}

// ---------------- fp32 -> bf16 convert (float4 -> ushort4) ----------------
__global__ void cvt_bf16_k(const float* __restrict__ in, ushort_t* __restrict__ out) {
    int i = (blockIdx.x * 256 + threadIdx.x) * 4;
    float4 v = *(const float4*)&in[i];
    ushort4 o;
    o.x = f2bf(v.x); o.y = f2bf(v.y); o.z = f2bf(v.z); o.w = f2bf(v.w);
    *(ushort4*)&out[i] = o;
}

// ---------------- bf16-MFMA GEMM: out[N,M] = act(X[N,K]@W[M,K]^T + b1 + b2 + r1 + s*r2)
// fp32 inputs, converted to bf16 during LDS staging. 64x64 tile, 4 waves.
__global__ __launch_bounds__(256)
void gemm_bf_k(const float* __restrict__ X, const float* __restrict__ W,
               const float* __restrict__ bias1, const float* __restrict__ bias2,
               const float* __restrict__ res1, const float* __restrict__ res2, float res2scale,
               float* __restrict__ out, int K, int M, int dorelu, int obf)
{
    __shared__ ushort_t As[64][72];   // [row][k] bf16, 36-dword stride
    __shared__ ushort_t Bs[64][72];   // [col][k] bf16
    const int t = threadIdx.x;
    const int w = t >> 6, lane = t & 63;
    const int m = lane & 15, quad = lane >> 4;
    const int row0 = blockIdx.y << 6, col0 = blockIdx.x << 6;
    const int sr = t >> 2;            // staging row 0..63
    const int sc = (t & 3) << 4;      // staging col chunk 0,16,32,48

    f32x4 acc[4] = {};
    for (int k0 = 0; k0 < K; k0 += 64) {
        const float* xp = &X[(size_t)(row0 + sr) * K + k0 + sc];
        const float* wp = &W[(size_t)(col0 + sr) * K + k0 + sc];
        float4 xa = *(const float4*)xp,     xb = *(const float4*)(xp + 4);
        float4 xc = *(const float4*)(xp + 8), xd = *(const float4*)(xp + 12);
        float4 wa = *(const float4*)wp,     wb = *(const float4*)(wp + 4);
        float4 wc = *(const float4*)(wp + 8), wd = *(const float4*)(wp + 12);
        __syncthreads();
        {
            __attribute__((aligned(16))) ushort_t tx[16];
            tx[0]=f2bf(xa.x); tx[1]=f2bf(xa.y); tx[2]=f2bf(xa.z); tx[3]=f2bf(xa.w);
            tx[4]=f2bf(xb.x); tx[5]=f2bf(xb.y); tx[6]=f2bf(xb.z); tx[7]=f2bf(xb.w);
            tx[8]=f2bf(xc.x); tx[9]=f2bf(xc.y); tx[10]=f2bf(xc.z); tx[11]=f2bf(xc.w);
            tx[12]=f2bf(xd.x); tx[13]=f2bf(xd.y); tx[14]=f2bf(xd.z); tx[15]=f2bf(xd.w);
            *(uint4*)&As[sr][sc] = *(const uint4*)&tx[0];
            *(uint4*)&As[sr][sc + 8] = *(const uint4*)&tx[8];
            __attribute__((aligned(16))) ushort_t tw[16];
            tw[0]=f2bf(wa.x); tw[1]=f2bf(wa.y); tw[2]=f2bf(wa.z); tw[3]=f2bf(wa.w);
            tw[4]=f2bf(wb.x); tw[5]=f2bf(wb.y); tw[6]=f2bf(wb.z); tw[7]=f2bf(wb.w);
            tw[8]=f2bf(wc.x); tw[9]=f2bf(wc.y); tw[10]=f2bf(wc.z); tw[11]=f2bf(wc.w);
            tw[12]=f2bf(wd.x); tw[13]=f2bf(wd.y); tw[14]=f2bf(wd.z); tw[15]=f2bf(wd.w);
            *(uint4*)&Bs[sr][sc] = *(const uint4*)&tw[0];
            *(uint4*)&Bs[sr][sc + 8] = *(const uint4*)&tw[8];
        }
        __syncthreads();
        #pragma unroll
        for (int kc = 0; kc < 2; kc++) {
            bf16x8 af = *(const bf16x8*)&As[(w << 4) + m][kc * 32 + quad * 8];
            #pragma unroll
            for (int cb = 0; cb < 4; cb++) {
                bf16x8 bf = *(const bf16x8*)&Bs[cb * 16 + m][kc * 32 + quad * 8];
                acc[cb] = __builtin_amdgcn_mfma_f32_16x16x32_bf16(af, bf, acc[cb], 0, 0, 0);
            }
        }
    }
    #pragma unroll
    for (int cb = 0; cb < 4; cb++) {
        #pragma unroll
        for (int r = 0; r < 4; r++) {
            const int row = row0 + (w << 4) + quad * 4 + r;
            const int col = col0 + cb * 16 + m;
            float v = acc[cb][r];
            if (bias1) v += bias1[col];
            if (bias2) v += bias2[col];
            if (res1) v += res1[(size_t)row * M + col];
            if (res2) v += res2scale * res2[(size_t)row * M + col];
            if (dorelu) v = fmaxf(v, 0.f);
            if (obf) ((ushort_t*)out)[(size_t)row * M + col] = f2bf(v);
            else out[(size_t)row * M + col] = v;
        }
    }
}

// ---------------- K/V bf16 prep: Kb[h][n][d], Vtb[h][d][n] ----------------
__global__ __launch_bounds__(256)
void kv_prep_k(const float* __restrict__ qkv, ushort_t* __restrict__ Kb,
               ushort_t* __restrict__ Vtb)
{
    __shared__ ushort_t Vs[64][72];
    const int h = blockIdx.y;
    const int n0 = blockIdx.x << 6;
    const int t = threadIdx.x;
    for (int u = t; u < 1024; u += 256) {
        int r = u >> 4, c = u & 15;
        const float* kp = &qkv[(size_t)(n0 + r) * 768 + 256 + h * 64 + c * 4];
        float4 kv = *(const float4*)kp;
        float4 vv = *(const float4*)(kp + 256);
        ushort4 kb;
        kb.x = f2bf(kv.x); kb.y = f2bf(kv.y); kb.z = f2bf(kv.z); kb.w = f2bf(kv.w);
        *(ushort4*)&Kb[((size_t)(h * 4096 + n0 + r)) * 64 + c * 4] = kb;
        ushort4 vb;
        vb.x = f2bf(vv.x); vb.y = f2bf(vv.y); vb.z = f2bf(vv.z); vb.w = f2bf(vv.w);
        *(ushort4*)&Vs[r][c * 4] = vb;
    }
    __syncthreads();
    int d = t >> 2, kc = t & 3;
    __attribute__((aligned(16))) ushort_t vals[16];
    #pragma unroll
    for (int k = 0; k < 16; k++) vals[k] = Vs[kc * 16 + k][d];
    ushort_t* op = &Vtb[((size_t)(h * 64 + d)) * 4096 + n0 + kc * 16];
    *(uint4*)op = *(const uint4*)&vals[0];
    *(uint4*)(op + 8) = *(const uint4*)&vals[8];
}

// ---------------- split-K MFMA flash attention partials ----------------
__global__ __launch_bounds__(256)
void attn_part_k(const float* qkv, const ushort_t* __restrict__ Kb,
                 const ushort_t* __restrict__ Vtb, ushort_t* opart,
                 float* __restrict__ m_part, float* __restrict__ l_part)
{
    __shared__ ushort_t Kt[64][72];
    __shared__ ushort_t Vt[64][72];
    __shared__ float Pl[4][16][68];
    const int h = blockIdx.y & 3;
    const int split = blockIdx.y >> 2;
    const int q0 = blockIdx.x << 6;
    const int t = threadIdx.x;
    const int w = t >> 6, lane = t & 63;
    const int m = lane & 15, quad = lane >> 4;

    bf16x8 qf[2];
    #pragma unroll
    for (int kc = 0; kc < 2; kc++) {
        const float* qp = &qkv[(size_t)(q0 + w * 16 + m) * 768 + h * 64 + kc * 32 + quad * 8];
        float4 a = *(const float4*)qp;
        float4 b = *(const float4*)(qp + 4);
        qf[kc][0] = (short)f2bf(a.x * 0.125f);
        qf[kc][1] = (short)f2bf(a.y * 0.125f);
        qf[kc][2] = (short)f2bf(a.z * 0.125f);
        qf[kc][3] = (short)f2bf(a.w * 0.125f);
        qf[kc][4] = (short)f2bf(b.x * 0.125f);
        qf[kc][5] = (short)f2bf(b.y * 0.125f);
        qf[kc][6] = (short)f2bf(b.z * 0.125f);
        qf[kc][7] = (short)f2bf(b.w * 0.125f);
    }

    f32x4 o[4];
    float mrow[4], lrow[4];
    #pragma unroll
    for (int i = 0; i < 4; i++) {
        o[i] = (f32x4){0.f, 0.f, 0.f, 0.f};
        mrow[i] = -1e30f; lrow[i] = 0.f;
    }

    for (int kb = split * 16; kb < split * 16 + 16; kb++) {
        __syncthreads();
        for (int u = t; u < 512; u += 256) {
            int r = u >> 3, c = u & 7;
            *(uint4*)&Kt[r][c * 8] = *(const uint4*)&Kb[((size_t)(h * 4096 + kb * 64 + r)) * 64 + c * 8];
            *(uint4*)&Vt[r][c * 8] = *(const uint4*)&Vtb[((size_t)(h * 64 + r)) * 4096 + kb * 64 + c * 8];
        }
        __syncthreads();

        f32x4 s[4];
        #pragma unroll
        for (int b = 0; b < 4; b++) s[b] = (f32x4){0.f, 0.f, 0.f, 0.f};
        #pragma unroll
        for (int b = 0; b < 4; b++)
            #pragma unroll
            for (int kc = 0; kc < 2; kc++) {
                bf16x8 kf = *(const bf16x8*)&Kt[b * 16 + m][kc * 32 + quad * 8];
                s[b] = __builtin_amdgcn_mfma_f32_16x16x32_bf16(qf[kc], kf, s[b], 0, 0, 0);
            }

        float alpha[4];
        #pragma unroll
        for (int r = 0; r < 4; r++) {
            float mx = fmaxf(fmaxf(s[0][r], s[1][r]), fmaxf(s[2][r], s[3][r]));
            #pragma unroll
            for (int off = 1; off < 16; off <<= 1)
                mx = fmaxf(mx, __shfl_xor(mx, off));
            float mn = fmaxf(mrow[r], mx);
            alpha[r] = __expf(mrow[r] - mn);
            mrow[r] = mn;
            float rs = 0.f;
            #pragma unroll
            for (int b = 0; b < 4; b++) {
                float p = __expf(s[b][r] - mn);
                Pl[w][quad * 4 + r][b * 16 + m] = p;
                rs += p;
            }
            #pragma unroll
            for (int off = 1; off < 16; off <<= 1)
                rs += __shfl_xor(rs, off);
            lrow[r] = lrow[r] * alpha[r] + rs;
            o[0][r] *= alpha[r]; o[1][r] *= alpha[r];
            o[2][r] *= alpha[r]; o[3][r] *= alpha[r];
        }

        #pragma unroll
        for (int kc = 0; kc < 2; kc++) {
            float4 p0 = *(const float4*)&Pl[w][m][kc * 32 + quad * 8];
            float4 p1 = *(const float4*)&Pl[w][m][kc * 32 + quad * 8 + 4];
            bf16x8 pa;
            pa[0] = (short)f2bf(p0.x); pa[1] = (short)f2bf(p0.y);
            pa[2] = (short)f2bf(p0.z); pa[3] = (short)f2bf(p0.w);
            pa[4] = (short)f2bf(p1.x); pa[5] = (short)f2bf(p1.y);
            pa[6] = (short)f2bf(p1.z); pa[7] = (short)f2bf(p1.w);
            #pragma unroll
            for (int nb = 0; nb < 4; nb++) {
                bf16x8 vf = *(const bf16x8*)&Vt[nb * 16 + m][kc * 32 + quad * 8];
                o[nb] = __builtin_amdgcn_mfma_f32_16x16x32_bf16(pa, vf, o[nb], 0, 0, 0);
            }
        }
    }

    #pragma unroll
    for (int nb = 0; nb < 4; nb++)
        #pragma unroll
        for (int r = 0; r < 4; r++) {
            int q = q0 + w * 16 + quad * 4 + r;
            opart[(size_t)q * 1536 + 512 + split * 256 + h * 64 + nb * 16 + m] = f2bf(o[nb][r]);
        }
    if (m == 0) {
        #pragma unroll
        for (int r = 0; r < 4; r++) {
            int q = q0 + w * 16 + quad * 4 + r;
            m_part[(split * 4 + h) * 4096 + q] = mrow[r];
            l_part[(split * 4 + h) * 4096 + q] = lrow[r];
        }
    }
}

// merge 4 splits
__global__ __launch_bounds__(256)
void attn_merge_k(const ushort_t* __restrict__ opart, const float* __restrict__ m_part,
                  const float* __restrict__ l_part, float* __restrict__ att)
{
    int idx = blockIdx.x * 256 + threadIdx.x;
    int q = idx >> 8, c = idx & 255;
    int h = c >> 6, d = c & 63;
    float ms[4];
    float mmax = -1e30f;
    #pragma unroll
    for (int s = 0; s < 4; s++) {
        ms[s] = m_part[(s * 4 + h) * 4096 + q];
        mmax = fmaxf(mmax, ms[s]);
    }
    float onum = 0.f, lden = 0.f;
    #pragma unroll
    for (int s = 0; s < 4; s++) {
        float wgt = __expf(ms[s] - mmax);
        float ov = bf2f(opart[(size_t)q * 1536 + 512 + s * 256 + h * 64 + d]);
        onum += wgt * ov;
        lden += wgt * l_part[(s * 4 + h) * 4096 + q];
    }
    att[(size_t)q * 256 + c] = onum / lden;
}

// ---------------- symmetrized final MLP, MFMA bf16 ----------------
__global__ __launch_bounds__(256)
void sym_mlp_mfma_k(const ushort_t* __restrict__ Tb, const ushort_t* __restrict__ Wb,
                    const float* __restrict__ b2, float* __restrict__ out)
{
    __shared__ ushort_t As[128][72];
    __shared__ ushort_t Bs[128][72];
    const int t = threadIdx.x;
    const int w = t >> 6, lane = t & 63;
    const int m = lane & 15, quad = lane >> 4;
    const int wr = (w >> 1) * 64, wc = (w & 1) * 64;
    const int ri = blockIdx.y * 128, rj = blockIdx.x * 128;

    f32x4 acc[4][4] = {};
    for (int kk = 0; kk < 8; kk++) {
        const int k0 = kk * 64;
        const ushort_t* Asrc = (k0 < 256) ? Tb : Wb;
        const ushort_t* Bsrc = (k0 < 256) ? Wb : Tb;
        const int kcol = k0 & 255;
        __syncthreads();
        #pragma unroll
        for (int i = 0; i < 4; i++) {
            int s = t + i * 256;
            int row = s >> 3, ch = (s & 7) * 8;
            *(uint4*)&As[row][ch] = *(const uint4*)&Asrc[(size_t)(ri + row) * 256 + kcol + ch];
            *(uint4*)&Bs[row][ch] = *(const uint4*)&Bsrc[(size_t)(rj + row) * 256 + kcol + ch];
        }
        __syncthreads();
        #pragma unroll
        for (int kc = 0; kc < 2; kc++) {
            bf16x8 af[4], bfr[4];
            #pragma unroll
            for (int rb = 0; rb < 4; rb++)
                af[rb] = *(const bf16x8*)&As[wr + rb * 16 + m][kc * 32 + quad * 8];
            #pragma unroll
            for (int cb = 0; cb < 4; cb++)
                bfr[cb] = *(const bf16x8*)&Bs[wc + cb * 16 + m][kc * 32 + quad * 8];
            #pragma unroll
            for (int rb = 0; rb < 4; rb++)
                #pragma unroll
                for (int cb = 0; cb < 4; cb++)
                    acc[rb][cb] = __builtin_amdgcn_mfma_f32_16x16x32_bf16(af[rb], bfr[cb], acc[rb][cb], 0, 0, 0);
        }
    }
    #pragma unroll
    for (int rb = 0; rb < 4; rb++) {
        #pragma unroll
        for (int r = 0; r < 4; r++) {
            const int gr = ri + wr + rb * 16 + quad * 4 + r;
            const float br = b2[gr];
            #pragma unroll
            for (int cb = 0; cb < 4; cb++) {
                const int gc = rj + wc + cb * 16 + m;
                out[(size_t)gr * NN + gc] = 0.5f * (acc[rb][cb][r] + br + b2[gc]);
            }
        }
    }
}

// ---------------- launch ----------------
extern "C" void kernel_launch(void* const* d_in, const int* in_sizes, int n_in,
                              void* d_out, int out_size, void* d_ws, size_t ws_size,
                              hipStream_t stream) {
    (void)in_sizes; (void)n_in; (void)out_size; (void)ws_size;
    const float* x = (const float*)d_in[0];
    const int* ei = (const int*)d_in[1];
    const int* src = ei;
    const int* dst = ei + EE;

    float* ws = (float*)d_ws;
    const int NH = NN * HC;          // 1,048,576 floats
    float* h0  = ws;                 // current h
    float* hb  = ws + 1 * NH;        // gcn agg; later doubles as Tb/W2b (bf16)
    float* hc  = ws + 2 * NH;        // "out"  (doubles as bf16 K/Vt during attention)
    float* att = ws + 3 * NH;        // xw / attention out (reused)
    float* qkv = ws + 4 * NH;        // N x 768 ; K/V cols double as bf16 o-partials
    float* ffh = ws + 4 * NH;        // N x 512 (qkv dead by then)
    float* deg = ws + 7 * NH;
    float* dinv = deg + NN;
    int* offs    = (int*)(dinv + NN);       // 4097 ints
    int* cursor  = offs + 4100;             // 4096 ints
    int* csr_src = cursor + 4096;           // 65536 ints
    float* m_part = (float*)(csr_src + EE); // 65536 floats
    float* l_part = m_part + 65536;         // 65536 floats
    ushort_t* Kb  = (ushort_t*)hc;   // [4][4096][64] bf16
    ushort_t* Vtb = Kb + NH;         // [4][64][4096] bf16
    ushort_t* Tb  = (ushort_t*)hb;   // [4096][256] bf16  (after hb dead)
    ushort_t* W2b = Tb + NH;         // [4096][256] bf16

    // degree + CSR (graph static across both GPS layers)
    deg_init_k<<<NN / 256, 256, 0, stream>>>(deg);
    deg_scatter_k<<<EE / 256, 256, 0, stream>>>(dst, deg);
    dinv_k<<<NN / 256, 256, 0, stream>>>(deg, dinv);
    scan_offsets_k<<<1, 1024, 0, stream>>>(deg, offs, cursor);
    csr_fill_k<<<EE / 256, 256, 0, stream>>>(src, dst, cursor, csr_src);

    // pre: h0 = relu(x @ pre_w^T + pre_b)
    gemm_bf_k<<<dim3(4, 64), 256, 0, stream>>>(
        x, (const float*)d_in[2], (const float*)d_in[3], nullptr,
        nullptr, nullptr, 0.f, h0, 128, 256, 1, 0);

    for (int L = 0; L < 2; L++) {
        int B = 4 + L * 10;
        const float* gw = (const float*)d_in[B + 0];
        const float* gb = (const float*)d_in[B + 1];
        const float* iw = (const float*)d_in[B + 2];
        const float* ib = (const float*)d_in[B + 3];
        const float* ow = (const float*)d_in[B + 4];
        const float* ob = (const float*)d_in[B + 5];
        const float* w1 = (const float*)d_in[B + 6];
        const float* b1 = (const float*)d_in[B + 7];
        const float* w2 = (const float*)d_in[B + 8];
        const float* b2 = (const float*)d_in[B + 9];

        gemm_bf_k<<<dim3(4, 64), 256, 0, stream>>>(
            h0, gw, nullptr, nullptr, nullptr, nullptr, 0.f, att, 256, 256, 0, 0);
        gcn_gather_k<<<NN / 4, 256, 0, stream>>>(att, dinv, offs, csr_src, hb);
        gemm_bf_k<<<dim3(12, 64), 256, 0, stream>>>(
            h0, iw, ib, nullptr, nullptr, nullptr, 0.f, qkv, 256, 768, 0, 0);
        kv_prep_k<<<dim3(64, 4), 256, 0, stream>>>(qkv, Kb, Vtb);
        attn_part_k<<<dim3(64, 16), 256, 0, stream>>>(
            qkv, Kb, Vtb, (ushort_t*)qkv, m_part, l_part);
        attn_merge_k<<<NN, 256, 0, stream>>>(
            (const ushort_t*)qkv, m_part, l_part, att);
        gemm_bf_k<<<dim3(4, 64), 256, 0, stream>>>(
            att, ow, ob, gb, hb, h0, 2.0f, hc, 256, 256, 0, 0);
        gemm_bf_k<<<dim3(8, 64), 256, 0, stream>>>(
            hc, w1, b1, nullptr, nullptr, nullptr, 0.f, ffh, 256, 512, 1, 0);
        gemm_bf_k<<<dim3(4, 64), 256, 0, stream>>>(
            ffh, w2, b2, nullptr, hc, nullptr, 0.f, h0, 512, 256, 1, 0);
    }

    // Tb(bf16) = relu(h0 @ mlp_w1^T + mlp_b1)
    gemm_bf_k<<<dim3(4, 64), 256, 0, stream>>>(
        h0, (const float*)d_in[24], (const float*)d_in[25], nullptr,
        nullptr, nullptr, 0.f, (float*)Tb, 256, 256, 1, 1);
    // W2b = bf16(mlp_w2)
    cvt_bf16_k<<<NH / 1024, 256, 0, stream>>>((const float*)d_in[26], W2b);
    // out = 0.5*(delta + delta^T) via K=512 concat GEMM
    sym_mlp_mfma_k<<<dim3(32, 32), 256, 0, stream>>>(
        Tb, W2b, (const float*)d_in[27], (float*)d_out);
}

// Round 9
// 494.144 us; speedup vs baseline: 4.7731x; 1.0546x over previous
//
#include <hip/hip_runtime.h>

#define NN 4096
#define EE 65536
#define HC 256   // hidden channels

typedef unsigned short ushort_t;
typedef __attribute__((ext_vector_type(8))) short bf16x8;
typedef __attribute__((ext_vector_type(4))) float f32x4;

__device__ __forceinline__ ushort_t f2bf(float f) {
    unsigned int u = __float_as_uint(f);
    unsigned int r = (u + 0x7fffu + ((u >> 16) & 1u)) >> 16;
    return (ushort_t)r;
}
__device__ __forceinline__ float bf2f(ushort_t u) {
    return __uint_as_float(((unsigned int)u) << 16);
}

// ---------------- degree / CSR build ----------------
__global__ void deg_init_k(float* __restrict__ deg) {
    int i = blockIdx.x * 256 + threadIdx.x;
    deg[i] = 1.0f;  // self loop
}
__global__ void deg_scatter_k(const int* __restrict__ dst, float* __restrict__ deg) {
    int e = blockIdx.x * 256 + threadIdx.x;
    atomicAdd(&deg[dst[e]], 1.0f);
}
__global__ void dinv_k(const float* __restrict__ deg, float* __restrict__ dinv) {
    int i = blockIdx.x * 256 + threadIdx.x;
    dinv[i] = rsqrtf(deg[i]);
}
// exclusive scan of in-degree counts (deg[i]-1), 4096 entries, single block
__global__ __launch_bounds__(1024)
void scan_offsets_k(const float* __restrict__ deg, int* __restrict__ offs,
                    int* __restrict__ cursor) {
    __shared__ int part[1024];
    const int t = threadIdx.x;
    int c0 = (int)deg[t * 4 + 0] - 1;
    int c1 = (int)deg[t * 4 + 1] - 1;
    int c2 = (int)deg[t * 4 + 2] - 1;
    int c3 = (int)deg[t * 4 + 3] - 1;
    part[t] = c0 + c1 + c2 + c3;
    __syncthreads();
    for (int off = 1; off < 1024; off <<= 1) {
        int v = (t >= off) ? part[t - off] : 0;
        __syncthreads();
        part[t] += v;
        __syncthreads();
    }
    int base = (t == 0) ? 0 : part[t - 1];
    offs[t * 4 + 0] = base;
    offs[t * 4 + 1] = base + c0;
    offs[t * 4 + 2] = base + c0 + c1;
    offs[t * 4 + 3] = base + c0 + c1 + c2;
    cursor[t * 4 + 0] = base;
    cursor[t * 4 + 1] = base + c0;
    cursor[t * 4 + 2] = base + c0 + c1;
    cursor[t * 4 + 3] = base + c0 + c1 + c2;
    if (t == 1023) offs[4096] = part[1023];
}
__global__ void csr_fill_k(const int* __restrict__ src, const int* __restrict__ dst,
                           int* __restrict__ cursor, int* __restrict__ csr_src) {
    int e = blockIdx.x * 256 + threadIdx.x;
    int pos = atomicAdd(&cursor[dst[e]], 1);
    csr_src[pos] = src[e];
}

// ---------------- GCN gather: 4 nodes/block, 64 lanes x float4 per node ----------------
__global__ __launch_bounds__(256)
void gcn_gather_k(const float* __restrict__ xw, const float* __restrict__ dinv,
                  const int* __restrict__ offs, const int* __restrict__ csr_src,
                  float* __restrict__ agg) {
    const int node = blockIdx.x * 4 + (threadIdx.x >> 6);
    const int c = (threadIdx.x & 63) * 4;
    const float dd = dinv[node];
    float4 a = *(const float4*)&xw[(size_t)node * HC + c];
    const float self = dd * dd;
    float4 acc = make_float4(a.x * self, a.y * self, a.z * self, a.w * self);
    const int beg = offs[node], end = offs[node + 1];
    for (int e = beg; e < end; e++) {
        int s = csr_src[e];
        float coef = dinv[s] * dd;
        const float4 v = *(const float4*)&xw[(size_t)s * HC + c];
        acc.x += v.x * coef;
        acc.y += v.y * coef;
        acc.z += v.z * coef;
        acc.w += v.w * coef;
    }
    *(float4*)&agg[(size_t)node * HC + c] = acc;
}

// ---------------- fp32 -> bf16 convert (float4 -> ushort4) ----------------
__global__ void cvt_bf16_k(const float* __restrict__ in, ushort_t* __restrict__ out) {
    int i = (blockIdx.x * 256 + threadIdx.x) * 4;
    float4 v = *(const float4*)&in[i];
    ushort4 o;
    o.x = f2bf(v.x); o.y = f2bf(v.y); o.z = f2bf(v.z); o.w = f2bf(v.w);
    *(ushort4*)&out[i] = o;
}

// ---------------- bf16-MFMA GEMM (unchanged this round) ----------------
__global__ __launch_bounds__(256)
void gemm_bf_k(const float* __restrict__ X, const float* __restrict__ W,
               const float* __restrict__ bias1, const float* __restrict__ bias2,
               const float* __restrict__ res1, const float* __restrict__ res2, float res2scale,
               float* __restrict__ out, int K, int M, int dorelu, int obf)
{
    __shared__ ushort_t As[64][72];
    __shared__ ushort_t Bs[64][72];
    const int t = threadIdx.x;
    const int w = t >> 6, lane = t & 63;
    const int m = lane & 15, quad = lane >> 4;
    const int row0 = blockIdx.y << 6, col0 = blockIdx.x << 6;
    const int sr = t >> 2;
    const int sc = (t & 3) << 4;

    f32x4 acc[4] = {};
    for (int k0 = 0; k0 < K; k0 += 64) {
        const float* xp = &X[(size_t)(row0 + sr) * K + k0 + sc];
        const float* wp = &W[(size_t)(col0 + sr) * K + k0 + sc];
        float4 xa = *(const float4*)xp,     xb = *(const float4*)(xp + 4);
        float4 xc = *(const float4*)(xp + 8), xd = *(const float4*)(xp + 12);
        float4 wa = *(const float4*)wp,     wb = *(const float4*)(wp + 4);
        float4 wc = *(const float4*)(wp + 8), wd = *(const float4*)(wp + 12);
        __syncthreads();
        {
            __attribute__((aligned(16))) ushort_t tx[16];
            tx[0]=f2bf(xa.x); tx[1]=f2bf(xa.y); tx[2]=f2bf(xa.z); tx[3]=f2bf(xa.w);
            tx[4]=f2bf(xb.x); tx[5]=f2bf(xb.y); tx[6]=f2bf(xb.z); tx[7]=f2bf(xb.w);
            tx[8]=f2bf(xc.x); tx[9]=f2bf(xc.y); tx[10]=f2bf(xc.z); tx[11]=f2bf(xc.w);
            tx[12]=f2bf(xd.x); tx[13]=f2bf(xd.y); tx[14]=f2bf(xd.z); tx[15]=f2bf(xd.w);
            *(uint4*)&As[sr][sc] = *(const uint4*)&tx[0];
            *(uint4*)&As[sr][sc + 8] = *(const uint4*)&tx[8];
            __attribute__((aligned(16))) ushort_t tw[16];
            tw[0]=f2bf(wa.x); tw[1]=f2bf(wa.y); tw[2]=f2bf(wa.z); tw[3]=f2bf(wa.w);
            tw[4]=f2bf(wb.x); tw[5]=f2bf(wb.y); tw[6]=f2bf(wb.z); tw[7]=f2bf(wb.w);
            tw[8]=f2bf(wc.x); tw[9]=f2bf(wc.y); tw[10]=f2bf(wc.z); tw[11]=f2bf(wc.w);
            tw[12]=f2bf(wd.x); tw[13]=f2bf(wd.y); tw[14]=f2bf(wd.z); tw[15]=f2bf(wd.w);
            *(uint4*)&Bs[sr][sc] = *(const uint4*)&tw[0];
            *(uint4*)&Bs[sr][sc + 8] = *(const uint4*)&tw[8];
        }
        __syncthreads();
        #pragma unroll
        for (int kc = 0; kc < 2; kc++) {
            bf16x8 af = *(const bf16x8*)&As[(w << 4) + m][kc * 32 + quad * 8];
            #pragma unroll
            for (int cb = 0; cb < 4; cb++) {
                bf16x8 bf = *(const bf16x8*)&Bs[cb * 16 + m][kc * 32 + quad * 8];
                acc[cb] = __builtin_amdgcn_mfma_f32_16x16x32_bf16(af, bf, acc[cb], 0, 0, 0);
            }
        }
    }
    #pragma unroll
    for (int cb = 0; cb < 4; cb++) {
        #pragma unroll
        for (int r = 0; r < 4; r++) {
            const int row = row0 + (w << 4) + quad * 4 + r;
            const int col = col0 + cb * 16 + m;
            float v = acc[cb][r];
            if (bias1) v += bias1[col];
            if (bias2) v += bias2[col];
            if (res1) v += res1[(size_t)row * M + col];
            if (res2) v += res2scale * res2[(size_t)row * M + col];
            if (dorelu) v = fmaxf(v, 0.f);
            if (obf) ((ushort_t*)out)[(size_t)row * M + col] = f2bf(v);
            else out[(size_t)row * M + col] = v;
        }
    }
}

// ---------------- K/V bf16 prep: Kb[h][n][d], Vtb[h][d][n] ----------------
__global__ __launch_bounds__(256)
void kv_prep_k(const float* __restrict__ qkv, ushort_t* __restrict__ Kb,
               ushort_t* __restrict__ Vtb)
{
    __shared__ ushort_t Vs[64][72];
    const int h = blockIdx.y;
    const int n0 = blockIdx.x << 6;
    const int t = threadIdx.x;
    for (int u = t; u < 1024; u += 256) {
        int r = u >> 4, c = u & 15;
        const float* kp = &qkv[(size_t)(n0 + r) * 768 + 256 + h * 64 + c * 4];
        float4 kv = *(const float4*)kp;
        float4 vv = *(const float4*)(kp + 256);
        ushort4 kb;
        kb.x = f2bf(kv.x); kb.y = f2bf(kv.y); kb.z = f2bf(kv.z); kb.w = f2bf(kv.w);
        *(ushort4*)&Kb[((size_t)(h * 4096 + n0 + r)) * 64 + c * 4] = kb;
        ushort4 vb;
        vb.x = f2bf(vv.x); vb.y = f2bf(vv.y); vb.z = f2bf(vv.z); vb.w = f2bf(vv.w);
        *(ushort4*)&Vs[r][c * 4] = vb;
    }
    __syncthreads();
    int d = t >> 2, kc = t & 3;
    __attribute__((aligned(16))) ushort_t vals[16];
    #pragma unroll
    for (int k = 0; k < 16; k++) vals[k] = Vs[kc * 16 + k][d];
    ushort_t* op = &Vtb[((size_t)(h * 64 + d)) * 4096 + n0 + kc * 16];
    *(uint4*)op = *(const uint4*)&vals[0];
    *(uint4*)(op + 8) = *(const uint4*)&vals[8];
}

// ---------------- split-K MFMA flash attention partials ----------------
// bf16 P in LDS (direct A-frag reads); l accumulated via ones-column MFMA.
__global__ __launch_bounds__(256)
void attn_part_k(const float* qkv, const ushort_t* __restrict__ Kb,
                 const ushort_t* __restrict__ Vtb, ushort_t* opart,
                 float* __restrict__ m_part, float* __restrict__ l_part)
{
    __shared__ ushort_t Kt[64][72];
    __shared__ ushort_t Vt[64][72];
    __shared__ ushort_t Plb[4][16][72];   // per-wave bf16 P [qrow][key]
    const int h = blockIdx.y & 3;
    const int split = blockIdx.y >> 2;
    const int q0 = blockIdx.x << 6;
    const int t = threadIdx.x;
    const int w = t >> 6, lane = t & 63;
    const int m = lane & 15, quad = lane >> 4;

    bf16x8 qf[2];
    #pragma unroll
    for (int kc = 0; kc < 2; kc++) {
        const float* qp = &qkv[(size_t)(q0 + w * 16 + m) * 768 + h * 64 + kc * 32 + quad * 8];
        float4 a = *(const float4*)qp;
        float4 b = *(const float4*)(qp + 4);
        qf[kc][0] = (short)f2bf(a.x * 0.125f);
        qf[kc][1] = (short)f2bf(a.y * 0.125f);
        qf[kc][2] = (short)f2bf(a.z * 0.125f);
        qf[kc][3] = (short)f2bf(a.w * 0.125f);
        qf[kc][4] = (short)f2bf(b.x * 0.125f);
        qf[kc][5] = (short)f2bf(b.y * 0.125f);
        qf[kc][6] = (short)f2bf(b.z * 0.125f);
        qf[kc][7] = (short)f2bf(b.w * 0.125f);
    }
    bf16x8 onesf;
    #pragma unroll
    for (int j = 0; j < 8; j++) onesf[j] = (short)0x3F80;   // bf16 1.0

    f32x4 o[4], ol;
    float mrow[4];
    #pragma unroll
    for (int i = 0; i < 4; i++) {
        o[i] = (f32x4){0.f, 0.f, 0.f, 0.f};
        mrow[i] = -1e30f;
    }
    ol = (f32x4){0.f, 0.f, 0.f, 0.f};

    for (int kb = split * 16; kb < split * 16 + 16; kb++) {
        __syncthreads();
        for (int u = t; u < 512; u += 256) {
            int r = u >> 3, c = u & 7;
            *(uint4*)&Kt[r][c * 8] = *(const uint4*)&Kb[((size_t)(h * 4096 + kb * 64 + r)) * 64 + c * 8];
            *(uint4*)&Vt[r][c * 8] = *(const uint4*)&Vtb[((size_t)(h * 64 + r)) * 4096 + kb * 64 + c * 8];
        }
        __syncthreads();

        f32x4 s[4];
        #pragma unroll
        for (int b = 0; b < 4; b++) s[b] = (f32x4){0.f, 0.f, 0.f, 0.f};
        #pragma unroll
        for (int b = 0; b < 4; b++)
            #pragma unroll
            for (int kc = 0; kc < 2; kc++) {
                bf16x8 kf = *(const bf16x8*)&Kt[b * 16 + m][kc * 32 + quad * 8];
                s[b] = __builtin_amdgcn_mfma_f32_16x16x32_bf16(qf[kc], kf, s[b], 0, 0, 0);
            }

        #pragma unroll
        for (int r = 0; r < 4; r++) {
            float mx = fmaxf(fmaxf(s[0][r], s[1][r]), fmaxf(s[2][r], s[3][r]));
            #pragma unroll
            for (int off = 1; off < 16; off <<= 1)
                mx = fmaxf(mx, __shfl_xor(mx, off));
            float mn = fmaxf(mrow[r], mx);
            float alpha = __expf(mrow[r] - mn);
            mrow[r] = mn;
            #pragma unroll
            for (int b = 0; b < 4; b++)
                Plb[w][quad * 4 + r][b * 16 + m] = f2bf(__expf(s[b][r] - mn));
            o[0][r] *= alpha; o[1][r] *= alpha;
            o[2][r] *= alpha; o[3][r] *= alpha;
            ol[r] *= alpha;
        }

        // PV + l-accumulation (P written/read by same wave; no barrier needed)
        #pragma unroll
        for (int kc = 0; kc < 2; kc++) {
            bf16x8 pa = *(const bf16x8*)&Plb[w][m][kc * 32 + quad * 8];
            #pragma unroll
            for (int nb = 0; nb < 4; nb++) {
                bf16x8 vf = *(const bf16x8*)&Vt[nb * 16 + m][kc * 32 + quad * 8];
                o[nb] = __builtin_amdgcn_mfma_f32_16x16x32_bf16(pa, vf, o[nb], 0, 0, 0);
            }
            ol = __builtin_amdgcn_mfma_f32_16x16x32_bf16(pa, onesf, ol, 0, 0, 0);
        }
    }

    #pragma unroll
    for (int nb = 0; nb < 4; nb++)
        #pragma unroll
        for (int r = 0; r < 4; r++) {
            int q = q0 + w * 16 + quad * 4 + r;
            opart[(size_t)q * 1536 + 512 + split * 256 + h * 64 + nb * 16 + m] = f2bf(o[nb][r]);
        }
    if (m == 0) {
        #pragma unroll
        for (int r = 0; r < 4; r++) {
            int q = q0 + w * 16 + quad * 4 + r;
            m_part[(split * 4 + h) * 4096 + q] = mrow[r];
            l_part[(split * 4 + h) * 4096 + q] = ol[r];
        }
    }
}

// merge 4 splits
__global__ __launch_bounds__(256)
void attn_merge_k(const ushort_t* __restrict__ opart, const float* __restrict__ m_part,
                  const float* __restrict__ l_part, float* __restrict__ att)
{
    int idx = blockIdx.x * 256 + threadIdx.x;
    int q = idx >> 8, c = idx & 255;
    int h = c >> 6, d = c & 63;
    float ms[4];
    float mmax = -1e30f;
    #pragma unroll
    for (int s = 0; s < 4; s++) {
        ms[s] = m_part[(s * 4 + h) * 4096 + q];
        mmax = fmaxf(mmax, ms[s]);
    }
    float onum = 0.f, lden = 0.f;
    #pragma unroll
    for (int s = 0; s < 4; s++) {
        float wgt = __expf(ms[s] - mmax);
        float ov = bf2f(opart[(size_t)q * 1536 + 512 + s * 256 + h * 64 + d]);
        onum += wgt * ov;
        lden += wgt * l_part[(s * 4 + h) * 4096 + q];
    }
    att[(size_t)q * 256 + c] = onum / lden;
}

// ---------------- symmetrized final MLP, MFMA bf16 ----------------
__global__ __launch_bounds__(256)
void sym_mlp_mfma_k(const ushort_t* __restrict__ Tb, const ushort_t* __restrict__ Wb,
                    const float* __restrict__ b2, float* __restrict__ out)
{
    __shared__ ushort_t As[128][72];
    __shared__ ushort_t Bs[128][72];
    const int t = threadIdx.x;
    const int w = t >> 6, lane = t & 63;
    const int m = lane & 15, quad = lane >> 4;
    const int wr = (w >> 1) * 64, wc = (w & 1) * 64;
    const int ri = blockIdx.y * 128, rj = blockIdx.x * 128;

    f32x4 acc[4][4] = {};
    for (int kk = 0; kk < 8; kk++) {
        const int k0 = kk * 64;
        const ushort_t* Asrc = (k0 < 256) ? Tb : Wb;
        const ushort_t* Bsrc = (k0 < 256) ? Wb : Tb;
        const int kcol = k0 & 255;
        __syncthreads();
        #pragma unroll
        for (int i = 0; i < 4; i++) {
            int s = t + i * 256;
            int row = s >> 3, ch = (s & 7) * 8;
            *(uint4*)&As[row][ch] = *(const uint4*)&Asrc[(size_t)(ri + row) * 256 + kcol + ch];
            *(uint4*)&Bs[row][ch] = *(const uint4*)&Bsrc[(size_t)(rj + row) * 256 + kcol + ch];
        }
        __syncthreads();
        #pragma unroll
        for (int kc = 0; kc < 2; kc++) {
            bf16x8 af[4], bfr[4];
            #pragma unroll
            for (int rb = 0; rb < 4; rb++)
                af[rb] = *(const bf16x8*)&As[wr + rb * 16 + m][kc * 32 + quad * 8];
            #pragma unroll
            for (int cb = 0; cb < 4; cb++)
                bfr[cb] = *(const bf16x8*)&Bs[wc + cb * 16 + m][kc * 32 + quad * 8];
            #pragma unroll
            for (int rb = 0; rb < 4; rb++)
                #pragma unroll
                for (int cb = 0; cb < 4; cb++)
                    acc[rb][cb] = __builtin_amdgcn_mfma_f32_16x16x32_bf16(af[rb], bfr[cb], acc[rb][cb], 0, 0, 0);
        }
    }
    #pragma unroll
    for (int rb = 0; rb < 4; rb++) {
        #pragma unroll
        for (int r = 0; r < 4; r++) {
            const int gr = ri + wr + rb * 16 + quad * 4 + r;
            const float br = b2[gr];
            #pragma unroll
            for (int cb = 0; cb < 4; cb++) {
                const int gc = rj + wc + cb * 16 + m;
                out[(size_t)gr * NN + gc] = 0.5f * (acc[rb][cb][r] + br + b2[gc]);
            }
        }
    }
}

// ---------------- launch ----------------
extern "C" void kernel_launch(void* const* d_in, const int* in_sizes, int n_in,
                              void* d_out, int out_size, void* d_ws, size_t ws_size,
                              hipStream_t stream) {
    (void)in_sizes; (void)n_in; (void)out_size; (void)ws_size;
    const float* x = (const float*)d_in[0];
    const int* ei = (const int*)d_in[1];
    const int* src = ei;
    const int* dst = ei + EE;

    float* ws = (float*)d_ws;
    const int NH = NN * HC;          // 1,048,576 floats
    float* h0  = ws;                 // current h
    float* hb  = ws + 1 * NH;        // gcn agg; later doubles as Tb/W2b (bf16)
    float* hc  = ws + 2 * NH;        // "out"  (doubles as bf16 K/Vt during attention)
    float* att = ws + 3 * NH;        // xw / attention out (reused)
    float* qkv = ws + 4 * NH;        // N x 768 ; K/V cols double as bf16 o-partials
    float* ffh = ws + 4 * NH;        // N x 512 (qkv dead by then)
    float* deg = ws + 7 * NH;
    float* dinv = deg + NN;
    int* offs    = (int*)(dinv + NN);       // 4097 ints
    int* cursor  = offs + 4100;             // 4096 ints
    int* csr_src = cursor + 4096;           // 65536 ints
    float* m_part = (float*)(csr_src + EE); // 65536 floats
    float* l_part = m_part + 65536;         // 65536 floats
    ushort_t* Kb  = (ushort_t*)hc;   // [4][4096][64] bf16
    ushort_t* Vtb = Kb + NH;         // [4][64][4096] bf16
    ushort_t* Tb  = (ushort_t*)hb;   // [4096][256] bf16  (after hb dead)
    ushort_t* W2b = Tb + NH;         // [4096][256] bf16

    // degree + CSR (graph static across both GPS layers)
    deg_init_k<<<NN / 256, 256, 0, stream>>>(deg);
    deg_scatter_k<<<EE / 256, 256, 0, stream>>>(dst, deg);
    dinv_k<<<NN / 256, 256, 0, stream>>>(deg, dinv);
    scan_offsets_k<<<1, 1024, 0, stream>>>(deg, offs, cursor);
    csr_fill_k<<<EE / 256, 256, 0, stream>>>(src, dst, cursor, csr_src);

    // pre: h0 = relu(x @ pre_w^T + pre_b)
    gemm_bf_k<<<dim3(4, 64), 256, 0, stream>>>(
        x, (const float*)d_in[2], (const float*)d_in[3], nullptr,
        nullptr, nullptr, 0.f, h0, 128, 256, 1, 0);

    for (int L = 0; L < 2; L++) {
        int B = 4 + L * 10;
        const float* gw = (const float*)d_in[B + 0];
        const float* gb = (const float*)d_in[B + 1];
        const float* iw = (const float*)d_in[B + 2];
        const float* ib = (const float*)d_in[B + 3];
        const float* ow = (const float*)d_in[B + 4];
        const float* ob = (const float*)d_in[B + 5];
        const float* w1 = (const float*)d_in[B + 6];
        const float* b1 = (const float*)d_in[B + 7];
        const float* w2 = (const float*)d_in[B + 8];
        const float* b2 = (const float*)d_in[B + 9];

        gemm_bf_k<<<dim3(4, 64), 256, 0, stream>>>(
            h0, gw, nullptr, nullptr, nullptr, nullptr, 0.f, att, 256, 256, 0, 0);
        gcn_gather_k<<<NN / 4, 256, 0, stream>>>(att, dinv, offs, csr_src, hb);
        gemm_bf_k<<<dim3(12, 64), 256, 0, stream>>>(
            h0, iw, ib, nullptr, nullptr, nullptr, 0.f, qkv, 256, 768, 0, 0);
        kv_prep_k<<<dim3(64, 4), 256, 0, stream>>>(qkv, Kb, Vtb);
        attn_part_k<<<dim3(64, 16), 256, 0, stream>>>(
            qkv, Kb, Vtb, (ushort_t*)qkv, m_part, l_part);
        attn_merge_k<<<NN, 256, 0, stream>>>(
            (const ushort_t*)qkv, m_part, l_part, att);
        gemm_bf_k<<<dim3(4, 64), 256, 0, stream>>>(
            att, ow, ob, gb, hb, h0, 2.0f, hc, 256, 256, 0, 0);
        gemm_bf_k<<<dim3(8, 64), 256, 0, stream>>>(
            hc, w1, b1, nullptr, nullptr, nullptr, 0.f, ffh, 256, 512, 1, 0);
        gemm_bf_k<<<dim3(4, 64), 256, 0, stream>>>(
            ffh, w2, b2, nullptr, hc, nullptr, 0.f, h0, 512, 256, 1, 0);
    }

    // Tb(bf16) = relu(h0 @ mlp_w1^T + mlp_b1)
    gemm_bf_k<<<dim3(4, 64), 256, 0, stream>>>(
        h0, (const float*)d_in[24], (const float*)d_in[25], nullptr,
        nullptr, nullptr, 0.f, (float*)Tb, 256, 256, 1, 1);
    // W2b = bf16(mlp_w2)
    cvt_bf16_k<<<NH / 1024, 256, 0, stream>>>((const float*)d_in[26], W2b);
    // out = 0.5*(delta + delta^T) via K=512 concat GEMM
    sym_mlp_mfma_k<<<dim3(32, 32), 256, 0, stream>>>(
        Tb, W2b, (const float*)d_in[27], (float*)d_out);
}

// Round 10
// 466.030 us; speedup vs baseline: 5.0611x; 1.0603x over previous
//
#include <hip/hip_runtime.h>

#define NN 4096
#define EE 65536
#define HC 256   // hidden channels

typedef unsigned short ushort_t;
typedef __attribute__((ext_vector_type(8))) short bf16x8;
typedef __attribute__((ext_vector_type(4))) float f32x4;

__device__ __forceinline__ ushort_t f2bf(float f) {
    unsigned int u = __float_as_uint(f);
    unsigned int r = (u + 0x7fffu + ((u >> 16) & 1u)) >> 16;
    return (ushort_t)r;
}
__device__ __forceinline__ float bf2f(ushort_t u) {
    return __uint_as_float(((unsigned int)u) << 16);
}
// pack two floats to bf16 pair (round-half-up), a in low 16 (lower address)
__device__ __forceinline__ unsigned int pack2bf(float a, float b) {
    unsigned int ua = __float_as_uint(a) + 0x8000u;
    unsigned int ub = __float_as_uint(b) + 0x8000u;
    return __builtin_amdgcn_perm(ub, ua, 0x07060302u);
}

// ---------------- degree / CSR build ----------------
__global__ void deg_init_k(float* __restrict__ deg) {
    int i = blockIdx.x * 256 + threadIdx.x;
    deg[i] = 1.0f;  // self loop
}
__global__ void deg_scatter_k(const int* __restrict__ dst, float* __restrict__ deg) {
    int e = blockIdx.x * 256 + threadIdx.x;
    atomicAdd(&deg[dst[e]], 1.0f);
}
__global__ void dinv_k(const float* __restrict__ deg, float* __restrict__ dinv) {
    int i = blockIdx.x * 256 + threadIdx.x;
    dinv[i] = rsqrtf(deg[i]);
}
__global__ __launch_bounds__(1024)
void scan_offsets_k(const float* __restrict__ deg, int* __restrict__ offs,
                    int* __restrict__ cursor) {
    __shared__ int part[1024];
    const int t = threadIdx.x;
    int c0 = (int)deg[t * 4 + 0] - 1;
    int c1 = (int)deg[t * 4 + 1] - 1;
    int c2 = (int)deg[t * 4 + 2] - 1;
    int c3 = (int)deg[t * 4 + 3] - 1;
    part[t] = c0 + c1 + c2 + c3;
    __syncthreads();
    for (int off = 1; off < 1024; off <<= 1) {
        int v = (t >= off) ? part[t - off] : 0;
        __syncthreads();
        part[t] += v;
        __syncthreads();
    }
    int base = (t == 0) ? 0 : part[t - 1];
    offs[t * 4 + 0] = base;
    offs[t * 4 + 1] = base + c0;
    offs[t * 4 + 2] = base + c0 + c1;
    offs[t * 4 + 3] = base + c0 + c1 + c2;
    cursor[t * 4 + 0] = base;
    cursor[t * 4 + 1] = base + c0;
    cursor[t * 4 + 2] = base + c0 + c1;
    cursor[t * 4 + 3] = base + c0 + c1 + c2;
    if (t == 1023) offs[4096] = part[1023];
}
__global__ void csr_fill_k(const int* __restrict__ src, const int* __restrict__ dst,
                           int* __restrict__ cursor, int* __restrict__ csr_src) {
    int e = blockIdx.x * 256 + threadIdx.x;
    int pos = atomicAdd(&cursor[dst[e]], 1);
    csr_src[pos] = src[e];
}

// ---------------- GCN gather ----------------
__global__ __launch_bounds__(256)
void gcn_gather_k(const float* __restrict__ xw, const float* __restrict__ dinv,
                  const int* __restrict__ offs, const int* __restrict__ csr_src,
                  float* __restrict__ agg) {
    const int node = blockIdx.x * 4 + (threadIdx.x >> 6);
    const int c = (threadIdx.x & 63) * 4;
    const float dd = dinv[node];
    float4 a = *(const float4*)&xw[(size_t)node * HC + c];
    const float self = dd * dd;
    float4 acc = make_float4(a.x * self, a.y * self, a.z * self, a.w * self);
    const int beg = offs[node], end = offs[node + 1];
    for (int e = beg; e < end; e++) {
        int s = csr_src[e];
        float coef = dinv[s] * dd;
        const float4 v = *(const float4*)&xw[(size_t)s * HC + c];
        acc.x += v.x * coef;
        acc.y += v.y * coef;
        acc.z += v.z * coef;
        acc.w += v.w * coef;
    }
    *(float4*)&agg[(size_t)node * HC + c] = acc;
}

// ---------------- fp32 -> bf16 convert ----------------
__global__ void cvt_bf16_k(const float* __restrict__ in, ushort_t* __restrict__ out) {
    int i = (blockIdx.x * 256 + threadIdx.x) * 4;
    float4 v = *(const float4*)&in[i];
    unsigned int d0 = pack2bf(v.x, v.y), d1 = pack2bf(v.z, v.w);
    *(uint2*)&out[i] = make_uint2(d0, d1);
}

// ---------------- bf16-MFMA GEMM, optional dual weight region ----------------
// region1: cols [0,colsplit) from W -> out (stride M); region2: cols >= colsplit
// from W2 (bias bias_r2) -> out2 (stride M2). colsplit=0 -> single region.
__global__ __launch_bounds__(256)
void gemm_bf_k(const float* __restrict__ X, const float* __restrict__ W,
               const float* __restrict__ bias1, const float* __restrict__ bias2,
               const float* __restrict__ res1, const float* __restrict__ res2, float res2scale,
               float* __restrict__ out, int K, int M, int dorelu, int obf,
               int colsplit, const float* __restrict__ W2,
               const float* __restrict__ bias_r2, float* __restrict__ out2, int M2)
{
    __shared__ ushort_t As[64][72];
    __shared__ ushort_t Bs[64][72];
    const int t = threadIdx.x;
    const int w = t >> 6, lane = t & 63;
    const int m = lane & 15, quad = lane >> 4;
    const int row0 = blockIdx.y << 6, col0 = blockIdx.x << 6;
    const int sr = t >> 2;
    const int sc = (t & 3) << 4;

    const float* Wu = W;
    const float* b1u = bias1;
    const float* b2u = bias2;
    float* outu = out;
    int Mu = M, colu = col0;
    if (colsplit > 0 && col0 >= colsplit) {
        Wu = W2; b1u = bias_r2; b2u = nullptr;
        outu = out2; Mu = M2; colu = col0 - colsplit;
    }

    f32x4 acc[4] = {};
    for (int k0 = 0; k0 < K; k0 += 64) {
        const float* xp = &X[(size_t)(row0 + sr) * K + k0 + sc];
        const float* wp = &Wu[(size_t)(colu + sr) * K + k0 + sc];
        float4 xa = *(const float4*)xp,       xb = *(const float4*)(xp + 4);
        float4 xc = *(const float4*)(xp + 8), xd = *(const float4*)(xp + 12);
        float4 wa = *(const float4*)wp,       wb = *(const float4*)(wp + 4);
        float4 wc = *(const float4*)(wp + 8), wd = *(const float4*)(wp + 12);
        __syncthreads();
        {
            unsigned int tx[8];
            tx[0] = pack2bf(xa.x, xa.y); tx[1] = pack2bf(xa.z, xa.w);
            tx[2] = pack2bf(xb.x, xb.y); tx[3] = pack2bf(xb.z, xb.w);
            tx[4] = pack2bf(xc.x, xc.y); tx[5] = pack2bf(xc.z, xc.w);
            tx[6] = pack2bf(xd.x, xd.y); tx[7] = pack2bf(xd.z, xd.w);
            *(uint4*)&As[sr][sc]     = *(const uint4*)&tx[0];
            *(uint4*)&As[sr][sc + 8] = *(const uint4*)&tx[4];
            unsigned int tw[8];
            tw[0] = pack2bf(wa.x, wa.y); tw[1] = pack2bf(wa.z, wa.w);
            tw[2] = pack2bf(wb.x, wb.y); tw[3] = pack2bf(wb.z, wb.w);
            tw[4] = pack2bf(wc.x, wc.y); tw[5] = pack2bf(wc.z, wc.w);
            tw[6] = pack2bf(wd.x, wd.y); tw[7] = pack2bf(wd.z, wd.w);
            *(uint4*)&Bs[sr][sc]     = *(const uint4*)&tw[0];
            *(uint4*)&Bs[sr][sc + 8] = *(const uint4*)&tw[4];
        }
        __syncthreads();
        #pragma unroll
        for (int kc = 0; kc < 2; kc++) {
            bf16x8 af = *(const bf16x8*)&As[(w << 4) + m][kc * 32 + quad * 8];
            #pragma unroll
            for (int cb = 0; cb < 4; cb++) {
                bf16x8 bf = *(const bf16x8*)&Bs[cb * 16 + m][kc * 32 + quad * 8];
                acc[cb] = __builtin_amdgcn_mfma_f32_16x16x32_bf16(af, bf, acc[cb], 0, 0, 0);
            }
        }
    }
    #pragma unroll
    for (int cb = 0; cb < 4; cb++) {
        #pragma unroll
        for (int r = 0; r < 4; r++) {
            const int row = row0 + (w << 4) + quad * 4 + r;
            const int col = colu + cb * 16 + m;
            float v = acc[cb][r];
            if (b1u) v += b1u[col];
            if (b2u) v += b2u[col];
            if (res1) v += res1[(size_t)row * Mu + col];
            if (res2) v += res2scale * res2[(size_t)row * Mu + col];
            if (dorelu) v = fmaxf(v, 0.f);
            if (obf) ((ushort_t*)outu)[(size_t)row * Mu + col] = f2bf(v);
            else outu[(size_t)row * Mu + col] = v;
        }
    }
}

// ---------------- K/V bf16 prep: Kb[h][n][d], Vtb[h][d][n] ----------------
__global__ __launch_bounds__(256)
void kv_prep_k(const float* __restrict__ qkv, ushort_t* __restrict__ Kb,
               ushort_t* __restrict__ Vtb)
{
    __shared__ ushort_t Vs[64][72];
    const int h = blockIdx.y;
    const int n0 = blockIdx.x << 6;
    const int t = threadIdx.x;
    for (int u = t; u < 1024; u += 256) {
        int r = u >> 4, c = u & 15;
        const float* kp = &qkv[(size_t)(n0 + r) * 768 + 256 + h * 64 + c * 4];
        float4 kv = *(const float4*)kp;
        float4 vv = *(const float4*)(kp + 256);
        *(uint2*)&Kb[((size_t)(h * 4096 + n0 + r)) * 64 + c * 4] =
            make_uint2(pack2bf(kv.x, kv.y), pack2bf(kv.z, kv.w));
        *(uint2*)&Vs[r][c * 4] =
            make_uint2(pack2bf(vv.x, vv.y), pack2bf(vv.z, vv.w));
    }
    __syncthreads();
    int d = t >> 2, kc = t & 3;
    __attribute__((aligned(16))) ushort_t vals[16];
    #pragma unroll
    for (int k = 0; k < 16; k++) vals[k] = Vs[kc * 16 + k][d];
    ushort_t* op = &Vtb[((size_t)(h * 64 + d)) * 4096 + n0 + kc * 16];
    *(uint4*)op = *(const uint4*)&vals[0];
    *(uint4*)(op + 8) = *(const uint4*)&vals[8];
}

// ---------------- split-K MFMA flash attention partials ----------------
// Kt rows permuted so lane m's score blocks hold consecutive keys 4m..4m+3:
// Kt[c] = K[4*(c&15) + (c>>4)]; Plb written as packed b64; V/P reads in
// natural key order (contraction index consistent on both sides).
__global__ __launch_bounds__(256)
void attn_part_k(const float* qkv, const ushort_t* __restrict__ Kb,
                 const ushort_t* __restrict__ Vtb, ushort_t* opart,
                 float* __restrict__ m_part, float* __restrict__ l_part)
{
    __shared__ ushort_t Kt[64][72];
    __shared__ ushort_t Vt[64][72];
    __shared__ ushort_t Plb[4][16][72];
    const int h = blockIdx.y & 3;
    const int split = blockIdx.y >> 2;
    const int q0 = blockIdx.x << 6;
    const int t = threadIdx.x;
    const int w = t >> 6, lane = t & 63;
    const int m = lane & 15, quad = lane >> 4;

    bf16x8 qf[2];
    #pragma unroll
    for (int kc = 0; kc < 2; kc++) {
        const float* qp = &qkv[(size_t)(q0 + w * 16 + m) * 768 + h * 64 + kc * 32 + quad * 8];
        float4 a = *(const float4*)qp;
        float4 b = *(const float4*)(qp + 4);
        qf[kc][0] = (short)f2bf(a.x * 0.125f);
        qf[kc][1] = (short)f2bf(a.y * 0.125f);
        qf[kc][2] = (short)f2bf(a.z * 0.125f);
        qf[kc][3] = (short)f2bf(a.w * 0.125f);
        qf[kc][4] = (short)f2bf(b.x * 0.125f);
        qf[kc][5] = (short)f2bf(b.y * 0.125f);
        qf[kc][6] = (short)f2bf(b.z * 0.125f);
        qf[kc][7] = (short)f2bf(b.w * 0.125f);
    }
    bf16x8 onesf;
    #pragma unroll
    for (int j = 0; j < 8; j++) onesf[j] = (short)0x3F80;

    f32x4 o[4], ol;
    float mrow[4];
    #pragma unroll
    for (int i = 0; i < 4; i++) {
        o[i] = (f32x4){0.f, 0.f, 0.f, 0.f};
        mrow[i] = -1e30f;
    }
    ol = (f32x4){0.f, 0.f, 0.f, 0.f};

    for (int kb = split * 16; kb < split * 16 + 16; kb++) {
        __syncthreads();
        for (int u = t; u < 512; u += 256) {
            int r = u >> 3, c = u & 7;
            int pr = ((r & 15) << 2) | (r >> 4);   // permuted key row for Kt
            *(uint4*)&Kt[r][c * 8] = *(const uint4*)&Kb[((size_t)(h * 4096 + kb * 64 + pr)) * 64 + c * 8];
            *(uint4*)&Vt[r][c * 8] = *(const uint4*)&Vtb[((size_t)(h * 64 + r)) * 4096 + kb * 64 + c * 8];
        }
        __syncthreads();

        f32x4 s[4];
        #pragma unroll
        for (int b = 0; b < 4; b++) s[b] = (f32x4){0.f, 0.f, 0.f, 0.f};
        #pragma unroll
        for (int b = 0; b < 4; b++)
            #pragma unroll
            for (int kc = 0; kc < 2; kc++) {
                bf16x8 kf = *(const bf16x8*)&Kt[b * 16 + m][kc * 32 + quad * 8];
                s[b] = __builtin_amdgcn_mfma_f32_16x16x32_bf16(qf[kc], kf, s[b], 0, 0, 0);
            }

        #pragma unroll
        for (int r = 0; r < 4; r++) {
            float mx = fmaxf(fmaxf(s[0][r], s[1][r]), fmaxf(s[2][r], s[3][r]));
            #pragma unroll
            for (int off = 1; off < 16; off <<= 1)
                mx = fmaxf(mx, __shfl_xor(mx, off));
            float mn = fmaxf(mrow[r], mx);
            float alpha = __expf(mrow[r] - mn);
            mrow[r] = mn;
            // s[b][r] is key 4m+b -> one packed 8B store of 4 consecutive keys
            unsigned int d0 = pack2bf(__expf(s[0][r] - mn), __expf(s[1][r] - mn));
            unsigned int d1 = pack2bf(__expf(s[2][r] - mn), __expf(s[3][r] - mn));
            *(uint2*)&Plb[w][quad * 4 + r][m * 4] = make_uint2(d0, d1);
            o[0][r] *= alpha; o[1][r] *= alpha;
            o[2][r] *= alpha; o[3][r] *= alpha;
            ol[r] *= alpha;
        }

        #pragma unroll
        for (int kc = 0; kc < 2; kc++) {
            bf16x8 pa = *(const bf16x8*)&Plb[w][m][kc * 32 + quad * 8];
            #pragma unroll
            for (int nb = 0; nb < 4; nb++) {
                bf16x8 vf = *(const bf16x8*)&Vt[nb * 16 + m][kc * 32 + quad * 8];
                o[nb] = __builtin_amdgcn_mfma_f32_16x16x32_bf16(pa, vf, o[nb], 0, 0, 0);
            }
            ol = __builtin_amdgcn_mfma_f32_16x16x32_bf16(pa, onesf, ol, 0, 0, 0);
        }
    }

    #pragma unroll
    for (int nb = 0; nb < 4; nb++)
        #pragma unroll
        for (int r = 0; r < 4; r++) {
            int q = q0 + w * 16 + quad * 4 + r;
            opart[(size_t)q * 1536 + 512 + split * 256 + h * 64 + nb * 16 + m] = f2bf(o[nb][r]);
        }
    if (m == 0) {
        #pragma unroll
        for (int r = 0; r < 4; r++) {
            int q = q0 + w * 16 + quad * 4 + r;
            m_part[(split * 4 + h) * 4096 + q] = mrow[r];
            l_part[(split * 4 + h) * 4096 + q] = ol[r];
        }
    }
}

// merge 4 splits
__global__ __launch_bounds__(256)
void attn_merge_k(const ushort_t* __restrict__ opart, const float* __restrict__ m_part,
                  const float* __restrict__ l_part, float* __restrict__ att)
{
    int idx = blockIdx.x * 256 + threadIdx.x;
    int q = idx >> 8, c = idx & 255;
    int h = c >> 6, d = c & 63;
    float ms[4];
    float mmax = -1e30f;
    #pragma unroll
    for (int s = 0; s < 4; s++) {
        ms[s] = m_part[(s * 4 + h) * 4096 + q];
        mmax = fmaxf(mmax, ms[s]);
    }
    float onum = 0.f, lden = 0.f;
    #pragma unroll
    for (int s = 0; s < 4; s++) {
        float wgt = __expf(ms[s] - mmax);
        float ov = bf2f(opart[(size_t)q * 1536 + 512 + s * 256 + h * 64 + d]);
        onum += wgt * ov;
        lden += wgt * l_part[(s * 4 + h) * 4096 + q];
    }
    att[(size_t)q * 256 + c] = onum / lden;
}

// ---------------- symmetrized final MLP, MFMA bf16 ----------------
__global__ __launch_bounds__(256)
void sym_mlp_mfma_k(const ushort_t* __restrict__ Tb, const ushort_t* __restrict__ Wb,
                    const float* __restrict__ b2, float* __restrict__ out)
{
    __shared__ ushort_t As[128][72];
    __shared__ ushort_t Bs[128][72];
    const int t = threadIdx.x;
    const int w = t >> 6, lane = t & 63;
    const int m = lane & 15, quad = lane >> 4;
    const int wr = (w >> 1) * 64, wc = (w & 1) * 64;
    const int ri = blockIdx.y * 128, rj = blockIdx.x * 128;

    f32x4 acc[4][4] = {};
    for (int kk = 0; kk < 8; kk++) {
        const int k0 = kk * 64;
        const ushort_t* Asrc = (k0 < 256) ? Tb : Wb;
        const ushort_t* Bsrc = (k0 < 256) ? Wb : Tb;
        const int kcol = k0 & 255;
        __syncthreads();
        #pragma unroll
        for (int i = 0; i < 4; i++) {
            int s = t + i * 256;
            int row = s >> 3, ch = (s & 7) * 8;
            *(uint4*)&As[row][ch] = *(const uint4*)&Asrc[(size_t)(ri + row) * 256 + kcol + ch];
            *(uint4*)&Bs[row][ch] = *(const uint4*)&Bsrc[(size_t)(rj + row) * 256 + kcol + ch];
        }
        __syncthreads();
        #pragma unroll
        for (int kc = 0; kc < 2; kc++) {
            bf16x8 af[4], bfr[4];
            #pragma unroll
            for (int rb = 0; rb < 4; rb++)
                af[rb] = *(const bf16x8*)&As[wr + rb * 16 + m][kc * 32 + quad * 8];
            #pragma unroll
            for (int cb = 0; cb < 4; cb++)
                bfr[cb] = *(const bf16x8*)&Bs[wc + cb * 16 + m][kc * 32 + quad * 8];
            #pragma unroll
            for (int rb = 0; rb < 4; rb++)
                #pragma unroll
                for (int cb = 0; cb < 4; cb++)
                    acc[rb][cb] = __builtin_amdgcn_mfma_f32_16x16x32_bf16(af[rb], bfr[cb], acc[rb][cb], 0, 0, 0);
        }
    }
    #pragma unroll
    for (int rb = 0; rb < 4; rb++) {
        #pragma unroll
        for (int r = 0; r < 4; r++) {
            const int gr = ri + wr + rb * 16 + quad * 4 + r;
            const float br = b2[gr];
            #pragma unroll
            for (int cb = 0; cb < 4; cb++) {
                const int gc = rj + wc + cb * 16 + m;
                out[(size_t)gr * NN + gc] = 0.5f * (acc[rb][cb][r] + br + b2[gc]);
            }
        }
    }
}

// ---------------- launch ----------------
extern "C" void kernel_launch(void* const* d_in, const int* in_sizes, int n_in,
                              void* d_out, int out_size, void* d_ws, size_t ws_size,
                              hipStream_t stream) {
    (void)in_sizes; (void)n_in; (void)out_size; (void)ws_size;
    const float* x = (const float*)d_in[0];
    const int* ei = (const int*)d_in[1];
    const int* src = ei;
    const int* dst = ei + EE;

    float* ws = (float*)d_ws;
    const int NH = NN * HC;          // 1,048,576 floats
    float* h0  = ws;
    float* hb  = ws + 1 * NH;
    float* hc  = ws + 2 * NH;
    float* att = ws + 3 * NH;
    float* qkv = ws + 4 * NH;
    float* ffh = ws + 4 * NH;        // reuses qkv region (dead by then)
    float* deg = ws + 7 * NH;
    float* dinv = deg + NN;
    int* offs    = (int*)(dinv + NN);
    int* cursor  = offs + 4100;
    int* csr_src = cursor + 4096;
    float* m_part = (float*)(csr_src + EE);
    float* l_part = m_part + 65536;
    ushort_t* Kb  = (ushort_t*)hc;
    ushort_t* Vtb = Kb + NH;
    ushort_t* Tb  = (ushort_t*)hb;
    ushort_t* W2b = Tb + NH;

    deg_init_k<<<NN / 256, 256, 0, stream>>>(deg);
    deg_scatter_k<<<EE / 256, 256, 0, stream>>>(dst, deg);
    dinv_k<<<NN / 256, 256, 0, stream>>>(deg, dinv);
    scan_offsets_k<<<1, 1024, 0, stream>>>(deg, offs, cursor);
    csr_fill_k<<<EE / 256, 256, 0, stream>>>(src, dst, cursor, csr_src);

    // pre: h0 = relu(x @ pre_w^T + pre_b)
    gemm_bf_k<<<dim3(4, 64), 256, 0, stream>>>(
        x, (const float*)d_in[2], (const float*)d_in[3], nullptr,
        nullptr, nullptr, 0.f, h0, 128, 256, 1, 0,
        0, nullptr, nullptr, nullptr, 0);

    for (int L = 0; L < 2; L++) {
        int B = 4 + L * 10;
        const float* gw = (const float*)d_in[B + 0];
        const float* gb = (const float*)d_in[B + 1];
        const float* iw = (const float*)d_in[B + 2];
        const float* ib = (const float*)d_in[B + 3];
        const float* ow = (const float*)d_in[B + 4];
        const float* ob = (const float*)d_in[B + 5];
        const float* w1 = (const float*)d_in[B + 6];
        const float* b1 = (const float*)d_in[B + 7];
        const float* w2 = (const float*)d_in[B + 8];
        const float* b2 = (const float*)d_in[B + 9];

        // fused: cols 0-255 = h0@gw^T -> att(xw); cols 256-1023 = h0@iw^T+ib -> qkv
        gemm_bf_k<<<dim3(16, 64), 256, 0, stream>>>(
            h0, gw, nullptr, nullptr, nullptr, nullptr, 0.f, att, 256, 256, 0, 0,
            256, iw, ib, qkv, 768);
        gcn_gather_k<<<NN / 4, 256, 0, stream>>>(att, dinv, offs, csr_src, hb);
        kv_prep_k<<<dim3(64, 4), 256, 0, stream>>>(qkv, Kb, Vtb);
        attn_part_k<<<dim3(64, 16), 256, 0, stream>>>(
            qkv, Kb, Vtb, (ushort_t*)qkv, m_part, l_part);
        attn_merge_k<<<NN, 256, 0, stream>>>(
            (const ushort_t*)qkv, m_part, l_part, att);
        gemm_bf_k<<<dim3(4, 64), 256, 0, stream>>>(
            att, ow, ob, gb, hb, h0, 2.0f, hc, 256, 256, 0, 0,
            0, nullptr, nullptr, nullptr, 0);
        gemm_bf_k<<<dim3(8, 64), 256, 0, stream>>>(
            hc, w1, b1, nullptr, nullptr, nullptr, 0.f, ffh, 256, 512, 1, 0,
            0, nullptr, nullptr, nullptr, 0);
        gemm_bf_k<<<dim3(4, 64), 256, 0, stream>>>(
            ffh, w2, b2, nullptr, hc, nullptr, 0.f, h0, 512, 256, 1, 0,
            0, nullptr, nullptr, nullptr, 0);
    }

    // Tb(bf16) = relu(h0 @ mlp_w1^T + mlp_b1)
    gemm_bf_k<<<dim3(4, 64), 256, 0, stream>>>(
        h0, (const float*)d_in[24], (const float*)d_in[25], nullptr,
        nullptr, nullptr, 0.f, (float*)Tb, 256, 256, 1, 1,
        0, nullptr, nullptr, nullptr, 0);
    // W2b = bf16(mlp_w2)
    cvt_bf16_k<<<NH / 1024, 256, 0, stream>>>((const float*)d_in[26], W2b);
    // out = 0.5*(delta + delta^T) via K=512 concat GEMM
    sym_mlp_mfma_k<<<dim3(32, 32), 256, 0, stream>>>(
        Tb, W2b, (const float*)d_in[27], (float*)d_out);
}

// Round 11
// 445.353 us; speedup vs baseline: 5.2960x; 1.0464x over previous
//
#include <hip/hip_runtime.h>

#define NN 4096
#define EE 65536
#define HC 256   // hidden channels

typedef unsigned short ushort_t;
typedef __attribute__((ext_vector_type(8))) short bf16x8;
typedef __attribute__((ext_vector_type(4))) float f32x4;

__device__ __forceinline__ ushort_t f2bf(float f) {
    unsigned int u = __float_as_uint(f);
    unsigned int r = (u + 0x7fffu + ((u >> 16) & 1u)) >> 16;
    return (ushort_t)r;
}
__device__ __forceinline__ float bf2f(ushort_t u) {
    return __uint_as_float(((unsigned int)u) << 16);
}
// pack two floats to bf16 pair (round-half-up), a in low 16 (lower address)
__device__ __forceinline__ unsigned int pack2bf(float a, float b) {
    unsigned int ua = __float_as_uint(a) + 0x8000u;
    unsigned int ub = __float_as_uint(b) + 0x8000u;
    return __builtin_amdgcn_perm(ub, ua, 0x07060302u);
}

// ---------------- degree / CSR build ----------------
__global__ void deg_init_k(float* __restrict__ deg) {
    int i = blockIdx.x * 256 + threadIdx.x;
    deg[i] = 1.0f;  // self loop
}
__global__ void deg_scatter_k(const int* __restrict__ dst, float* __restrict__ deg) {
    int e = blockIdx.x * 256 + threadIdx.x;
    atomicAdd(&deg[dst[e]], 1.0f);
}
__global__ void dinv_k(const float* __restrict__ deg, float* __restrict__ dinv) {
    int i = blockIdx.x * 256 + threadIdx.x;
    dinv[i] = rsqrtf(deg[i]);
}
__global__ __launch_bounds__(1024)
void scan_offsets_k(const float* __restrict__ deg, int* __restrict__ offs,
                    int* __restrict__ cursor) {
    __shared__ int part[1024];
    const int t = threadIdx.x;
    int c0 = (int)deg[t * 4 + 0] - 1;
    int c1 = (int)deg[t * 4 + 1] - 1;
    int c2 = (int)deg[t * 4 + 2] - 1;
    int c3 = (int)deg[t * 4 + 3] - 1;
    part[t] = c0 + c1 + c2 + c3;
    __syncthreads();
    for (int off = 1; off < 1024; off <<= 1) {
        int v = (t >= off) ? part[t - off] : 0;
        __syncthreads();
        part[t] += v;
        __syncthreads();
    }
    int base = (t == 0) ? 0 : part[t - 1];
    offs[t * 4 + 0] = base;
    offs[t * 4 + 1] = base + c0;
    offs[t * 4 + 2] = base + c0 + c1;
    offs[t * 4 + 3] = base + c0 + c1 + c2;
    cursor[t * 4 + 0] = base;
    cursor[t * 4 + 1] = base + c0;
    cursor[t * 4 + 2] = base + c0 + c1;
    cursor[t * 4 + 3] = base + c0 + c1 + c2;
    if (t == 1023) offs[4096] = part[1023];
}
__global__ void csr_fill_k(const int* __restrict__ src, const int* __restrict__ dst,
                           int* __restrict__ cursor, int* __restrict__ csr_src) {
    int e = blockIdx.x * 256 + threadIdx.x;
    int pos = atomicAdd(&cursor[dst[e]], 1);
    csr_src[pos] = src[e];
}

// ---------------- GCN gather ----------------
__global__ __launch_bounds__(256)
void gcn_gather_k(const float* __restrict__ xw, const float* __restrict__ dinv,
                  const int* __restrict__ offs, const int* __restrict__ csr_src,
                  float* __restrict__ agg) {
    const int node = blockIdx.x * 4 + (threadIdx.x >> 6);
    const int c = (threadIdx.x & 63) * 4;
    const float dd = dinv[node];
    float4 a = *(const float4*)&xw[(size_t)node * HC + c];
    const float self = dd * dd;
    float4 acc = make_float4(a.x * self, a.y * self, a.z * self, a.w * self);
    const int beg = offs[node], end = offs[node + 1];
    for (int e = beg; e < end; e++) {
        int s = csr_src[e];
        float coef = dinv[s] * dd;
        const float4 v = *(const float4*)&xw[(size_t)s * HC + c];
        acc.x += v.x * coef;
        acc.y += v.y * coef;
        acc.z += v.z * coef;
        acc.w += v.w * coef;
    }
    *(float4*)&agg[(size_t)node * HC + c] = acc;
}

// ---------------- fp32 -> bf16 convert ----------------
__global__ void cvt_bf16_k(const float* __restrict__ in, ushort_t* __restrict__ out) {
    int i = (blockIdx.x * 256 + threadIdx.x) * 4;
    float4 v = *(const float4*)&in[i];
    unsigned int d0 = pack2bf(v.x, v.y), d1 = pack2bf(v.z, v.w);
    *(uint2*)&out[i] = make_uint2(d0, d1);
}

// ---------------- bf16-MFMA GEMM, 64row x 32col tile (2 blocks/CU+), dual region ----
__global__ __launch_bounds__(256)
void gemm_bf_k(const float* __restrict__ X, const float* __restrict__ W,
               const float* __restrict__ bias1, const float* __restrict__ bias2,
               const float* __restrict__ res1, const float* __restrict__ res2, float res2scale,
               float* __restrict__ out, int K, int M, int dorelu, int obf,
               int colsplit, const float* __restrict__ W2,
               const float* __restrict__ bias_r2, float* __restrict__ out2, int M2)
{
    __shared__ ushort_t As[64][72];
    __shared__ ushort_t Bs[32][72];
    const int t = threadIdx.x;
    const int w = t >> 6, lane = t & 63;
    const int m = lane & 15, quad = lane >> 4;
    const int row0 = blockIdx.y << 6, col0 = blockIdx.x << 5;   // 32-col tiles
    const int sr = t >> 2;
    const int sc = (t & 3) << 4;
    const int wr2 = t >> 3;           // W staging row 0..31
    const int wc2 = (t & 7) << 3;     // W staging k-chunk 0,8,...,56

    const float* Wu = W;
    const float* b1u = bias1;
    const float* b2u = bias2;
    float* outu = out;
    int Mu = M, colu = col0;
    if (colsplit > 0 && col0 >= colsplit) {
        Wu = W2; b1u = bias_r2; b2u = nullptr;
        outu = out2; Mu = M2; colu = col0 - colsplit;
    }

    f32x4 acc[2] = {};
    for (int k0 = 0; k0 < K; k0 += 64) {
        const float* xp = &X[(size_t)(row0 + sr) * K + k0 + sc];
        const float* wp = &Wu[(size_t)(colu + wr2) * K + k0 + wc2];
        float4 xa = *(const float4*)xp,       xb = *(const float4*)(xp + 4);
        float4 xc = *(const float4*)(xp + 8), xd = *(const float4*)(xp + 12);
        float4 wa = *(const float4*)wp,       wb = *(const float4*)(wp + 4);
        __syncthreads();
        {
            unsigned int tx[8];
            tx[0] = pack2bf(xa.x, xa.y); tx[1] = pack2bf(xa.z, xa.w);
            tx[2] = pack2bf(xb.x, xb.y); tx[3] = pack2bf(xb.z, xb.w);
            tx[4] = pack2bf(xc.x, xc.y); tx[5] = pack2bf(xc.z, xc.w);
            tx[6] = pack2bf(xd.x, xd.y); tx[7] = pack2bf(xd.z, xd.w);
            *(uint4*)&As[sr][sc]     = *(const uint4*)&tx[0];
            *(uint4*)&As[sr][sc + 8] = *(const uint4*)&tx[4];
            unsigned int tw[4];
            tw[0] = pack2bf(wa.x, wa.y); tw[1] = pack2bf(wa.z, wa.w);
            tw[2] = pack2bf(wb.x, wb.y); tw[3] = pack2bf(wb.z, wb.w);
            *(uint4*)&Bs[wr2][wc2] = *(const uint4*)&tw[0];
        }
        __syncthreads();
        #pragma unroll
        for (int kc = 0; kc < 2; kc++) {
            bf16x8 af = *(const bf16x8*)&As[(w << 4) + m][kc * 32 + quad * 8];
            #pragma unroll
            for (int cb = 0; cb < 2; cb++) {
                bf16x8 bf = *(const bf16x8*)&Bs[cb * 16 + m][kc * 32 + quad * 8];
                acc[cb] = __builtin_amdgcn_mfma_f32_16x16x32_bf16(af, bf, acc[cb], 0, 0, 0);
            }
        }
    }
    #pragma unroll
    for (int cb = 0; cb < 2; cb++) {
        #pragma unroll
        for (int r = 0; r < 4; r++) {
            const int row = row0 + (w << 4) + quad * 4 + r;
            const int col = colu + cb * 16 + m;
            float v = acc[cb][r];
            if (b1u) v += b1u[col];
            if (b2u) v += b2u[col];
            if (res1) v += res1[(size_t)row * Mu + col];
            if (res2) v += res2scale * res2[(size_t)row * Mu + col];
            if (dorelu) v = fmaxf(v, 0.f);
            if (obf) ((ushort_t*)outu)[(size_t)row * Mu + col] = f2bf(v);
            else outu[(size_t)row * Mu + col] = v;
        }
    }
}

// ---------------- K/V bf16 prep: Kb[h][n][d], Vtb[h][d][n] ----------------
__global__ __launch_bounds__(256)
void kv_prep_k(const float* __restrict__ qkv, ushort_t* __restrict__ Kb,
               ushort_t* __restrict__ Vtb)
{
    __shared__ ushort_t Vs[64][72];
    const int h = blockIdx.y;
    const int n0 = blockIdx.x << 6;
    const int t = threadIdx.x;
    for (int u = t; u < 1024; u += 256) {
        int r = u >> 4, c = u & 15;
        const float* kp = &qkv[(size_t)(n0 + r) * 768 + 256 + h * 64 + c * 4];
        float4 kv = *(const float4*)kp;
        float4 vv = *(const float4*)(kp + 256);
        *(uint2*)&Kb[((size_t)(h * 4096 + n0 + r)) * 64 + c * 4] =
            make_uint2(pack2bf(kv.x, kv.y), pack2bf(kv.z, kv.w));
        *(uint2*)&Vs[r][c * 4] =
            make_uint2(pack2bf(vv.x, vv.y), pack2bf(vv.z, vv.w));
    }
    __syncthreads();
    int d = t >> 2, kc = t & 3;
    __attribute__((aligned(16))) ushort_t vals[16];
    #pragma unroll
    for (int k = 0; k < 16; k++) vals[k] = Vs[kc * 16 + k][d];
    ushort_t* op = &Vtb[((size_t)(h * 64 + d)) * 4096 + n0 + kc * 16];
    *(uint4*)op = *(const uint4*)&vals[0];
    *(uint4*)(op + 8) = *(const uint4*)&vals[8];
}

// ---------------- split-K MFMA flash attention partials (exp2 domain) ----------------
__global__ __launch_bounds__(256)
void attn_part_k(const float* qkv, const ushort_t* __restrict__ Kb,
                 const ushort_t* __restrict__ Vtb, ushort_t* opart,
                 float* __restrict__ m_part, float* __restrict__ l_part)
{
    __shared__ ushort_t Kt[64][72];
    __shared__ ushort_t Vt[64][72];
    __shared__ ushort_t Plb[4][16][72];
    const int h = blockIdx.y & 3;
    const int split = blockIdx.y >> 2;
    const int q0 = blockIdx.x << 6;
    const int t = threadIdx.x;
    const int w = t >> 6, lane = t & 63;
    const int m = lane & 15, quad = lane >> 4;

    // Q prescaled by 0.125*log2(e): scores land in log2 domain
    const float qs = 0.125f * 1.44269504f;
    bf16x8 qf[2];
    #pragma unroll
    for (int kc = 0; kc < 2; kc++) {
        const float* qp = &qkv[(size_t)(q0 + w * 16 + m) * 768 + h * 64 + kc * 32 + quad * 8];
        float4 a = *(const float4*)qp;
        float4 b = *(const float4*)(qp + 4);
        qf[kc][0] = (short)f2bf(a.x * qs);
        qf[kc][1] = (short)f2bf(a.y * qs);
        qf[kc][2] = (short)f2bf(a.z * qs);
        qf[kc][3] = (short)f2bf(a.w * qs);
        qf[kc][4] = (short)f2bf(b.x * qs);
        qf[kc][5] = (short)f2bf(b.y * qs);
        qf[kc][6] = (short)f2bf(b.z * qs);
        qf[kc][7] = (short)f2bf(b.w * qs);
    }
    bf16x8 onesf;
    #pragma unroll
    for (int j = 0; j < 8; j++) onesf[j] = (short)0x3F80;

    f32x4 o[4], ol;
    float mrow[4];
    #pragma unroll
    for (int i = 0; i < 4; i++) {
        o[i] = (f32x4){0.f, 0.f, 0.f, 0.f};
        mrow[i] = -1e30f;
    }
    ol = (f32x4){0.f, 0.f, 0.f, 0.f};

    for (int kb = split * 16; kb < split * 16 + 16; kb++) {
        __syncthreads();
        for (int u = t; u < 512; u += 256) {
            int r = u >> 3, c = u & 7;
            int pr = ((r & 15) << 2) | (r >> 4);   // permuted key row for Kt
            *(uint4*)&Kt[r][c * 8] = *(const uint4*)&Kb[((size_t)(h * 4096 + kb * 64 + pr)) * 64 + c * 8];
            *(uint4*)&Vt[r][c * 8] = *(const uint4*)&Vtb[((size_t)(h * 64 + r)) * 4096 + kb * 64 + c * 8];
        }
        __syncthreads();

        f32x4 s[4];
        #pragma unroll
        for (int b = 0; b < 4; b++) s[b] = (f32x4){0.f, 0.f, 0.f, 0.f};
        #pragma unroll
        for (int b = 0; b < 4; b++)
            #pragma unroll
            for (int kc = 0; kc < 2; kc++) {
                bf16x8 kf = *(const bf16x8*)&Kt[b * 16 + m][kc * 32 + quad * 8];
                s[b] = __builtin_amdgcn_mfma_f32_16x16x32_bf16(qf[kc], kf, s[b], 0, 0, 0);
            }

        #pragma unroll
        for (int r = 0; r < 4; r++) {
            float mx = fmaxf(fmaxf(s[0][r], s[1][r]), fmaxf(s[2][r], s[3][r]));
            #pragma unroll
            for (int off = 1; off < 16; off <<= 1)
                mx = fmaxf(mx, __shfl_xor(mx, off));
            float mn = fmaxf(mrow[r], mx);
            float alpha = __builtin_amdgcn_exp2f(mrow[r] - mn);
            mrow[r] = mn;
            unsigned int d0 = pack2bf(__builtin_amdgcn_exp2f(s[0][r] - mn),
                                      __builtin_amdgcn_exp2f(s[1][r] - mn));
            unsigned int d1 = pack2bf(__builtin_amdgcn_exp2f(s[2][r] - mn),
                                      __builtin_amdgcn_exp2f(s[3][r] - mn));
            *(uint2*)&Plb[w][quad * 4 + r][m * 4] = make_uint2(d0, d1);
            o[0][r] *= alpha; o[1][r] *= alpha;
            o[2][r] *= alpha; o[3][r] *= alpha;
            ol[r] *= alpha;
        }

        #pragma unroll
        for (int kc = 0; kc < 2; kc++) {
            bf16x8 pa = *(const bf16x8*)&Plb[w][m][kc * 32 + quad * 8];
            #pragma unroll
            for (int nb = 0; nb < 4; nb++) {
                bf16x8 vf = *(const bf16x8*)&Vt[nb * 16 + m][kc * 32 + quad * 8];
                o[nb] = __builtin_amdgcn_mfma_f32_16x16x32_bf16(pa, vf, o[nb], 0, 0, 0);
            }
            ol = __builtin_amdgcn_mfma_f32_16x16x32_bf16(pa, onesf, ol, 0, 0, 0);
        }
    }

    #pragma unroll
    for (int nb = 0; nb < 4; nb++)
        #pragma unroll
        for (int r = 0; r < 4; r++) {
            int q = q0 + w * 16 + quad * 4 + r;
            opart[(size_t)q * 1536 + 512 + split * 256 + h * 64 + nb * 16 + m] = f2bf(o[nb][r]);
        }
    if (m == 0) {
        #pragma unroll
        for (int r = 0; r < 4; r++) {
            int q = q0 + w * 16 + quad * 4 + r;
            m_part[(split * 4 + h) * 4096 + q] = mrow[r];
            l_part[(split * 4 + h) * 4096 + q] = ol[r];
        }
    }
}

// merge 4 splits (m in log2 domain)
__global__ __launch_bounds__(256)
void attn_merge_k(const ushort_t* __restrict__ opart, const float* __restrict__ m_part,
                  const float* __restrict__ l_part, float* __restrict__ att)
{
    int idx = blockIdx.x * 256 + threadIdx.x;
    int q = idx >> 8, c = idx & 255;
    int h = c >> 6, d = c & 63;
    float ms[4];
    float mmax = -1e30f;
    #pragma unroll
    for (int s = 0; s < 4; s++) {
        ms[s] = m_part[(s * 4 + h) * 4096 + q];
        mmax = fmaxf(mmax, ms[s]);
    }
    float onum = 0.f, lden = 0.f;
    #pragma unroll
    for (int s = 0; s < 4; s++) {
        float wgt = __builtin_amdgcn_exp2f(ms[s] - mmax);
        float ov = bf2f(opart[(size_t)q * 1536 + 512 + s * 256 + h * 64 + d]);
        onum += wgt * ov;
        lden += wgt * l_part[(s * 4 + h) * 4096 + q];
    }
    att[(size_t)q * 256 + c] = onum / lden;
}

// ---------------- symmetrized final MLP, MFMA bf16 ----------------
__global__ __launch_bounds__(256)
void sym_mlp_mfma_k(const ushort_t* __restrict__ Tb, const ushort_t* __restrict__ Wb,
                    const float* __restrict__ b2, float* __restrict__ out)
{
    __shared__ ushort_t As[128][72];
    __shared__ ushort_t Bs[128][72];
    const int t = threadIdx.x;
    const int w = t >> 6, lane = t & 63;
    const int m = lane & 15, quad = lane >> 4;
    const int wr = (w >> 1) * 64, wc = (w & 1) * 64;
    const int ri = blockIdx.y * 128, rj = blockIdx.x * 128;

    f32x4 acc[4][4] = {};
    for (int kk = 0; kk < 8; kk++) {
        const int k0 = kk * 64;
        const ushort_t* Asrc = (k0 < 256) ? Tb : Wb;
        const ushort_t* Bsrc = (k0 < 256) ? Wb : Tb;
        const int kcol = k0 & 255;
        __syncthreads();
        #pragma unroll
        for (int i = 0; i < 4; i++) {
            int s = t + i * 256;
            int row = s >> 3, ch = (s & 7) * 8;
            *(uint4*)&As[row][ch] = *(const uint4*)&Asrc[(size_t)(ri + row) * 256 + kcol + ch];
            *(uint4*)&Bs[row][ch] = *(const uint4*)&Bsrc[(size_t)(rj + row) * 256 + kcol + ch];
        }
        __syncthreads();
        #pragma unroll
        for (int kc = 0; kc < 2; kc++) {
            bf16x8 af[4], bfr[4];
            #pragma unroll
            for (int rb = 0; rb < 4; rb++)
                af[rb] = *(const bf16x8*)&As[wr + rb * 16 + m][kc * 32 + quad * 8];
            #pragma unroll
            for (int cb = 0; cb < 4; cb++)
                bfr[cb] = *(const bf16x8*)&Bs[wc + cb * 16 + m][kc * 32 + quad * 8];
            #pragma unroll
            for (int rb = 0; rb < 4; rb++)
                #pragma unroll
                for (int cb = 0; cb < 4; cb++)
                    acc[rb][cb] = __builtin_amdgcn_mfma_f32_16x16x32_bf16(af[rb], bfr[cb], acc[rb][cb], 0, 0, 0);
        }
    }
    #pragma unroll
    for (int rb = 0; rb < 4; rb++) {
        #pragma unroll
        for (int r = 0; r < 4; r++) {
            const int gr = ri + wr + rb * 16 + quad * 4 + r;
            const float br = b2[gr];
            #pragma unroll
            for (int cb = 0; cb < 4; cb++) {
                const int gc = rj + wc + cb * 16 + m;
                out[(size_t)gr * NN + gc] = 0.5f * (acc[rb][cb][r] + br + b2[gc]);
            }
        }
    }
}

// ---------------- launch ----------------
extern "C" void kernel_launch(void* const* d_in, const int* in_sizes, int n_in,
                              void* d_out, int out_size, void* d_ws, size_t ws_size,
                              hipStream_t stream) {
    (void)in_sizes; (void)n_in; (void)out_size; (void)ws_size;
    const float* x = (const float*)d_in[0];
    const int* ei = (const int*)d_in[1];
    const int* src = ei;
    const int* dst = ei + EE;

    float* ws = (float*)d_ws;
    const int NH = NN * HC;          // 1,048,576 floats
    float* h0  = ws;
    float* hb  = ws + 1 * NH;
    float* hc  = ws + 2 * NH;
    float* att = ws + 3 * NH;
    float* qkv = ws + 4 * NH;
    float* ffh = ws + 4 * NH;        // reuses qkv region (dead by then)
    float* deg = ws + 7 * NH;
    float* dinv = deg + NN;
    int* offs    = (int*)(dinv + NN);
    int* cursor  = offs + 4100;
    int* csr_src = cursor + 4096;
    float* m_part = (float*)(csr_src + EE);
    float* l_part = m_part + 65536;
    ushort_t* Kb  = (ushort_t*)hc;
    ushort_t* Vtb = Kb + NH;
    ushort_t* Tb  = (ushort_t*)hb;
    ushort_t* W2b = Tb + NH;

    deg_init_k<<<NN / 256, 256, 0, stream>>>(deg);
    deg_scatter_k<<<EE / 256, 256, 0, stream>>>(dst, deg);
    dinv_k<<<NN / 256, 256, 0, stream>>>(deg, dinv);
    scan_offsets_k<<<1, 1024, 0, stream>>>(deg, offs, cursor);
    csr_fill_k<<<EE / 256, 256, 0, stream>>>(src, dst, cursor, csr_src);

    // pre: h0 = relu(x @ pre_w^T + pre_b)
    gemm_bf_k<<<dim3(8, 64), 256, 0, stream>>>(
        x, (const float*)d_in[2], (const float*)d_in[3], nullptr,
        nullptr, nullptr, 0.f, h0, 128, 256, 1, 0,
        0, nullptr, nullptr, nullptr, 0);

    for (int L = 0; L < 2; L++) {
        int B = 4 + L * 10;
        const float* gw = (const float*)d_in[B + 0];
        const float* gb = (const float*)d_in[B + 1];
        const float* iw = (const float*)d_in[B + 2];
        const float* ib = (const float*)d_in[B + 3];
        const float* ow = (const float*)d_in[B + 4];
        const float* ob = (const float*)d_in[B + 5];
        const float* w1 = (const float*)d_in[B + 6];
        const float* b1 = (const float*)d_in[B + 7];
        const float* w2 = (const float*)d_in[B + 8];
        const float* b2 = (const float*)d_in[B + 9];

        // fused: cols 0-255 = h0@gw^T -> att(xw); cols 256-1023 = h0@iw^T+ib -> qkv
        gemm_bf_k<<<dim3(32, 64), 256, 0, stream>>>(
            h0, gw, nullptr, nullptr, nullptr, nullptr, 0.f, att, 256, 256, 0, 0,
            256, iw, ib, qkv, 768);
        gcn_gather_k<<<NN / 4, 256, 0, stream>>>(att, dinv, offs, csr_src, hb);
        kv_prep_k<<<dim3(64, 4), 256, 0, stream>>>(qkv, Kb, Vtb);
        attn_part_k<<<dim3(64, 16), 256, 0, stream>>>(
            qkv, Kb, Vtb, (ushort_t*)qkv, m_part, l_part);
        attn_merge_k<<<NN, 256, 0, stream>>>(
            (const ushort_t*)qkv, m_part, l_part, att);
        gemm_bf_k<<<dim3(8, 64), 256, 0, stream>>>(
            att, ow, ob, gb, hb, h0, 2.0f, hc, 256, 256, 0, 0,
            0, nullptr, nullptr, nullptr, 0);
        gemm_bf_k<<<dim3(16, 64), 256, 0, stream>>>(
            hc, w1, b1, nullptr, nullptr, nullptr, 0.f, ffh, 256, 512, 1, 0,
            0, nullptr, nullptr, nullptr, 0);
        gemm_bf_k<<<dim3(8, 64), 256, 0, stream>>>(
            ffh, w2, b2, nullptr, hc, nullptr, 0.f, h0, 512, 256, 1, 0,
            0, nullptr, nullptr, nullptr, 0);
    }

    // Tb(bf16) = relu(h0 @ mlp_w1^T + mlp_b1)
    gemm_bf_k<<<dim3(8, 64), 256, 0, stream>>>(
        h0, (const float*)d_in[24], (const float*)d_in[25], nullptr,
        nullptr, nullptr, 0.f, (float*)Tb, 256, 256, 1, 1,
        0, nullptr, nullptr, nullptr, 0);
    // W2b = bf16(mlp_w2)
    cvt_bf16_k<<<NH / 1024, 256, 0, stream>>>((const float*)d_in[26], W2b);
    // out = 0.5*(delta + delta^T) via K=512 concat GEMM
    sym_mlp_mfma_k<<<dim3(32, 32), 256, 0, stream>>>(
        Tb, W2b, (const float*)d_in[27], (float*)d_out);
}